// Round 1
// baseline (5222.279 us; speedup 1.0000x reference)
//
#include <hip/hip_runtime.h>

// ---------------------------------------------------------------------------
// AxialBlock fused implementation (fp32, correctness-first baseline)
// NB=16, CIN=128, COUT=256, MID=128, G=8, GP=16, K=64
// ---------------------------------------------------------------------------

__device__ __forceinline__ float wave_sum(float v){
  #pragma unroll
  for (int o = 32; o; o >>= 1) v += __shfl_xor(v, o, 64);
  return v;
}
__device__ __forceinline__ float wave_max(float v){
  #pragma unroll
  for (int o = 32; o; o >>= 1) v = fmaxf(v, __shfl_xor(v, o, 64));
  return v;
}

// ---------------------------------------------------------------------------
// Generic 1x1 conv: out[n][o][p] = sum_c w[o][c]*in[n][c][p] + bias[o]
// in: (16,128,4096). Also accumulates per-channel sum/sumsq into acc[2*O].
// grid (64 ptiles, O/32, 16), block (64,4), 8 outputs/thread.
// ---------------------------------------------------------------------------
__global__ __launch_bounds__(256) void k_conv(const float* __restrict__ in,
    const float* __restrict__ w, const float* __restrict__ bias,
    float* __restrict__ out, float* __restrict__ acc, int O)
{
  __shared__ float xt[128][64];
  const int n = blockIdx.z, pt = blockIdx.x, ot = blockIdx.y;
  const int tx = threadIdx.x, ty = threadIdx.y;
  const int tid = ty*64 + tx;
  const int p0 = pt*64;
  const float* xb = in + (size_t)n*128*4096 + p0;
  #pragma unroll 4
  for (int r = 0; r < 32; ++r){
    int idx = tid + r*256;
    xt[idx>>6][idx&63] = xb[(size_t)(idx>>6)*4096 + (idx&63)];
  }
  __syncthreads();
  const int ob = __builtin_amdgcn_readfirstlane(ot*32 + ty*8);
  float a[8];
  #pragma unroll
  for (int j = 0; j < 8; ++j) a[j] = bias[ob+j];
  for (int c = 0; c < 128; ++c){
    float xv = xt[c][tx];
    #pragma unroll
    for (int j = 0; j < 8; ++j) a[j] = fmaf(w[(ob+j)*128 + c], xv, a[j]);
  }
  float* op = out + ((size_t)n*O + ob)*4096 + p0 + tx;
  #pragma unroll
  for (int j = 0; j < 8; ++j){
    float v = a[j];
    op[(size_t)j*4096] = v;
    float s  = wave_sum(v);
    float s2 = wave_sum(v*v);
    if (tx == 0){ atomicAdd(&acc[ob+j], s); atomicAdd(&acc[O+ob+j], s2); }
  }
}

// ---------------------------------------------------------------------------
// BN finalize: scsh[c]=g*rstd ; scsh[C+c]=b-mean*scale
// ---------------------------------------------------------------------------
__global__ void k_finalize(const float* __restrict__ acc, const float* __restrict__ g,
    const float* __restrict__ b, float* __restrict__ scsh, int C, float invcnt)
{
  int c = blockIdx.x*blockDim.x + threadIdx.x;
  if (c >= C) return;
  float mean = acc[c]*invcnt;
  float var  = acc[C+c]*invcnt - mean*mean;
  float sc = g[c]*rsqrtf(var + 1e-5f);
  scsh[c]   = sc;
  scsh[C+c] = fmaf(-mean, sc, b[c]);
}

// ---------------------------------------------------------------------------
// bn1+relu + transpose: hin[(n*64+w)*8192 + c*64 + h] = relu(bn(out0[n][c][h][w]))
// grid (128 c, 16 n), block (64,4)
// ---------------------------------------------------------------------------
__global__ __launch_bounds__(256) void k_trans_bnrelu(const float* __restrict__ out0,
    const float* __restrict__ scsh, float* __restrict__ hin)
{
  __shared__ float t[64][65];
  const int c = blockIdx.x, n = blockIdx.y;
  const int tx = threadIdx.x, ty = threadIdx.y;
  const float sc = scsh[c], sh = scsh[128+c];
  const float* src = out0 + ((size_t)n*128 + c)*4096;
  #pragma unroll
  for (int r = 0; r < 16; ++r){
    int h = ty + r*4;
    t[h][tx] = src[h*64 + tx];           // t[h][w]
  }
  __syncthreads();
  float* dst = hin + (size_t)(n*64)*8192 + (size_t)c*64;
  #pragma unroll
  for (int r = 0; r < 16; ++r){
    int w_ = ty + r*4;
    float vv = fmaf(sc, t[tx][w_], sh);  // value at (h=tx, w=w_)... see index below
    // target: hin[(n*64+w)*8192 + c*64 + h], lanes tx = h, w = w_
    // value needed = t[h=tx? no] -> value at (w=w_, h=tx) is t[tx? ]:
    // t[h][w]: want t[tx][w_]? t[tx][w_] = value at h=tx, w=w_. Correct.
    dst[(size_t)w_*8192 + tx] = fmaxf(vv, 0.f);
  }
}

// ---------------------------------------------------------------------------
// QKV gemm: qkv[b][o][l] = sum_c w[o][c]*in[b][c][l]  (raw, stats accumulated)
// in: (1024,128,64) contiguous. grid (1024, 4), block (64,4), 16 outs/thread
// ---------------------------------------------------------------------------
__global__ __launch_bounds__(256) void k_qkv(const float* __restrict__ in,
    const float* __restrict__ wq, float* __restrict__ qkv, float* __restrict__ acc)
{
  __shared__ float xt[128][64];
  const int b = blockIdx.x, ot = blockIdx.y;
  const int tx = threadIdx.x, ty = threadIdx.y;
  const int tid = ty*64 + tx;
  const float* xb = in + (size_t)b*8192;
  #pragma unroll 4
  for (int r = 0; r < 32; ++r){
    int idx = tid + r*256;
    xt[idx>>6][idx&63] = xb[idx];
  }
  __syncthreads();
  const int ob = __builtin_amdgcn_readfirstlane(ot*64 + ty*16);
  float a[16];
  #pragma unroll
  for (int j = 0; j < 16; ++j) a[j] = 0.f;
  for (int c = 0; c < 128; ++c){
    float xv = xt[c][tx];
    #pragma unroll
    for (int j = 0; j < 16; ++j) a[j] = fmaf(wq[(ob+j)*128 + c], xv, a[j]);
  }
  float* op = qkv + ((size_t)b*256 + ob)*64 + tx;
  #pragma unroll
  for (int j = 0; j < 16; ++j){
    float v = a[j];
    op[(size_t)j*64] = v;
    float s  = wave_sum(v);
    float s2 = wave_sum(v*v);
    if (tx == 0){ atomicAdd(&acc[ob+j], s); atomicAdd(&acc[256+ob+j], s2); }
  }
}

// ---------------------------------------------------------------------------
// Precompute windowed sums/correlations of rel rows for the sim-BN stats:
// W[c,c2][i] = sum_{u=0..63} r_c[i+u]*r_c2[i+u] ; S[c][i] = sum_u r_c[i+u]
// side 0: rows 0..7 (q_e); side 1: rows 8..15 (k_e)
// ---------------------------------------------------------------------------
__global__ __launch_bounds__(256) void k_prep_rel(const float* __restrict__ rel,
                                                  float* __restrict__ rw)
{
  const int side = blockIdx.x;
  const float* base = rel + side*8*127;
  float* Wout = rw + side*4096;
  float* Sout = rw + 8192 + side*512;
  const int tid = threadIdx.y*64 + threadIdx.x;
  for (int idx = tid; idx < 4096; idx += 256){
    int pr = idx >> 6, i = idx & 63;
    int c = pr >> 3, c2 = pr & 7;
    const float* r1 = base + c*127 + i;
    const float* r2 = base + c2*127 + i;
    float s = 0.f;
    #pragma unroll 8
    for (int u = 0; u < 64; ++u) s = fmaf(r1[u], r2[u], s);
    Wout[idx] = s;
  }
  for (int idx = tid; idx < 512; idx += 256){
    int c = idx >> 6, i = idx & 63;
    const float* r1 = base + c*127 + i;
    float s = 0.f;
    #pragma unroll 8
    for (int u = 0; u < 64; ++u) s += r1[u];
    Sout[idx] = s;
  }
}

// ---------------------------------------------------------------------------
// sim-BN stats: per (b,g) computes sum & sumsq of qk, qr, kr over (i,j)
// via Gram-matrix factorization (no 64x64 logits materialized).
// grid (1024), block (64,4); each wave handles 2 groups.
// ---------------------------------------------------------------------------
__global__ __launch_bounds__(256) void k_att_stats(const float* __restrict__ qkv,
    const float* __restrict__ bq, const float* __restrict__ rw, float* __restrict__ accsim)
{
  __shared__ float WqS[4096], WkS[4096], SqS[512], SkS[512];
  const int b = blockIdx.x;
  const int tx = threadIdx.x, ty = threadIdx.y;
  const int tid = ty*64 + tx;
  for (int idx = tid; idx < 4096; idx += 256){ WqS[idx] = rw[idx]; WkS[idx] = rw[4096+idx]; }
  for (int idx = tid; idx < 512;  idx += 256){ SqS[idx] = rw[8192+idx]; SkS[idx] = rw[8704+idx]; }
  __syncthreads();
  const int i = tx;
  for (int gi = 0; gi < 2; ++gi){
    int g = ty*2 + gi;
    float q[8], k[8];
    #pragma unroll
    for (int c = 0; c < 8; ++c){
      int oq = g*32 + c, ok = oq + 8;
      q[c] = fmaf(bq[oq], qkv[((size_t)b*256 + oq)*64 + i], bq[256+oq]);
      k[c] = fmaf(bq[ok], qkv[((size_t)b*256 + ok)*64 + i], bq[256+ok]);
    }
    float qs[8], ks[8];
    #pragma unroll
    for (int c = 0; c < 8; ++c){ qs[c] = wave_sum(q[c]); ks[c] = wave_sum(k[c]); }
    float sum_qk = 0.f;
    #pragma unroll
    for (int c = 0; c < 8; ++c) sum_qk = fmaf(qs[c], ks[c], sum_qk);
    float ss_qk = 0.f;
    #pragma unroll
    for (int c = 0; c < 8; ++c){
      #pragma unroll
      for (int c2 = 0; c2 < 8; ++c2){
        float gq = wave_sum(q[c]*q[c2]);
        float gk = wave_sum(k[c]*k[c2]);
        ss_qk = fmaf(gq, gk, ss_qk);
      }
    }
    float tq = 0.f, tk = 0.f, tq2 = 0.f, tk2 = 0.f;
    #pragma unroll
    for (int c = 0; c < 8; ++c){
      tq = fmaf(q[c], SqS[c*64 + i], tq);
      tk = fmaf(k[c], SkS[c*64 + i], tk);
    }
    #pragma unroll
    for (int c = 0; c < 8; ++c){
      #pragma unroll
      for (int c2 = 0; c2 < 8; ++c2){
        tq2 = fmaf(q[c]*q[c2], WqS[(c*8+c2)*64 + i], tq2);
        tk2 = fmaf(k[c]*k[c2], WkS[(c*8+c2)*64 + i], tk2);
      }
    }
    float sum_qr = 0.1f  * wave_sum(tq);
    float ss_qr  = 0.01f * wave_sum(tq2);
    float sum_kr = 0.1f  * wave_sum(tk);
    float ss_kr  = 0.01f * wave_sum(tk2);
    if (tx == 0){
      atomicAdd(&accsim[g],        sum_qk); atomicAdd(&accsim[24+g],      ss_qk);
      atomicAdd(&accsim[8+g],      sum_qr); atomicAdd(&accsim[24+8+g],    ss_qr);
      atomicAdd(&accsim[16+g],     sum_kr); atomicAdd(&accsim[24+16+g],   ss_kr);
    }
  }
}

// ---------------------------------------------------------------------------
// attention pass 2: logits -> BN-combine -> softmax -> sv/sve, write svout
// (B,256,64) raw (pre-bo-BN) + bo stats. grid (1024 b, 8 g), block (64,4)
// ---------------------------------------------------------------------------
__global__ __launch_bounds__(256) void k_att2(const float* __restrict__ qkv,
    const float* __restrict__ bq, const float* __restrict__ rel,
    const float* __restrict__ simsc, float* __restrict__ svout, float* __restrict__ accbo)
{
  __shared__ float q[8][64];
  __shared__ float v[16][64];
  __shared__ float re[4064];     // all 32 rel rows x 127
  __shared__ float P[64][65];
  const int b = blockIdx.x, g = blockIdx.y;
  const int tx = threadIdx.x, ty = threadIdx.y;
  const int tid = ty*64 + tx;
  #pragma unroll
  for (int r = 0; r < 2; ++r){
    int u = ty + r*4;                       // 0..7: q
    int o = g*32 + u;
    q[u][tx] = fmaf(bq[o], qkv[((size_t)b*256 + o)*64 + tx], bq[256+o]);
  }
  #pragma unroll
  for (int r = 0; r < 4; ++r){
    int u = ty + r*4;                       // 0..15: v
    int o = g*32 + 16 + u;
    v[u][tx] = fmaf(bq[o], qkv[((size_t)b*256 + o)*64 + tx], bq[256+o]);
  }
  for (int idx = tid; idx < 4064; idx += 256) re[idx] = rel[idx];
  float kreg[8];                            // lane tx holds k[c][j=tx]
  #pragma unroll
  for (int c = 0; c < 8; ++c){
    int o = g*32 + 8 + c;
    kreg[c] = fmaf(bq[o], qkv[((size_t)b*256 + o)*64 + tx], bq[256+o]);
  }
  __syncthreads();
  const float scq = simsc[g], scr = 0.1f*simsc[8+g], sck = 0.1f*simsc[16+g];
  const float shf = simsc[24+g] + simsc[24+8+g] + simsc[24+16+g];
  // phase A: logits; lanes = j
  for (int t = 0; t < 16; ++t){
    int i = ty + 4*t;
    float qk = 0.f, qr = 0.f, kr = 0.f;
    #pragma unroll
    for (int c = 0; c < 8; ++c){
      float qv = q[c][i];
      qk = fmaf(qv, kreg[c], qk);
      qr = fmaf(qv, re[c*127 + (i - tx + 63)], qr);
      kr = fmaf(kreg[c], re[(8+c)*127 + (tx - i + 63)], kr);
    }
    P[i][tx] = fmaf(scq, qk, fmaf(scr, qr, fmaf(sck, kr, shf)));
  }
  __syncthreads();
  // phase B: softmax along j (lanes)
  for (int t = 0; t < 16; ++t){
    int i = ty*16 + t;
    float xv = P[i][tx];
    float m = wave_max(xv);
    float e = __expf(xv - m);
    float s = wave_sum(e);
    P[i][tx] = e / s;
  }
  __syncthreads();
  // phase C: sv (ty 0..1) / sve (ty 2..3); lanes = i
  float out8[8];
  #pragma unroll
  for (int c = 0; c < 8; ++c) out8[c] = 0.f;
  const int i = tx;
  if (ty < 2){
    const int c0 = ty*8;
    for (int jj = 0; jj < 64; ++jj){
      float p = P[i][jj];
      #pragma unroll
      for (int cc = 0; cc < 8; ++cc) out8[cc] = fmaf(p, v[c0+cc][jj], out8[cc]);
    }
  } else {
    const int c0 = (ty-2)*8;
    for (int jj = 0; jj < 64; ++jj){
      float p = P[i][jj];
      #pragma unroll
      for (int cc = 0; cc < 8; ++cc)
        out8[cc] = fmaf(p, re[(16+c0+cc)*127 + (i - jj + 63)], out8[cc]);
    }
    #pragma unroll
    for (int cc = 0; cc < 8; ++cc) out8[cc] *= 0.1f;
  }
  const int chbase = (ty < 2) ? (g*16 + ty*8) : (128 + g*16 + (ty-2)*8);
  #pragma unroll
  for (int cc = 0; cc < 8; ++cc){
    float val = out8[cc];
    svout[((size_t)b*256 + chbase + cc)*64 + i] = val;
    float s  = wave_sum(val);
    float s2 = wave_sum(val*val);
    if (tx == 0){ atomicAdd(&accbo[chbase+cc], s); atomicAdd(&accbo[256+chbase+cc], s2); }
  }
}

// ---------------------------------------------------------------------------
// bo-BN + pair-sum + transpose (h-axial -> w-axial input):
// win[(n*64+h)*8192 + c*64 + w] = bn(sv[(n*64+w)][2c][h]) + bn(sv[..][2c+1][h])
// ---------------------------------------------------------------------------
__global__ __launch_bounds__(256) void k_pairT(const float* __restrict__ sv,
    const float* __restrict__ bo, float* __restrict__ win)
{
  __shared__ float t[64][65];
  const int c = blockIdx.x, n = blockIdx.y;
  const int tx = threadIdx.x, ty = threadIdx.y;
  const float s0 = bo[2*c], s1 = bo[2*c+1];
  const float sh = bo[256 + 2*c] + bo[256 + 2*c + 1];
  const float* base = sv + (size_t)(n*64)*256*64;
  #pragma unroll
  for (int r = 0; r < 16; ++r){
    int w_ = ty + r*4;
    float v0 = base[((size_t)w_*256 + 2*c    )*64 + tx];
    float v1 = base[((size_t)w_*256 + 2*c + 1)*64 + tx];
    t[w_][tx] = fmaf(s0, v0, fmaf(s1, v1, sh));  // t[w][h]
  }
  __syncthreads();
  float* dst = win + (size_t)(n*64)*8192 + (size_t)c*64;
  #pragma unroll
  for (int r = 0; r < 16; ++r){
    int h_ = ty + r*4;
    dst[(size_t)h_*8192 + tx] = t[tx][h_];       // lanes = w
  }
}

// ---------------------------------------------------------------------------
// bo-BN + pair-sum, no transpose (w-axial -> natural NCHW):
// wbuf[n][m][h][w] = bn(sv[(n*64+h)][2m][w]) + bn(sv[..][2m+1][w])
// ---------------------------------------------------------------------------
__global__ __launch_bounds__(256) void k_pair_w(const float* __restrict__ sv,
    const float* __restrict__ bo, float* __restrict__ wbuf)
{
  const int m = blockIdx.x, n = blockIdx.y;
  const int tx = threadIdx.x, ty = threadIdx.y;
  const float s0 = bo[2*m], s1 = bo[2*m+1];
  const float sh = bo[256 + 2*m] + bo[256 + 2*m + 1];
  #pragma unroll
  for (int r = 0; r < 16; ++r){
    int h = ty + r*4;
    float v0 = sv[((size_t)(n*64+h)*256 + 2*m    )*64 + tx];
    float v1 = sv[((size_t)(n*64+h)*256 + 2*m + 1)*64 + tx];
    wbuf[((size_t)(n*128+m)*64 + h)*64 + tx] = fmaf(s0, v0, fmaf(s1, v1, sh));
  }
}

// ---------------------------------------------------------------------------
// final: out = bn2(y2) + c1_w . x + c1_b
// ---------------------------------------------------------------------------
__global__ __launch_bounds__(256) void k_final(const float* __restrict__ x,
    const float* __restrict__ w1, const float* __restrict__ b1,
    const float* __restrict__ y2, const float* __restrict__ scsh,
    float* __restrict__ out)
{
  __shared__ float xt[128][64];
  const int n = blockIdx.z, pt = blockIdx.x, ot = blockIdx.y;
  const int tx = threadIdx.x, ty = threadIdx.y;
  const int tid = ty*64 + tx;
  const int p0 = pt*64;
  const float* xb = x + (size_t)n*128*4096 + p0;
  #pragma unroll 4
  for (int r = 0; r < 32; ++r){
    int idx = tid + r*256;
    xt[idx>>6][idx&63] = xb[(size_t)(idx>>6)*4096 + (idx&63)];
  }
  __syncthreads();
  const int ob = __builtin_amdgcn_readfirstlane(ot*32 + ty*8);
  float a[8];
  #pragma unroll
  for (int j = 0; j < 8; ++j) a[j] = b1[ob+j];
  for (int c = 0; c < 128; ++c){
    float xv = xt[c][tx];
    #pragma unroll
    for (int j = 0; j < 8; ++j) a[j] = fmaf(w1[(ob+j)*128 + c], xv, a[j]);
  }
  #pragma unroll
  for (int j = 0; j < 8; ++j){
    size_t idx = ((size_t)n*256 + ob + j)*4096 + p0 + tx;
    out[idx] = a[j] + fmaf(scsh[ob+j], y2[idx], scsh[256+ob+j]);
  }
}

// ---------------------------------------------------------------------------

extern "C" void kernel_launch(void* const* d_in, const int* in_sizes, int n_in,
                              void* d_out, int out_size, void* d_ws, size_t ws_size,
                              hipStream_t stream)
{
  const float* x     = (const float*)d_in[0];
  const float* c1_w  = (const float*)d_in[1];
  const float* c1_b  = (const float*)d_in[2];
  const float* cd_w  = (const float*)d_in[3];
  const float* cd_b  = (const float*)d_in[4];
  const float* bn1_g = (const float*)d_in[5];
  const float* bn1_b = (const float*)d_in[6];
  const float* h_qkv = (const float*)d_in[7];
  const float* h_bqg = (const float*)d_in[8];
  const float* h_bqb = (const float*)d_in[9];
  const float* h_bsg = (const float*)d_in[10];
  const float* h_bsb = (const float*)d_in[11];
  const float* h_bog = (const float*)d_in[12];
  const float* h_bob = (const float*)d_in[13];
  const float* h_rel = (const float*)d_in[14];
  const float* w_qkv = (const float*)d_in[15];
  const float* w_bqg = (const float*)d_in[16];
  const float* w_bqb = (const float*)d_in[17];
  const float* w_bsg = (const float*)d_in[18];
  const float* w_bsb = (const float*)d_in[19];
  const float* w_bog = (const float*)d_in[20];
  const float* w_bob = (const float*)d_in[21];
  const float* w_rel = (const float*)d_in[22];
  const float* cu_w  = (const float*)d_in[23];
  const float* cu_b  = (const float*)d_in[24];
  const float* bn2_g = (const float*)d_in[25];
  const float* bn2_b = (const float*)d_in[26];
  float* out = (float*)d_out;
  char* ws = (char*)d_ws;

  // workspace plan (aliased across dead stages), peak 160MB + ~110KB:
  float* OUT0 = (float*)(ws + 0);                    // 32MB (n,128,4096)
  float* HIN  = (float*)(ws + (32ull<<20));          // 32MB (1024,128,64)
  float* QKV  = (float*)(ws + (64ull<<20));          // 64MB (1024,256,64) h-phase
  float* SVO  = (float*)(ws + 0);                    // 64MB, after OUT0/HIN dead
  float* WIN  = (float*)(ws + (64ull<<20));          // 32MB, after QKV(h) dead
  float* QKVW = (float*)(ws + (96ull<<20));          // 64MB w-phase
  float* WBUF = (float*)(ws + (64ull<<20));          // 32MB, after WIN dead
  float* Y2   = (float*)(ws + (96ull<<20));          // 64MB, after QKVW dead
  float* ST   = (float*)(ws + (160ull<<20));         // stats
  float* RWH  = (float*)(ws + (160ull<<20) + 32768); // 9216 floats
  float* RWW  = (float*)(ws + (160ull<<20) + 32768 + 40960);

  float* ACC_BN1 = ST;        float* SC_BN1 = ST + 256;
  float* ACC_BQ  = ST + 512;  float* SC_BQ  = ST + 1024;
  float* ACC_SIM = ST + 1536; float* SC_SIM = ST + 1584;
  float* ACC_BO  = ST + 1632; float* SC_BO  = ST + 2144;
  float* ACC_BQW = ST + 2656; float* SC_BQW = ST + 3168;
  float* ACC_SIMW= ST + 3680; float* SC_SIMW= ST + 3728;
  float* ACC_BOW = ST + 3776; float* SC_BOW = ST + 4288;
  float* ACC_BN2 = ST + 4800; float* SC_BN2 = ST + 5312;

  hipMemsetAsync(ST, 0, 5824*sizeof(float), stream);

  const dim3 blk(64,4);
  const float inv64k = 1.f/65536.f;
  const float invsim = 1.f/4194304.f;

  k_prep_rel<<<2, blk, 0, stream>>>(h_rel, RWH);
  k_prep_rel<<<2, blk, 0, stream>>>(w_rel, RWW);

  // cd conv + bn1 stats
  k_conv<<<dim3(64,4,16), blk, 0, stream>>>(x, cd_w, cd_b, OUT0, ACC_BN1, 128);
  k_finalize<<<1, 128, 0, stream>>>(ACC_BN1, bn1_g, bn1_b, SC_BN1, 128, inv64k);
  k_trans_bnrelu<<<dim3(128,16), blk, 0, stream>>>(OUT0, SC_BN1, HIN);

  // ---- h axial ----
  k_qkv<<<dim3(1024,4), blk, 0, stream>>>(HIN, h_qkv, QKV, ACC_BQ);
  k_finalize<<<1, 256, 0, stream>>>(ACC_BQ, h_bqg, h_bqb, SC_BQ, 256, inv64k);
  k_att_stats<<<1024, blk, 0, stream>>>(QKV, SC_BQ, RWH, ACC_SIM);
  k_finalize<<<1, 32, 0, stream>>>(ACC_SIM, h_bsg, h_bsb, SC_SIM, 24, invsim);
  k_att2<<<dim3(1024,8), blk, 0, stream>>>(QKV, SC_BQ, h_rel, SC_SIM, SVO, ACC_BO);
  k_finalize<<<1, 256, 0, stream>>>(ACC_BO, h_bog, h_bob, SC_BO, 256, inv64k);
  k_pairT<<<dim3(128,16), blk, 0, stream>>>(SVO, SC_BO, WIN);

  // ---- w axial ----
  k_qkv<<<dim3(1024,4), blk, 0, stream>>>(WIN, w_qkv, QKVW, ACC_BQW);
  k_finalize<<<1, 256, 0, stream>>>(ACC_BQW, w_bqg, w_bqb, SC_BQW, 256, inv64k);
  k_att_stats<<<1024, blk, 0, stream>>>(QKVW, SC_BQW, RWW, ACC_SIMW);
  k_finalize<<<1, 32, 0, stream>>>(ACC_SIMW, w_bsg, w_bsb, SC_SIMW, 24, invsim);
  k_att2<<<dim3(1024,8), blk, 0, stream>>>(QKVW, SC_BQW, w_rel, SC_SIMW, SVO, ACC_BOW);
  k_finalize<<<1, 256, 0, stream>>>(ACC_BOW, w_bog, w_bob, SC_BOW, 256, inv64k);
  k_pair_w<<<dim3(128,16), blk, 0, stream>>>(SVO, SC_BOW, WBUF);

  // cu conv + bn2 stats, then fused residual + c1 conv
  k_conv<<<dim3(64,8,16), blk, 0, stream>>>(WBUF, cu_w, cu_b, Y2, ACC_BN2, 256);
  k_finalize<<<1, 256, 0, stream>>>(ACC_BN2, bn2_g, bn2_b, SC_BN2, 256, inv64k);
  k_final<<<dim3(64,8,16), blk, 0, stream>>>(x, c1_w, c1_b, Y2, SC_BN2, out);
}

// Round 2
// 1910.468 us; speedup vs baseline: 2.7335x; 2.7335x over previous
//
#include <hip/hip_runtime.h>

// ---------------------------------------------------------------------------
// AxialBlock fused implementation (fp32). Round 2: spread stats atomics over
// 64 accumulator copies to kill memory-side RMW contention.
// NB=16, CIN=128, COUT=256, MID=128, G=8, GP=16, K=64
// ---------------------------------------------------------------------------

#define NCOPY 64

__device__ __forceinline__ float wave_sum(float v){
  #pragma unroll
  for (int o = 32; o; o >>= 1) v += __shfl_xor(v, o, 64);
  return v;
}
__device__ __forceinline__ float wave_max(float v){
  #pragma unroll
  for (int o = 32; o; o >>= 1) v = fmaxf(v, __shfl_xor(v, o, 64));
  return v;
}

// ---------------------------------------------------------------------------
// Generic 1x1 conv: out[n][o][p] = sum_c w[o][c]*in[n][c][p] + bias[o]
// in: (16,128,4096). Stats into acc copy = blockIdx.x (0..63).
// grid (64 ptiles, O/32, 16), block (64,4), 8 outputs/thread.
// ---------------------------------------------------------------------------
__global__ __launch_bounds__(256) void k_conv(const float* __restrict__ in,
    const float* __restrict__ w, const float* __restrict__ bias,
    float* __restrict__ out, float* __restrict__ acc, int O)
{
  __shared__ float xt[128][64];
  const int n = blockIdx.z, pt = blockIdx.x, ot = blockIdx.y;
  const int tx = threadIdx.x, ty = threadIdx.y;
  const int tid = ty*64 + tx;
  const int p0 = pt*64;
  const float* xb = in + (size_t)n*128*4096 + p0;
  #pragma unroll 4
  for (int r = 0; r < 32; ++r){
    int idx = tid + r*256;
    xt[idx>>6][idx&63] = xb[(size_t)(idx>>6)*4096 + (idx&63)];
  }
  __syncthreads();
  const int ob = __builtin_amdgcn_readfirstlane(ot*32 + ty*8);
  float a[8];
  #pragma unroll
  for (int j = 0; j < 8; ++j) a[j] = bias[ob+j];
  for (int c = 0; c < 128; ++c){
    float xv = xt[c][tx];
    #pragma unroll
    for (int j = 0; j < 8; ++j) a[j] = fmaf(w[(ob+j)*128 + c], xv, a[j]);
  }
  float* op = out + ((size_t)n*O + ob)*4096 + p0 + tx;
  float* accb = acc + (size_t)(pt & (NCOPY-1)) * 2 * O;
  #pragma unroll
  for (int j = 0; j < 8; ++j){
    float v = a[j];
    op[(size_t)j*4096] = v;
    float s  = wave_sum(v);
    float s2 = wave_sum(v*v);
    if (tx == 0){ atomicAdd(&accb[ob+j], s); atomicAdd(&accb[O+ob+j], s2); }
  }
}

// ---------------------------------------------------------------------------
// BN finalize: sum NCOPY copies; scsh[c]=g*rstd ; scsh[C+c]=b-mean*scale
// ---------------------------------------------------------------------------
__global__ void k_finalize(const float* __restrict__ acc, const float* __restrict__ g,
    const float* __restrict__ b, float* __restrict__ scsh, int C, float invcnt)
{
  int c = blockIdx.x*blockDim.x + threadIdx.x;
  if (c >= C) return;
  float s = 0.f, s2 = 0.f;
  #pragma unroll 4
  for (int k2 = 0; k2 < NCOPY; ++k2){
    s  += acc[(size_t)k2*2*C + c];
    s2 += acc[(size_t)k2*2*C + C + c];
  }
  float mean = s*invcnt;
  float var  = s2*invcnt - mean*mean;
  float sc = g[c]*rsqrtf(var + 1e-5f);
  scsh[c]   = sc;
  scsh[C+c] = fmaf(-mean, sc, b[c]);
}

// ---------------------------------------------------------------------------
// bn1+relu + transpose: hin[(n*64+w)*8192 + c*64 + h] = relu(bn(out0[n][c][h][w]))
// grid (128 c, 16 n), block (64,4)
// ---------------------------------------------------------------------------
__global__ __launch_bounds__(256) void k_trans_bnrelu(const float* __restrict__ out0,
    const float* __restrict__ scsh, float* __restrict__ hin)
{
  __shared__ float t[64][65];
  const int c = blockIdx.x, n = blockIdx.y;
  const int tx = threadIdx.x, ty = threadIdx.y;
  const float sc = scsh[c], sh = scsh[128+c];
  const float* src = out0 + ((size_t)n*128 + c)*4096;
  #pragma unroll
  for (int r = 0; r < 16; ++r){
    int h = ty + r*4;
    t[h][tx] = src[h*64 + tx];           // t[h][w]
  }
  __syncthreads();
  float* dst = hin + (size_t)(n*64)*8192 + (size_t)c*64;
  #pragma unroll
  for (int r = 0; r < 16; ++r){
    int w_ = ty + r*4;
    float vv = fmaf(sc, t[tx][w_], sh);  // value at (h=tx, w=w_)
    dst[(size_t)w_*8192 + tx] = fmaxf(vv, 0.f);
  }
}

// ---------------------------------------------------------------------------
// QKV gemm: qkv[b][o][l] = sum_c w[o][c]*in[b][c][l]  (raw, stats accumulated)
// in: (1024,128,64) contiguous. grid (1024, 4), block (64,4), 16 outs/thread
// ---------------------------------------------------------------------------
__global__ __launch_bounds__(256) void k_qkv(const float* __restrict__ in,
    const float* __restrict__ wq, float* __restrict__ qkv, float* __restrict__ acc)
{
  __shared__ float xt[128][64];
  const int b = blockIdx.x, ot = blockIdx.y;
  const int tx = threadIdx.x, ty = threadIdx.y;
  const int tid = ty*64 + tx;
  const float* xb = in + (size_t)b*8192;
  #pragma unroll 4
  for (int r = 0; r < 32; ++r){
    int idx = tid + r*256;
    xt[idx>>6][idx&63] = xb[idx];
  }
  __syncthreads();
  const int ob = __builtin_amdgcn_readfirstlane(ot*64 + ty*16);
  float a[16];
  #pragma unroll
  for (int j = 0; j < 16; ++j) a[j] = 0.f;
  for (int c = 0; c < 128; ++c){
    float xv = xt[c][tx];
    #pragma unroll
    for (int j = 0; j < 16; ++j) a[j] = fmaf(wq[(ob+j)*128 + c], xv, a[j]);
  }
  float* op = qkv + ((size_t)b*256 + ob)*64 + tx;
  float* accb = acc + (size_t)(b & (NCOPY-1)) * 512;
  #pragma unroll
  for (int j = 0; j < 16; ++j){
    float v = a[j];
    op[(size_t)j*64] = v;
    float s  = wave_sum(v);
    float s2 = wave_sum(v*v);
    if (tx == 0){ atomicAdd(&accb[ob+j], s); atomicAdd(&accb[256+ob+j], s2); }
  }
}

// ---------------------------------------------------------------------------
// Precompute windowed sums/correlations of rel rows for the sim-BN stats:
// W[c,c2][i] = sum_{u=0..63} r_c[i+u]*r_c2[i+u] ; S[c][i] = sum_u r_c[i+u]
// ---------------------------------------------------------------------------
__global__ __launch_bounds__(256) void k_prep_rel(const float* __restrict__ rel,
                                                  float* __restrict__ rw)
{
  const int side = blockIdx.x;
  const float* base = rel + side*8*127;
  float* Wout = rw + side*4096;
  float* Sout = rw + 8192 + side*512;
  const int tid = threadIdx.y*64 + threadIdx.x;
  for (int idx = tid; idx < 4096; idx += 256){
    int pr = idx >> 6, i = idx & 63;
    int c = pr >> 3, c2 = pr & 7;
    const float* r1 = base + c*127 + i;
    const float* r2 = base + c2*127 + i;
    float s = 0.f;
    #pragma unroll 8
    for (int u = 0; u < 64; ++u) s = fmaf(r1[u], r2[u], s);
    Wout[idx] = s;
  }
  for (int idx = tid; idx < 512; idx += 256){
    int c = idx >> 6, i = idx & 63;
    const float* r1 = base + c*127 + i;
    float s = 0.f;
    #pragma unroll 8
    for (int u = 0; u < 64; ++u) s += r1[u];
    Sout[idx] = s;
  }
}

// ---------------------------------------------------------------------------
// sim-BN stats per (b,g) via Gram factorization. grid (1024), block (64,4)
// ---------------------------------------------------------------------------
__global__ __launch_bounds__(256) void k_att_stats(const float* __restrict__ qkv,
    const float* __restrict__ bq, const float* __restrict__ rw, float* __restrict__ accsim)
{
  __shared__ float WqS[4096], WkS[4096], SqS[512], SkS[512];
  const int b = blockIdx.x;
  const int tx = threadIdx.x, ty = threadIdx.y;
  const int tid = ty*64 + tx;
  for (int idx = tid; idx < 4096; idx += 256){ WqS[idx] = rw[idx]; WkS[idx] = rw[4096+idx]; }
  for (int idx = tid; idx < 512;  idx += 256){ SqS[idx] = rw[8192+idx]; SkS[idx] = rw[8704+idx]; }
  __syncthreads();
  float* accb = accsim + (size_t)(b & (NCOPY-1)) * 48;
  const int i = tx;
  for (int gi = 0; gi < 2; ++gi){
    int g = ty*2 + gi;
    float q[8], k[8];
    #pragma unroll
    for (int c = 0; c < 8; ++c){
      int oq = g*32 + c, ok = oq + 8;
      q[c] = fmaf(bq[oq], qkv[((size_t)b*256 + oq)*64 + i], bq[256+oq]);
      k[c] = fmaf(bq[ok], qkv[((size_t)b*256 + ok)*64 + i], bq[256+ok]);
    }
    float qs[8], ks[8];
    #pragma unroll
    for (int c = 0; c < 8; ++c){ qs[c] = wave_sum(q[c]); ks[c] = wave_sum(k[c]); }
    float sum_qk = 0.f;
    #pragma unroll
    for (int c = 0; c < 8; ++c) sum_qk = fmaf(qs[c], ks[c], sum_qk);
    float ss_qk = 0.f;
    #pragma unroll
    for (int c = 0; c < 8; ++c){
      #pragma unroll
      for (int c2 = 0; c2 < 8; ++c2){
        float gq = wave_sum(q[c]*q[c2]);
        float gk = wave_sum(k[c]*k[c2]);
        ss_qk = fmaf(gq, gk, ss_qk);
      }
    }
    float tq = 0.f, tk = 0.f, tq2 = 0.f, tk2 = 0.f;
    #pragma unroll
    for (int c = 0; c < 8; ++c){
      tq = fmaf(q[c], SqS[c*64 + i], tq);
      tk = fmaf(k[c], SkS[c*64 + i], tk);
    }
    #pragma unroll
    for (int c = 0; c < 8; ++c){
      #pragma unroll
      for (int c2 = 0; c2 < 8; ++c2){
        tq2 = fmaf(q[c]*q[c2], WqS[(c*8+c2)*64 + i], tq2);
        tk2 = fmaf(k[c]*k[c2], WkS[(c*8+c2)*64 + i], tk2);
      }
    }
    float sum_qr = 0.1f  * wave_sum(tq);
    float ss_qr  = 0.01f * wave_sum(tq2);
    float sum_kr = 0.1f  * wave_sum(tk);
    float ss_kr  = 0.01f * wave_sum(tk2);
    if (tx == 0){
      atomicAdd(&accb[g],      sum_qk); atomicAdd(&accb[24+g],    ss_qk);
      atomicAdd(&accb[8+g],    sum_qr); atomicAdd(&accb[24+8+g],  ss_qr);
      atomicAdd(&accb[16+g],   sum_kr); atomicAdd(&accb[24+16+g], ss_kr);
    }
  }
}

// ---------------------------------------------------------------------------
// attention pass 2: logits -> BN-combine -> softmax -> sv/sve
// grid (1024 b, 8 g), block (64,4)
// ---------------------------------------------------------------------------
__global__ __launch_bounds__(256) void k_att2(const float* __restrict__ qkv,
    const float* __restrict__ bq, const float* __restrict__ rel,
    const float* __restrict__ simsc, float* __restrict__ svout, float* __restrict__ accbo)
{
  __shared__ float q[8][64];
  __shared__ float v[16][64];
  __shared__ float re[4064];     // all 32 rel rows x 127
  __shared__ float P[64][65];
  const int b = blockIdx.x, g = blockIdx.y;
  const int tx = threadIdx.x, ty = threadIdx.y;
  const int tid = ty*64 + tx;
  #pragma unroll
  for (int r = 0; r < 2; ++r){
    int u = ty + r*4;                       // 0..7: q
    int o = g*32 + u;
    q[u][tx] = fmaf(bq[o], qkv[((size_t)b*256 + o)*64 + tx], bq[256+o]);
  }
  #pragma unroll
  for (int r = 0; r < 4; ++r){
    int u = ty + r*4;                       // 0..15: v
    int o = g*32 + 16 + u;
    v[u][tx] = fmaf(bq[o], qkv[((size_t)b*256 + o)*64 + tx], bq[256+o]);
  }
  for (int idx = tid; idx < 4064; idx += 256) re[idx] = rel[idx];
  float kreg[8];                            // lane tx holds k[c][j=tx]
  #pragma unroll
  for (int c = 0; c < 8; ++c){
    int o = g*32 + 8 + c;
    kreg[c] = fmaf(bq[o], qkv[((size_t)b*256 + o)*64 + tx], bq[256+o]);
  }
  __syncthreads();
  const float scq = simsc[g], scr = 0.1f*simsc[8+g], sck = 0.1f*simsc[16+g];
  const float shf = simsc[24+g] + simsc[24+8+g] + simsc[24+16+g];
  // phase A: logits; lanes = j
  for (int t = 0; t < 16; ++t){
    int i = ty + 4*t;
    float qk = 0.f, qr = 0.f, kr = 0.f;
    #pragma unroll
    for (int c = 0; c < 8; ++c){
      float qv = q[c][i];
      qk = fmaf(qv, kreg[c], qk);
      qr = fmaf(qv, re[c*127 + (i - tx + 63)], qr);
      kr = fmaf(kreg[c], re[(8+c)*127 + (tx - i + 63)], kr);
    }
    P[i][tx] = fmaf(scq, qk, fmaf(scr, qr, fmaf(sck, kr, shf)));
  }
  __syncthreads();
  // phase B: softmax along j (lanes)
  for (int t = 0; t < 16; ++t){
    int i = ty*16 + t;
    float xv = P[i][tx];
    float m = wave_max(xv);
    float e = __expf(xv - m);
    float s = wave_sum(e);
    P[i][tx] = e / s;
  }
  __syncthreads();
  // phase C: sv (ty 0..1) / sve (ty 2..3); lanes = i
  float out8[8];
  #pragma unroll
  for (int c = 0; c < 8; ++c) out8[c] = 0.f;
  const int i = tx;
  if (ty < 2){
    const int c0 = ty*8;
    for (int jj = 0; jj < 64; ++jj){
      float p = P[i][jj];
      #pragma unroll
      for (int cc = 0; cc < 8; ++cc) out8[cc] = fmaf(p, v[c0+cc][jj], out8[cc]);
    }
  } else {
    const int c0 = (ty-2)*8;
    for (int jj = 0; jj < 64; ++jj){
      float p = P[i][jj];
      #pragma unroll
      for (int cc = 0; cc < 8; ++cc)
        out8[cc] = fmaf(p, re[(16+c0+cc)*127 + (i - jj + 63)], out8[cc]);
    }
    #pragma unroll
    for (int cc = 0; cc < 8; ++cc) out8[cc] *= 0.1f;
  }
  const int chbase = (ty < 2) ? (g*16 + ty*8) : (128 + g*16 + (ty-2)*8);
  float* accb = accbo + (size_t)(b & (NCOPY-1)) * 512;
  #pragma unroll
  for (int cc = 0; cc < 8; ++cc){
    float val = out8[cc];
    svout[((size_t)b*256 + chbase + cc)*64 + i] = val;
    float s  = wave_sum(val);
    float s2 = wave_sum(val*val);
    if (tx == 0){ atomicAdd(&accb[chbase+cc], s); atomicAdd(&accb[256+chbase+cc], s2); }
  }
}

// ---------------------------------------------------------------------------
// bo-BN + pair-sum + transpose (h-axial -> w-axial input)
// ---------------------------------------------------------------------------
__global__ __launch_bounds__(256) void k_pairT(const float* __restrict__ sv,
    const float* __restrict__ bo, float* __restrict__ win)
{
  __shared__ float t[64][65];
  const int c = blockIdx.x, n = blockIdx.y;
  const int tx = threadIdx.x, ty = threadIdx.y;
  const float s0 = bo[2*c], s1 = bo[2*c+1];
  const float sh = bo[256 + 2*c] + bo[256 + 2*c + 1];
  const float* base = sv + (size_t)(n*64)*256*64;
  #pragma unroll
  for (int r = 0; r < 16; ++r){
    int w_ = ty + r*4;
    float v0 = base[((size_t)w_*256 + 2*c    )*64 + tx];
    float v1 = base[((size_t)w_*256 + 2*c + 1)*64 + tx];
    t[w_][tx] = fmaf(s0, v0, fmaf(s1, v1, sh));  // t[w][h]
  }
  __syncthreads();
  float* dst = win + (size_t)(n*64)*8192 + (size_t)c*64;
  #pragma unroll
  for (int r = 0; r < 16; ++r){
    int h_ = ty + r*4;
    dst[(size_t)h_*8192 + tx] = t[tx][h_];       // lanes = w
  }
}

// ---------------------------------------------------------------------------
// bo-BN + pair-sum, no transpose (w-axial -> natural NCHW)
// ---------------------------------------------------------------------------
__global__ __launch_bounds__(256) void k_pair_w(const float* __restrict__ sv,
    const float* __restrict__ bo, float* __restrict__ wbuf)
{
  const int m = blockIdx.x, n = blockIdx.y;
  const int tx = threadIdx.x, ty = threadIdx.y;
  const float s0 = bo[2*m], s1 = bo[2*m+1];
  const float sh = bo[256 + 2*m] + bo[256 + 2*m + 1];
  #pragma unroll
  for (int r = 0; r < 16; ++r){
    int h = ty + r*4;
    float v0 = sv[((size_t)(n*64+h)*256 + 2*m    )*64 + tx];
    float v1 = sv[((size_t)(n*64+h)*256 + 2*m + 1)*64 + tx];
    wbuf[((size_t)(n*128+m)*64 + h)*64 + tx] = fmaf(s0, v0, fmaf(s1, v1, sh));
  }
}

// ---------------------------------------------------------------------------
// final: out = bn2(y2) + c1_w . x + c1_b
// ---------------------------------------------------------------------------
__global__ __launch_bounds__(256) void k_final(const float* __restrict__ x,
    const float* __restrict__ w1, const float* __restrict__ b1,
    const float* __restrict__ y2, const float* __restrict__ scsh,
    float* __restrict__ out)
{
  __shared__ float xt[128][64];
  const int n = blockIdx.z, pt = blockIdx.x, ot = blockIdx.y;
  const int tx = threadIdx.x, ty = threadIdx.y;
  const int tid = ty*64 + tx;
  const int p0 = pt*64;
  const float* xb = x + (size_t)n*128*4096 + p0;
  #pragma unroll 4
  for (int r = 0; r < 32; ++r){
    int idx = tid + r*256;
    xt[idx>>6][idx&63] = xb[(size_t)(idx>>6)*4096 + (idx&63)];
  }
  __syncthreads();
  const int ob = __builtin_amdgcn_readfirstlane(ot*32 + ty*8);
  float a[8];
  #pragma unroll
  for (int j = 0; j < 8; ++j) a[j] = b1[ob+j];
  for (int c = 0; c < 128; ++c){
    float xv = xt[c][tx];
    #pragma unroll
    for (int j = 0; j < 8; ++j) a[j] = fmaf(w1[(ob+j)*128 + c], xv, a[j]);
  }
  #pragma unroll
  for (int j = 0; j < 8; ++j){
    size_t idx = ((size_t)n*256 + ob + j)*4096 + p0 + tx;
    out[idx] = a[j] + fmaf(scsh[ob+j], y2[idx], scsh[256+ob+j]);
  }
}

// ---------------------------------------------------------------------------

extern "C" void kernel_launch(void* const* d_in, const int* in_sizes, int n_in,
                              void* d_out, int out_size, void* d_ws, size_t ws_size,
                              hipStream_t stream)
{
  const float* x     = (const float*)d_in[0];
  const float* c1_w  = (const float*)d_in[1];
  const float* c1_b  = (const float*)d_in[2];
  const float* cd_w  = (const float*)d_in[3];
  const float* cd_b  = (const float*)d_in[4];
  const float* bn1_g = (const float*)d_in[5];
  const float* bn1_b = (const float*)d_in[6];
  const float* h_qkv = (const float*)d_in[7];
  const float* h_bqg = (const float*)d_in[8];
  const float* h_bqb = (const float*)d_in[9];
  const float* h_bsg = (const float*)d_in[10];
  const float* h_bsb = (const float*)d_in[11];
  const float* h_bog = (const float*)d_in[12];
  const float* h_bob = (const float*)d_in[13];
  const float* h_rel = (const float*)d_in[14];
  const float* w_qkv = (const float*)d_in[15];
  const float* w_bqg = (const float*)d_in[16];
  const float* w_bqb = (const float*)d_in[17];
  const float* w_bsg = (const float*)d_in[18];
  const float* w_bsb = (const float*)d_in[19];
  const float* w_bog = (const float*)d_in[20];
  const float* w_bob = (const float*)d_in[21];
  const float* w_rel = (const float*)d_in[22];
  const float* cu_w  = (const float*)d_in[23];
  const float* cu_b  = (const float*)d_in[24];
  const float* bn2_g = (const float*)d_in[25];
  const float* bn2_b = (const float*)d_in[26];
  float* out = (float*)d_out;
  char* ws = (char*)d_ws;

  // big buffers (aliased across dead stages), peak 160MB:
  float* OUT0 = (float*)(ws + 0);                    // 32MB (n,128,4096)
  float* HIN  = (float*)(ws + (32ull<<20));          // 32MB (1024,128,64)
  float* QKV  = (float*)(ws + (64ull<<20));          // 64MB (1024,256,64) h-phase
  float* SVO  = (float*)(ws + 0);                    // 64MB, after OUT0/HIN dead
  float* WIN  = (float*)(ws + (64ull<<20));          // 32MB, after QKV(h) dead
  float* QKVW = (float*)(ws + (96ull<<20));          // 64MB w-phase
  float* WBUF = (float*)(ws + (64ull<<20));          // 32MB, after WIN dead
  float* Y2   = (float*)(ws + (96ull<<20));          // 64MB, after QKVW dead
  float* ST   = (float*)(ws + (160ull<<20));         // stats region

  // NCOPY=64 spread accumulators (sizes in floats):
  float* ACC_BN1 = ST;             // 2*128*64 = 16384
  float* ACC_BQ  = ST + 16384;     // 2*256*64 = 32768
  float* ACC_SIM = ST + 49152;     // 2*24*64  = 3072
  float* ACC_BO  = ST + 52224;     // 32768
  float* ACC_BQW = ST + 84992;     // 32768
  float* ACC_SIMW= ST + 117760;    // 3072
  float* ACC_BOW = ST + 120832;    // 32768
  float* ACC_BN2 = ST + 153600;    // 32768  -> ACC total 186368 floats
  float* SCB     = ST + 186368;    // finalized scale/shift blocks
  float* SC_BN1 = SCB;        float* SC_BQ  = SCB + 256;
  float* SC_SIM = SCB + 768;  float* SC_BO  = SCB + 816;
  float* SC_BQW = SCB + 1328; float* SC_SIMW= SCB + 1840;
  float* SC_BOW = SCB + 1888; float* SC_BN2 = SCB + 2400;  // +512 -> 2912
  float* RWH  = ST + 189280;  // 9216 floats
  float* RWW  = ST + 198496;  // 9216 floats  (end: 207712 floats ~ 0.79MB)

  hipMemsetAsync(ST, 0, 186368*sizeof(float), stream);

  const dim3 blk(64,4);
  const float inv64k = 1.f/65536.f;
  const float invsim = 1.f/4194304.f;

  k_prep_rel<<<2, blk, 0, stream>>>(h_rel, RWH);
  k_prep_rel<<<2, blk, 0, stream>>>(w_rel, RWW);

  // cd conv + bn1 stats
  k_conv<<<dim3(64,4,16), blk, 0, stream>>>(x, cd_w, cd_b, OUT0, ACC_BN1, 128);
  k_finalize<<<1, 128, 0, stream>>>(ACC_BN1, bn1_g, bn1_b, SC_BN1, 128, inv64k);
  k_trans_bnrelu<<<dim3(128,16), blk, 0, stream>>>(OUT0, SC_BN1, HIN);

  // ---- h axial ----
  k_qkv<<<dim3(1024,4), blk, 0, stream>>>(HIN, h_qkv, QKV, ACC_BQ);
  k_finalize<<<1, 256, 0, stream>>>(ACC_BQ, h_bqg, h_bqb, SC_BQ, 256, inv64k);
  k_att_stats<<<1024, blk, 0, stream>>>(QKV, SC_BQ, RWH, ACC_SIM);
  k_finalize<<<1, 32, 0, stream>>>(ACC_SIM, h_bsg, h_bsb, SC_SIM, 24, invsim);
  k_att2<<<dim3(1024,8), blk, 0, stream>>>(QKV, SC_BQ, h_rel, SC_SIM, SVO, ACC_BO);
  k_finalize<<<1, 256, 0, stream>>>(ACC_BO, h_bog, h_bob, SC_BO, 256, inv64k);
  k_pairT<<<dim3(128,16), blk, 0, stream>>>(SVO, SC_BO, WIN);

  // ---- w axial ----
  k_qkv<<<dim3(1024,4), blk, 0, stream>>>(WIN, w_qkv, QKVW, ACC_BQW);
  k_finalize<<<1, 256, 0, stream>>>(ACC_BQW, w_bqg, w_bqb, SC_BQW, 256, inv64k);
  k_att_stats<<<1024, blk, 0, stream>>>(QKVW, SC_BQW, RWW, ACC_SIMW);
  k_finalize<<<1, 32, 0, stream>>>(ACC_SIMW, w_bsg, w_bsb, SC_SIMW, 24, invsim);
  k_att2<<<dim3(1024,8), blk, 0, stream>>>(QKVW, SC_BQW, w_rel, SC_SIMW, SVO, ACC_BOW);
  k_finalize<<<1, 256, 0, stream>>>(ACC_BOW, w_bog, w_bob, SC_BOW, 256, inv64k);
  k_pair_w<<<dim3(128,16), blk, 0, stream>>>(SVO, SC_BOW, WBUF);

  // cu conv + bn2 stats, then fused residual + c1 conv
  k_conv<<<dim3(64,8,16), blk, 0, stream>>>(WBUF, cu_w, cu_b, Y2, ACC_BN2, 256);
  k_finalize<<<1, 256, 0, stream>>>(ACC_BN2, bn2_g, bn2_b, SC_BN2, 256, inv64k);
  k_final<<<dim3(64,8,16), blk, 0, stream>>>(x, c1_w, c1_b, Y2, SC_BN2, out);
}

// Round 3
// 990.295 us; speedup vs baseline: 5.2735x; 1.9292x over previous
//
#include <hip/hip_runtime.h>

// ---------------------------------------------------------------------------
// AxialBlock fused implementation. Round 3: MFMA bf16 for all 5 GEMMs.
// NB=16, CIN=128, COUT=256, MID=128, G=8, GP=16, K=64
// ---------------------------------------------------------------------------

#define NCOPY 64

typedef __attribute__((ext_vector_type(8))) short bf16x8;
typedef __attribute__((ext_vector_type(4))) float f32x4;

__device__ __forceinline__ float wave_sum(float v){
  #pragma unroll
  for (int o = 32; o; o >>= 1) v += __shfl_xor(v, o, 64);
  return v;
}
__device__ __forceinline__ float wave_max(float v){
  #pragma unroll
  for (int o = 32; o; o >>= 1) v = fmaxf(v, __shfl_xor(v, o, 64));
  return v;
}
__device__ __forceinline__ ushort f2bf(float f){
  union { float f; unsigned u; } v; v.f = f;
  unsigned r = v.u + 0x7FFFu + ((v.u >> 16) & 1u);   // round-to-nearest-even
  return (ushort)(r >> 16);
}

// ---------------------------------------------------------------------------
// weight fp32 -> bf16 conversion
// ---------------------------------------------------------------------------
__global__ void k_cvt(const float* __restrict__ src, ushort* __restrict__ dst, int n){
  int i = blockIdx.x*256 + threadIdx.x;
  if (i < n) dst[i] = f2bf(src[i]);
}

// ---------------------------------------------------------------------------
// MFMA GEMM: out[o][col] = sum_c Wb[o][c] * X[c][col]  (+ epilogue per MODE)
// X fp32, addr = seg*(128<<SLOG) + c<<SLOG + (col & mask), seg = col>>SLOG.
// MODE 0: + bias, write, stats.  MODE 1: write, stats.  MODE 2: + bias +
// scsh[m]*y2+scsh[O+m] residual, write, no stats.
// grid: 1024 (64-col tiles); block: 256 thr (4 waves); wave rows = O/4.
// ---------------------------------------------------------------------------
template<int O, int MODE, int SLOG>
__global__ __launch_bounds__(256) void k_gemm(
    const float* __restrict__ X, const ushort* __restrict__ Wb,
    const float* __restrict__ bias, float* __restrict__ out,
    float* __restrict__ acc, const float* __restrict__ y2,
    const float* __restrict__ scsh)
{
  constexpr int RPW = O/4;       // rows per wave
  constexpr int NS  = RPW/16;    // 16-row subtiles per wave
  __shared__ ushort XT[64*128];  // [col][k] bf16, chunk-XOR swizzled

  const int tid = threadIdx.x;
  const int col0 = blockIdx.x << 6;
  const int seg  = col0 >> SLOG;
  const int p0   = col0 & ((1<<SLOG)-1);

  // ---- stage X tile (128c x 64col) -> bf16 transposed+swizzled ----
  {
    const int col = tid & 63;
    const int kc8 = tid >> 6;                  // 0..3
    const float* xb = X + (((size_t)seg*128) << SLOG) + p0 + col;
    #pragma unroll
    for (int q = 0; q < 4; ++q){
      int kc = kc8*4 + q;                      // k-chunk 0..15 (8 c's each)
      int c0 = kc*8;
      bf16x8 pk;
      #pragma unroll
      for (int j = 0; j < 8; ++j)
        pk[j] = (short)f2bf(xb[(size_t)(c0+j) << SLOG]);
      *(bf16x8*)&XT[col*128 + ((kc ^ (col & 15)) << 3)] = pk;
    }
  }
  __syncthreads();

  const int lane = tid & 63;
  const int wid  = tid >> 6;
  const int l15  = lane & 15, lg = lane >> 4;

  f32x4 accr[NS][4];
  #pragma unroll
  for (int s = 0; s < NS; ++s)
    #pragma unroll
    for (int ns = 0; ns < 4; ++ns)
      accr[s][ns] = (f32x4){0.f,0.f,0.f,0.f};

  #pragma unroll
  for (int kk = 0; kk < 4; ++kk){
    bf16x8 af[NS];
    #pragma unroll
    for (int s = 0; s < NS; ++s){
      int m = wid*RPW + s*16 + l15;
      af[s] = *(const bf16x8*)(Wb + (size_t)m*128 + kk*32 + lg*8);
    }
    bf16x8 bfr[4];
    #pragma unroll
    for (int ns = 0; ns < 4; ++ns){
      int ncol  = ns*16 + l15;
      int chunk = kk*4 + lg;
      bfr[ns] = *(const bf16x8*)&XT[ncol*128 + ((chunk ^ l15) << 3)];
    }
    #pragma unroll
    for (int s = 0; s < NS; ++s)
      #pragma unroll
      for (int ns = 0; ns < 4; ++ns)
        accr[s][ns] = __builtin_amdgcn_mfma_f32_16x16x32_bf16(
                        af[s], bfr[ns], accr[s][ns], 0, 0, 0);
  }

  // ---- epilogue ----
  float* accb = (MODE != 2) ? acc + (size_t)(blockIdx.x & (NCOPY-1))*2*O : nullptr;
  #pragma unroll
  for (int s = 0; s < NS; ++s){
    #pragma unroll
    for (int r = 0; r < 4; ++r){
      const int m = wid*RPW + s*16 + lg*4 + r;
      const float bs = (MODE != 1) ? bias[m] : 0.f;
      float vsum = 0.f, vsq = 0.f;
      #pragma unroll
      for (int ns = 0; ns < 4; ++ns){
        float v = accr[s][ns][r] + bs;
        size_t oidx = (((size_t)seg*O + m) << SLOG) + p0 + ns*16 + l15;
        if (MODE == 2)
          v += fmaf(scsh[m], y2[oidx], scsh[O+m]);
        out[oidx] = v;
        vsum += v; vsq = fmaf(v, v, vsq);
      }
      if (MODE != 2){
        #pragma unroll
        for (int o2 = 1; o2 < 16; o2 <<= 1){
          vsum += __shfl_xor(vsum, o2, 64);
          vsq  += __shfl_xor(vsq , o2, 64);
        }
        if (l15 == 0){
          atomicAdd(&accb[m],   vsum);
          atomicAdd(&accb[O+m], vsq);
        }
      }
    }
  }
}

// ---------------------------------------------------------------------------
// BN finalize: sum NCOPY copies; scsh[c]=g*rstd ; scsh[C+c]=b-mean*scale
// ---------------------------------------------------------------------------
__global__ void k_finalize(const float* __restrict__ acc, const float* __restrict__ g,
    const float* __restrict__ b, float* __restrict__ scsh, int C, float invcnt)
{
  int c = blockIdx.x*blockDim.x + threadIdx.x;
  if (c >= C) return;
  float s = 0.f, s2 = 0.f;
  #pragma unroll 4
  for (int k2 = 0; k2 < NCOPY; ++k2){
    s  += acc[(size_t)k2*2*C + c];
    s2 += acc[(size_t)k2*2*C + C + c];
  }
  float mean = s*invcnt;
  float var  = s2*invcnt - mean*mean;
  float sc = g[c]*rsqrtf(var + 1e-5f);
  scsh[c]   = sc;
  scsh[C+c] = fmaf(-mean, sc, b[c]);
}

// ---------------------------------------------------------------------------
// bn1+relu + transpose: hin[(n*64+w)*8192 + c*64 + h] = relu(bn(out0[n][c][h][w]))
// ---------------------------------------------------------------------------
__global__ __launch_bounds__(256) void k_trans_bnrelu(const float* __restrict__ out0,
    const float* __restrict__ scsh, float* __restrict__ hin)
{
  __shared__ float t[64][65];
  const int c = blockIdx.x, n = blockIdx.y;
  const int tx = threadIdx.x, ty = threadIdx.y;
  const float sc = scsh[c], sh = scsh[128+c];
  const float* src = out0 + ((size_t)n*128 + c)*4096;
  #pragma unroll
  for (int r = 0; r < 16; ++r){
    int h = ty + r*4;
    t[h][tx] = src[h*64 + tx];
  }
  __syncthreads();
  float* dst = hin + (size_t)(n*64)*8192 + (size_t)c*64;
  #pragma unroll
  for (int r = 0; r < 16; ++r){
    int w_ = ty + r*4;
    float vv = fmaf(sc, t[tx][w_], sh);
    dst[(size_t)w_*8192 + tx] = fmaxf(vv, 0.f);
  }
}

// ---------------------------------------------------------------------------
// rel windowed sums/correlations for sim-BN stats
// ---------------------------------------------------------------------------
__global__ __launch_bounds__(256) void k_prep_rel(const float* __restrict__ rel,
                                                  float* __restrict__ rw)
{
  const int side = blockIdx.x;
  const float* base = rel + side*8*127;
  float* Wout = rw + side*4096;
  float* Sout = rw + 8192 + side*512;
  const int tid = threadIdx.y*64 + threadIdx.x;
  for (int idx = tid; idx < 4096; idx += 256){
    int pr = idx >> 6, i = idx & 63;
    int c = pr >> 3, c2 = pr & 7;
    const float* r1 = base + c*127 + i;
    const float* r2 = base + c2*127 + i;
    float s = 0.f;
    #pragma unroll 8
    for (int u = 0; u < 64; ++u) s = fmaf(r1[u], r2[u], s);
    Wout[idx] = s;
  }
  for (int idx = tid; idx < 512; idx += 256){
    int c = idx >> 6, i = idx & 63;
    const float* r1 = base + c*127 + i;
    float s = 0.f;
    #pragma unroll 8
    for (int u = 0; u < 64; ++u) s += r1[u];
    Sout[idx] = s;
  }
}

// ---------------------------------------------------------------------------
// sim-BN stats per (b,g) via Gram factorization. grid (1024), block (64,4)
// ---------------------------------------------------------------------------
__global__ __launch_bounds__(256) void k_att_stats(const float* __restrict__ qkv,
    const float* __restrict__ bq, const float* __restrict__ rw, float* __restrict__ accsim)
{
  __shared__ float WqS[4096], WkS[4096], SqS[512], SkS[512];
  const int b = blockIdx.x;
  const int tx = threadIdx.x, ty = threadIdx.y;
  const int tid = ty*64 + tx;
  for (int idx = tid; idx < 4096; idx += 256){ WqS[idx] = rw[idx]; WkS[idx] = rw[4096+idx]; }
  for (int idx = tid; idx < 512;  idx += 256){ SqS[idx] = rw[8192+idx]; SkS[idx] = rw[8704+idx]; }
  __syncthreads();
  float* accb = accsim + (size_t)(b & (NCOPY-1)) * 48;
  const int i = tx;
  for (int gi = 0; gi < 2; ++gi){
    int g = ty*2 + gi;
    float q[8], k[8];
    #pragma unroll
    for (int c = 0; c < 8; ++c){
      int oq = g*32 + c, ok = oq + 8;
      q[c] = fmaf(bq[oq], qkv[((size_t)b*256 + oq)*64 + i], bq[256+oq]);
      k[c] = fmaf(bq[ok], qkv[((size_t)b*256 + ok)*64 + i], bq[256+ok]);
    }
    float qs[8], ks[8];
    #pragma unroll
    for (int c = 0; c < 8; ++c){ qs[c] = wave_sum(q[c]); ks[c] = wave_sum(k[c]); }
    float sum_qk = 0.f;
    #pragma unroll
    for (int c = 0; c < 8; ++c) sum_qk = fmaf(qs[c], ks[c], sum_qk);
    float ss_qk = 0.f;
    #pragma unroll
    for (int c = 0; c < 8; ++c){
      #pragma unroll
      for (int c2 = 0; c2 < 8; ++c2){
        float gq = wave_sum(q[c]*q[c2]);
        float gk = wave_sum(k[c]*k[c2]);
        ss_qk = fmaf(gq, gk, ss_qk);
      }
    }
    float tq = 0.f, tk = 0.f, tq2 = 0.f, tk2 = 0.f;
    #pragma unroll
    for (int c = 0; c < 8; ++c){
      tq = fmaf(q[c], SqS[c*64 + i], tq);
      tk = fmaf(k[c], SkS[c*64 + i], tk);
    }
    #pragma unroll
    for (int c = 0; c < 8; ++c){
      #pragma unroll
      for (int c2 = 0; c2 < 8; ++c2){
        tq2 = fmaf(q[c]*q[c2], WqS[(c*8+c2)*64 + i], tq2);
        tk2 = fmaf(k[c]*k[c2], WkS[(c*8+c2)*64 + i], tk2);
      }
    }
    float sum_qr = 0.1f  * wave_sum(tq);
    float ss_qr  = 0.01f * wave_sum(tq2);
    float sum_kr = 0.1f  * wave_sum(tk);
    float ss_kr  = 0.01f * wave_sum(tk2);
    if (tx == 0){
      atomicAdd(&accb[g],      sum_qk); atomicAdd(&accb[24+g],    ss_qk);
      atomicAdd(&accb[8+g],    sum_qr); atomicAdd(&accb[24+8+g],  ss_qr);
      atomicAdd(&accb[16+g],   sum_kr); atomicAdd(&accb[24+16+g], ss_kr);
    }
  }
}

// ---------------------------------------------------------------------------
// attention pass 2: logits -> BN-combine -> softmax -> sv/sve
// grid (1024 b, 8 g), block (64,4)
// ---------------------------------------------------------------------------
__global__ __launch_bounds__(256) void k_att2(const float* __restrict__ qkv,
    const float* __restrict__ bq, const float* __restrict__ rel,
    const float* __restrict__ simsc, float* __restrict__ svout, float* __restrict__ accbo)
{
  __shared__ float q[8][64];
  __shared__ float v[16][64];
  __shared__ float re[4064];
  __shared__ float P[64][65];
  const int b = blockIdx.x, g = blockIdx.y;
  const int tx = threadIdx.x, ty = threadIdx.y;
  const int tid = ty*64 + tx;
  #pragma unroll
  for (int r = 0; r < 2; ++r){
    int u = ty + r*4;
    int o = g*32 + u;
    q[u][tx] = fmaf(bq[o], qkv[((size_t)b*256 + o)*64 + tx], bq[256+o]);
  }
  #pragma unroll
  for (int r = 0; r < 4; ++r){
    int u = ty + r*4;
    int o = g*32 + 16 + u;
    v[u][tx] = fmaf(bq[o], qkv[((size_t)b*256 + o)*64 + tx], bq[256+o]);
  }
  for (int idx = tid; idx < 4064; idx += 256) re[idx] = rel[idx];
  float kreg[8];
  #pragma unroll
  for (int c = 0; c < 8; ++c){
    int o = g*32 + 8 + c;
    kreg[c] = fmaf(bq[o], qkv[((size_t)b*256 + o)*64 + tx], bq[256+o]);
  }
  __syncthreads();
  const float scq = simsc[g], scr = 0.1f*simsc[8+g], sck = 0.1f*simsc[16+g];
  const float shf = simsc[24+g] + simsc[24+8+g] + simsc[24+16+g];
  for (int t = 0; t < 16; ++t){
    int i = ty + 4*t;
    float qk = 0.f, qr = 0.f, kr = 0.f;
    #pragma unroll
    for (int c = 0; c < 8; ++c){
      float qv = q[c][i];
      qk = fmaf(qv, kreg[c], qk);
      qr = fmaf(qv, re[c*127 + (i - tx + 63)], qr);
      kr = fmaf(kreg[c], re[(8+c)*127 + (tx - i + 63)], kr);
    }
    P[i][tx] = fmaf(scq, qk, fmaf(scr, qr, fmaf(sck, kr, shf)));
  }
  __syncthreads();
  for (int t = 0; t < 16; ++t){
    int i = ty*16 + t;
    float xv = P[i][tx];
    float m = wave_max(xv);
    float e = __expf(xv - m);
    float s = wave_sum(e);
    P[i][tx] = e / s;
  }
  __syncthreads();
  float out8[8];
  #pragma unroll
  for (int c = 0; c < 8; ++c) out8[c] = 0.f;
  const int i = tx;
  if (ty < 2){
    const int c0 = ty*8;
    for (int jj = 0; jj < 64; ++jj){
      float p = P[i][jj];
      #pragma unroll
      for (int cc = 0; cc < 8; ++cc) out8[cc] = fmaf(p, v[c0+cc][jj], out8[cc]);
    }
  } else {
    const int c0 = (ty-2)*8;
    for (int jj = 0; jj < 64; ++jj){
      float p = P[i][jj];
      #pragma unroll
      for (int cc = 0; cc < 8; ++cc)
        out8[cc] = fmaf(p, re[(16+c0+cc)*127 + (i - jj + 63)], out8[cc]);
    }
    #pragma unroll
    for (int cc = 0; cc < 8; ++cc) out8[cc] *= 0.1f;
  }
  const int chbase = (ty < 2) ? (g*16 + ty*8) : (128 + g*16 + (ty-2)*8);
  float* accb = accbo + (size_t)(b & (NCOPY-1)) * 512;
  #pragma unroll
  for (int cc = 0; cc < 8; ++cc){
    float val = out8[cc];
    svout[((size_t)b*256 + chbase + cc)*64 + i] = val;
    float s  = wave_sum(val);
    float s2 = wave_sum(val*val);
    if (tx == 0){ atomicAdd(&accb[chbase+cc], s); atomicAdd(&accb[256+chbase+cc], s2); }
  }
}

// ---------------------------------------------------------------------------
// bo-BN + pair-sum + transpose (h-axial -> w-axial input)
// ---------------------------------------------------------------------------
__global__ __launch_bounds__(256) void k_pairT(const float* __restrict__ sv,
    const float* __restrict__ bo, float* __restrict__ win)
{
  __shared__ float t[64][65];
  const int c = blockIdx.x, n = blockIdx.y;
  const int tx = threadIdx.x, ty = threadIdx.y;
  const float s0 = bo[2*c], s1 = bo[2*c+1];
  const float sh = bo[256 + 2*c] + bo[256 + 2*c + 1];
  const float* base = sv + (size_t)(n*64)*256*64;
  #pragma unroll
  for (int r = 0; r < 16; ++r){
    int w_ = ty + r*4;
    float v0 = base[((size_t)w_*256 + 2*c    )*64 + tx];
    float v1 = base[((size_t)w_*256 + 2*c + 1)*64 + tx];
    t[w_][tx] = fmaf(s0, v0, fmaf(s1, v1, sh));
  }
  __syncthreads();
  float* dst = win + (size_t)(n*64)*8192 + (size_t)c*64;
  #pragma unroll
  for (int r = 0; r < 16; ++r){
    int h_ = ty + r*4;
    dst[(size_t)h_*8192 + tx] = t[tx][h_];
  }
}

// ---------------------------------------------------------------------------
// bo-BN + pair-sum, no transpose (w-axial -> natural NCHW)
// ---------------------------------------------------------------------------
__global__ __launch_bounds__(256) void k_pair_w(const float* __restrict__ sv,
    const float* __restrict__ bo, float* __restrict__ wbuf)
{
  const int m = blockIdx.x, n = blockIdx.y;
  const int tx = threadIdx.x, ty = threadIdx.y;
  const float s0 = bo[2*m], s1 = bo[2*m+1];
  const float sh = bo[256 + 2*m] + bo[256 + 2*m + 1];
  #pragma unroll
  for (int r = 0; r < 16; ++r){
    int h = ty + r*4;
    float v0 = sv[((size_t)(n*64+h)*256 + 2*m    )*64 + tx];
    float v1 = sv[((size_t)(n*64+h)*256 + 2*m + 1)*64 + tx];
    wbuf[((size_t)(n*128+m)*64 + h)*64 + tx] = fmaf(s0, v0, fmaf(s1, v1, sh));
  }
}

// ---------------------------------------------------------------------------

extern "C" void kernel_launch(void* const* d_in, const int* in_sizes, int n_in,
                              void* d_out, int out_size, void* d_ws, size_t ws_size,
                              hipStream_t stream)
{
  const float* x     = (const float*)d_in[0];
  const float* c1_w  = (const float*)d_in[1];
  const float* c1_b  = (const float*)d_in[2];
  const float* cd_w  = (const float*)d_in[3];
  const float* cd_b  = (const float*)d_in[4];
  const float* bn1_g = (const float*)d_in[5];
  const float* bn1_b = (const float*)d_in[6];
  const float* h_qkv = (const float*)d_in[7];
  const float* h_bqg = (const float*)d_in[8];
  const float* h_bqb = (const float*)d_in[9];
  const float* h_bsg = (const float*)d_in[10];
  const float* h_bsb = (const float*)d_in[11];
  const float* h_bog = (const float*)d_in[12];
  const float* h_bob = (const float*)d_in[13];
  const float* h_rel = (const float*)d_in[14];
  const float* w_qkv = (const float*)d_in[15];
  const float* w_bqg = (const float*)d_in[16];
  const float* w_bqb = (const float*)d_in[17];
  const float* w_bsg = (const float*)d_in[18];
  const float* w_bsb = (const float*)d_in[19];
  const float* w_bog = (const float*)d_in[20];
  const float* w_bob = (const float*)d_in[21];
  const float* w_rel = (const float*)d_in[22];
  const float* cu_w  = (const float*)d_in[23];
  const float* cu_b  = (const float*)d_in[24];
  const float* bn2_g = (const float*)d_in[25];
  const float* bn2_b = (const float*)d_in[26];
  float* out = (float*)d_out;
  char* ws = (char*)d_ws;

  // big buffers (aliased across dead stages), peak 160MB:
  float* OUT0 = (float*)(ws + 0);                    // 32MB (n,128,4096)
  float* HIN  = (float*)(ws + (32ull<<20));          // 32MB (1024,128,64)
  float* QKV  = (float*)(ws + (64ull<<20));          // 64MB (1024,256,64) h-phase
  float* SVO  = (float*)(ws + 0);                    // 64MB, after OUT0/HIN dead
  float* WIN  = (float*)(ws + (64ull<<20));          // 32MB, after QKV(h) dead
  float* QKVW = (float*)(ws + (96ull<<20));          // 64MB w-phase
  float* WBUF = (float*)(ws + (64ull<<20));          // 32MB, after WIN dead
  float* Y2   = (float*)(ws + (96ull<<20));          // 64MB, after QKVW dead
  float* ST   = (float*)(ws + (160ull<<20));         // stats region

  // NCOPY=64 spread accumulators (sizes in floats):
  float* ACC_BN1 = ST;             // 2*128*64 = 16384
  float* ACC_BQ  = ST + 16384;     // 2*256*64 = 32768
  float* ACC_SIM = ST + 49152;     // 2*24*64  = 3072
  float* ACC_BO  = ST + 52224;     // 32768
  float* ACC_BQW = ST + 84992;     // 32768
  float* ACC_SIMW= ST + 117760;    // 3072
  float* ACC_BOW = ST + 120832;    // 32768
  float* ACC_BN2 = ST + 153600;    // 32768  -> ACC total 186368 floats
  float* SCB     = ST + 186368;
  float* SC_BN1 = SCB;        float* SC_BQ  = SCB + 256;
  float* SC_SIM = SCB + 768;  float* SC_BO  = SCB + 816;
  float* SC_BQW = SCB + 1328; float* SC_SIMW= SCB + 1840;
  float* SC_BOW = SCB + 1888; float* SC_BN2 = SCB + 2400;  // -> 2912
  float* RWH  = ST + 189280;  // 9216 floats
  float* RWW  = ST + 198496;  // 9216 floats (end 207712)
  // bf16 weights:
  ushort* CDBF = (ushort*)(ST + 207712);   // 16384
  ushort* QHBF = CDBF + 16384;             // 32768
  ushort* QWBF = CDBF + 49152;             // 32768
  ushort* CUBF = CDBF + 81920;             // 32768
  ushort* C1BF = CDBF + 114688;            // 32768 (end 147456 ushorts)

  hipMemsetAsync(ST, 0, 186368*sizeof(float), stream);

  const dim3 blk(64,4);
  const float inv64k = 1.f/65536.f;
  const float invsim = 1.f/4194304.f;

  // weight conversions + rel prep
  k_cvt<<<64, 256, 0, stream>>>(cd_w, CDBF, 16384);
  k_cvt<<<128, 256, 0, stream>>>(h_qkv, QHBF, 32768);
  k_cvt<<<128, 256, 0, stream>>>(w_qkv, QWBF, 32768);
  k_cvt<<<128, 256, 0, stream>>>(cu_w, CUBF, 32768);
  k_cvt<<<128, 256, 0, stream>>>(c1_w, C1BF, 32768);
  k_prep_rel<<<2, blk, 0, stream>>>(h_rel, RWH);
  k_prep_rel<<<2, blk, 0, stream>>>(w_rel, RWW);

  // cd conv + bn1 stats
  k_gemm<128,0,12><<<1024, 256, 0, stream>>>(x, CDBF, cd_b, OUT0, ACC_BN1, nullptr, nullptr);
  k_finalize<<<1, 128, 0, stream>>>(ACC_BN1, bn1_g, bn1_b, SC_BN1, 128, inv64k);
  k_trans_bnrelu<<<dim3(128,16), blk, 0, stream>>>(OUT0, SC_BN1, HIN);

  // ---- h axial ----
  k_gemm<256,1,6><<<1024, 256, 0, stream>>>(HIN, QHBF, nullptr, QKV, ACC_BQ, nullptr, nullptr);
  k_finalize<<<1, 256, 0, stream>>>(ACC_BQ, h_bqg, h_bqb, SC_BQ, 256, inv64k);
  k_att_stats<<<1024, blk, 0, stream>>>(QKV, SC_BQ, RWH, ACC_SIM);
  k_finalize<<<1, 32, 0, stream>>>(ACC_SIM, h_bsg, h_bsb, SC_SIM, 24, invsim);
  k_att2<<<dim3(1024,8), blk, 0, stream>>>(QKV, SC_BQ, h_rel, SC_SIM, SVO, ACC_BO);
  k_finalize<<<1, 256, 0, stream>>>(ACC_BO, h_bog, h_bob, SC_BO, 256, inv64k);
  k_pairT<<<dim3(128,16), blk, 0, stream>>>(SVO, SC_BO, WIN);

  // ---- w axial ----
  k_gemm<256,1,6><<<1024, 256, 0, stream>>>(WIN, QWBF, nullptr, QKVW, ACC_BQW, nullptr, nullptr);
  k_finalize<<<1, 256, 0, stream>>>(ACC_BQW, w_bqg, w_bqb, SC_BQW, 256, inv64k);
  k_att_stats<<<1024, blk, 0, stream>>>(QKVW, SC_BQW, RWW, ACC_SIMW);
  k_finalize<<<1, 32, 0, stream>>>(ACC_SIMW, w_bsg, w_bsb, SC_SIMW, 24, invsim);
  k_att2<<<dim3(1024,8), blk, 0, stream>>>(QKVW, SC_BQW, w_rel, SC_SIMW, SVO, ACC_BOW);
  k_finalize<<<1, 256, 0, stream>>>(ACC_BOW, w_bog, w_bob, SC_BOW, 256, inv64k);
  k_pair_w<<<dim3(128,16), blk, 0, stream>>>(SVO, SC_BOW, WBUF);

  // cu conv + bn2 stats, then fused residual + c1 conv
  k_gemm<256,0,12><<<1024, 256, 0, stream>>>(WBUF, CUBF, cu_b, Y2, ACC_BN2, nullptr, nullptr);
  k_finalize<<<1, 256, 0, stream>>>(ACC_BN2, bn2_g, bn2_b, SC_BN2, 256, inv64k);
  k_gemm<256,2,12><<<1024, 256, 0, stream>>>(x, C1BF, c1_b, out, nullptr, Y2, SC_BN2);
}

// Round 4
// 900.509 us; speedup vs baseline: 5.7993x; 1.0997x over previous
//
#include <hip/hip_runtime.h>

// ---------------------------------------------------------------------------
// AxialBlock fused implementation. Round 4: restructured k_att2 (group-wise
// softmax reduce, folded BN scales, transposed V, deferred normalize).
// NB=16, CIN=128, COUT=256, MID=128, G=8, GP=16, K=64
// ---------------------------------------------------------------------------

#define NCOPY 64

typedef __attribute__((ext_vector_type(8))) short bf16x8;
typedef __attribute__((ext_vector_type(4))) float f32x4;

__device__ __forceinline__ float wave_sum(float v){
  #pragma unroll
  for (int o = 32; o; o >>= 1) v += __shfl_xor(v, o, 64);
  return v;
}
__device__ __forceinline__ ushort f2bf(float f){
  union { float f; unsigned u; } v; v.f = f;
  unsigned r = v.u + 0x7FFFu + ((v.u >> 16) & 1u);   // round-to-nearest-even
  return (ushort)(r >> 16);
}

// ---------------------------------------------------------------------------
// weight fp32 -> bf16 conversion
// ---------------------------------------------------------------------------
__global__ void k_cvt(const float* __restrict__ src, ushort* __restrict__ dst, int n){
  int i = blockIdx.x*256 + threadIdx.x;
  if (i < n) dst[i] = f2bf(src[i]);
}

// ---------------------------------------------------------------------------
// MFMA GEMM: out[o][col] = sum_c Wb[o][c] * X[c][col]  (+ epilogue per MODE)
// MODE 0: + bias, write, stats.  MODE 1: write, stats.  MODE 2: + bias +
// scsh residual, write, no stats.
// ---------------------------------------------------------------------------
template<int O, int MODE, int SLOG>
__global__ __launch_bounds__(256) void k_gemm(
    const float* __restrict__ X, const ushort* __restrict__ Wb,
    const float* __restrict__ bias, float* __restrict__ out,
    float* __restrict__ acc, const float* __restrict__ y2,
    const float* __restrict__ scsh)
{
  constexpr int RPW = O/4;       // rows per wave
  constexpr int NS  = RPW/16;    // 16-row subtiles per wave
  __shared__ ushort XT[64*128];  // [col][k] bf16, chunk-XOR swizzled

  const int tid = threadIdx.x;
  const int col0 = blockIdx.x << 6;
  const int seg  = col0 >> SLOG;
  const int p0   = col0 & ((1<<SLOG)-1);

  // ---- stage X tile (128c x 64col) -> bf16 transposed+swizzled ----
  {
    const int col = tid & 63;
    const int kc8 = tid >> 6;                  // 0..3
    const float* xb = X + (((size_t)seg*128) << SLOG) + p0 + col;
    #pragma unroll
    for (int q = 0; q < 4; ++q){
      int kc = kc8*4 + q;                      // k-chunk 0..15 (8 c's each)
      int c0 = kc*8;
      bf16x8 pk;
      #pragma unroll
      for (int j = 0; j < 8; ++j)
        pk[j] = (short)f2bf(xb[(size_t)(c0+j) << SLOG]);
      *(bf16x8*)&XT[col*128 + ((kc ^ (col & 15)) << 3)] = pk;
    }
  }
  __syncthreads();

  const int lane = tid & 63;
  const int wid  = tid >> 6;
  const int l15  = lane & 15, lg = lane >> 4;

  f32x4 accr[NS][4];
  #pragma unroll
  for (int s = 0; s < NS; ++s)
    #pragma unroll
    for (int ns = 0; ns < 4; ++ns)
      accr[s][ns] = (f32x4){0.f,0.f,0.f,0.f};

  #pragma unroll
  for (int kk = 0; kk < 4; ++kk){
    bf16x8 af[NS];
    #pragma unroll
    for (int s = 0; s < NS; ++s){
      int m = wid*RPW + s*16 + l15;
      af[s] = *(const bf16x8*)(Wb + (size_t)m*128 + kk*32 + lg*8);
    }
    bf16x8 bfr[4];
    #pragma unroll
    for (int ns = 0; ns < 4; ++ns){
      int ncol  = ns*16 + l15;
      int chunk = kk*4 + lg;
      bfr[ns] = *(const bf16x8*)&XT[ncol*128 + ((chunk ^ l15) << 3)];
    }
    #pragma unroll
    for (int s = 0; s < NS; ++s)
      #pragma unroll
      for (int ns = 0; ns < 4; ++ns)
        accr[s][ns] = __builtin_amdgcn_mfma_f32_16x16x32_bf16(
                        af[s], bfr[ns], accr[s][ns], 0, 0, 0);
  }

  // ---- epilogue ----
  float* accb = (MODE != 2) ? acc + (size_t)(blockIdx.x & (NCOPY-1))*2*O : nullptr;
  #pragma unroll
  for (int s = 0; s < NS; ++s){
    #pragma unroll
    for (int r = 0; r < 4; ++r){
      const int m = wid*RPW + s*16 + lg*4 + r;
      const float bs = (MODE != 1) ? bias[m] : 0.f;
      float vsum = 0.f, vsq = 0.f;
      #pragma unroll
      for (int ns = 0; ns < 4; ++ns){
        float v = accr[s][ns][r] + bs;
        size_t oidx = (((size_t)seg*O + m) << SLOG) + p0 + ns*16 + l15;
        if (MODE == 2)
          v += fmaf(scsh[m], y2[oidx], scsh[O+m]);
        out[oidx] = v;
        vsum += v; vsq = fmaf(v, v, vsq);
      }
      if (MODE != 2){
        #pragma unroll
        for (int o2 = 1; o2 < 16; o2 <<= 1){
          vsum += __shfl_xor(vsum, o2, 64);
          vsq  += __shfl_xor(vsq , o2, 64);
        }
        if (l15 == 0){
          atomicAdd(&accb[m],   vsum);
          atomicAdd(&accb[O+m], vsq);
        }
      }
    }
  }
}

// ---------------------------------------------------------------------------
// BN finalize: sum NCOPY copies; scsh[c]=g*rstd ; scsh[C+c]=b-mean*scale
// ---------------------------------------------------------------------------
__global__ void k_finalize(const float* __restrict__ acc, const float* __restrict__ g,
    const float* __restrict__ b, float* __restrict__ scsh, int C, float invcnt)
{
  int c = blockIdx.x*blockDim.x + threadIdx.x;
  if (c >= C) return;
  float s = 0.f, s2 = 0.f;
  #pragma unroll 4
  for (int k2 = 0; k2 < NCOPY; ++k2){
    s  += acc[(size_t)k2*2*C + c];
    s2 += acc[(size_t)k2*2*C + C + c];
  }
  float mean = s*invcnt;
  float var  = s2*invcnt - mean*mean;
  float sc = g[c]*rsqrtf(var + 1e-5f);
  scsh[c]   = sc;
  scsh[C+c] = fmaf(-mean, sc, b[c]);
}

// ---------------------------------------------------------------------------
// bn1+relu + transpose: hin[(n*64+w)*8192 + c*64 + h] = relu(bn(out0[n][c][h][w]))
// ---------------------------------------------------------------------------
__global__ __launch_bounds__(256) void k_trans_bnrelu(const float* __restrict__ out0,
    const float* __restrict__ scsh, float* __restrict__ hin)
{
  __shared__ float t[64][65];
  const int c = blockIdx.x, n = blockIdx.y;
  const int tx = threadIdx.x, ty = threadIdx.y;
  const float sc = scsh[c], sh = scsh[128+c];
  const float* src = out0 + ((size_t)n*128 + c)*4096;
  #pragma unroll
  for (int r = 0; r < 16; ++r){
    int h = ty + r*4;
    t[h][tx] = src[h*64 + tx];
  }
  __syncthreads();
  float* dst = hin + (size_t)(n*64)*8192 + (size_t)c*64;
  #pragma unroll
  for (int r = 0; r < 16; ++r){
    int w_ = ty + r*4;
    float vv = fmaf(sc, t[tx][w_], sh);
    dst[(size_t)w_*8192 + tx] = fmaxf(vv, 0.f);
  }
}

// ---------------------------------------------------------------------------
// rel windowed sums/correlations for sim-BN stats
// ---------------------------------------------------------------------------
__global__ __launch_bounds__(256) void k_prep_rel(const float* __restrict__ rel,
                                                  float* __restrict__ rw)
{
  const int side = blockIdx.x;
  const float* base = rel + side*8*127;
  float* Wout = rw + side*4096;
  float* Sout = rw + 8192 + side*512;
  const int tid = threadIdx.y*64 + threadIdx.x;
  for (int idx = tid; idx < 4096; idx += 256){
    int pr = idx >> 6, i = idx & 63;
    int c = pr >> 3, c2 = pr & 7;
    const float* r1 = base + c*127 + i;
    const float* r2 = base + c2*127 + i;
    float s = 0.f;
    #pragma unroll 8
    for (int u = 0; u < 64; ++u) s = fmaf(r1[u], r2[u], s);
    Wout[idx] = s;
  }
  for (int idx = tid; idx < 512; idx += 256){
    int c = idx >> 6, i = idx & 63;
    const float* r1 = base + c*127 + i;
    float s = 0.f;
    #pragma unroll 8
    for (int u = 0; u < 64; ++u) s += r1[u];
    Sout[idx] = s;
  }
}

// ---------------------------------------------------------------------------
// sim-BN stats per (b,g) via Gram factorization. grid (1024), block (64,4)
// ---------------------------------------------------------------------------
__global__ __launch_bounds__(256) void k_att_stats(const float* __restrict__ qkv,
    const float* __restrict__ bq, const float* __restrict__ rw, float* __restrict__ accsim)
{
  __shared__ float WqS[4096], WkS[4096], SqS[512], SkS[512];
  const int b = blockIdx.x;
  const int tx = threadIdx.x, ty = threadIdx.y;
  const int tid = ty*64 + tx;
  for (int idx = tid; idx < 4096; idx += 256){ WqS[idx] = rw[idx]; WkS[idx] = rw[4096+idx]; }
  for (int idx = tid; idx < 512;  idx += 256){ SqS[idx] = rw[8192+idx]; SkS[idx] = rw[8704+idx]; }
  __syncthreads();
  float* accb = accsim + (size_t)(b & (NCOPY-1)) * 48;
  const int i = tx;
  for (int gi = 0; gi < 2; ++gi){
    int g = ty*2 + gi;
    float q[8], k[8];
    #pragma unroll
    for (int c = 0; c < 8; ++c){
      int oq = g*32 + c, ok = oq + 8;
      q[c] = fmaf(bq[oq], qkv[((size_t)b*256 + oq)*64 + i], bq[256+oq]);
      k[c] = fmaf(bq[ok], qkv[((size_t)b*256 + ok)*64 + i], bq[256+ok]);
    }
    float qs[8], ks[8];
    #pragma unroll
    for (int c = 0; c < 8; ++c){ qs[c] = wave_sum(q[c]); ks[c] = wave_sum(k[c]); }
    float sum_qk = 0.f;
    #pragma unroll
    for (int c = 0; c < 8; ++c) sum_qk = fmaf(qs[c], ks[c], sum_qk);
    float ss_qk = 0.f;
    #pragma unroll
    for (int c = 0; c < 8; ++c){
      #pragma unroll
      for (int c2 = 0; c2 < 8; ++c2){
        float gq = wave_sum(q[c]*q[c2]);
        float gk = wave_sum(k[c]*k[c2]);
        ss_qk = fmaf(gq, gk, ss_qk);
      }
    }
    float tq = 0.f, tk = 0.f, tq2 = 0.f, tk2 = 0.f;
    #pragma unroll
    for (int c = 0; c < 8; ++c){
      tq = fmaf(q[c], SqS[c*64 + i], tq);
      tk = fmaf(k[c], SkS[c*64 + i], tk);
    }
    #pragma unroll
    for (int c = 0; c < 8; ++c){
      #pragma unroll
      for (int c2 = 0; c2 < 8; ++c2){
        tq2 = fmaf(q[c]*q[c2], WqS[(c*8+c2)*64 + i], tq2);
        tk2 = fmaf(k[c]*k[c2], WkS[(c*8+c2)*64 + i], tk2);
      }
    }
    float sum_qr = 0.1f  * wave_sum(tq);
    float ss_qr  = 0.01f * wave_sum(tq2);
    float sum_kr = 0.1f  * wave_sum(tk);
    float ss_kr  = 0.01f * wave_sum(tk2);
    if (tx == 0){
      atomicAdd(&accb[g],      sum_qk); atomicAdd(&accb[24+g],    ss_qk);
      atomicAdd(&accb[8+g],    sum_qr); atomicAdd(&accb[24+8+g],  ss_qr);
      atomicAdd(&accb[16+g],   sum_kr); atomicAdd(&accb[24+16+g], ss_kr);
    }
  }
}

// ---------------------------------------------------------------------------
// attention pass 2 (restructured): logits (BN folded) -> group-softmax ->
// sv/sve with deferred normalization. grid (1024 b, 8 g), block (64,4)
// ---------------------------------------------------------------------------
__global__ __launch_bounds__(256) void k_att2(const float* __restrict__ qkv,
    const float* __restrict__ bq, const float* __restrict__ rel,
    const float* __restrict__ simsc, float* __restrict__ svout, float* __restrict__ accbo)
{
  __shared__ float q[8][64];
  __shared__ float vT[64][18];   // transposed V: vT[j][c]
  __shared__ float re[4064];     // 32 rel rows x 127, BN/0.1-scaled
  __shared__ float P[64][65];
  __shared__ float rinv[64];
  const int b = blockIdx.x, g = blockIdx.y;
  const int tx = threadIdx.x, ty = threadIdx.y;
  const int tid = ty*64 + tx;

  const float scq  = simsc[g];
  const float scr_ = 0.1f*simsc[8+g];
  const float sck_ = 0.1f*simsc[16+g];

  // ---- stage q, vT (transposed), re (scale-folded), k in regs ----
  #pragma unroll
  for (int r = 0; r < 2; ++r){
    int u = ty + r*4;                       // 0..7: q rows
    int o = g*32 + u;
    q[u][tx] = fmaf(bq[o], qkv[((size_t)b*256 + o)*64 + tx], bq[256+o]);
  }
  #pragma unroll
  for (int r = 0; r < 4; ++r){
    int u = ty + r*4;                       // 0..15: v channels
    int o = g*32 + 16 + u;
    vT[tx][u] = fmaf(bq[o], qkv[((size_t)b*256 + o)*64 + tx], bq[256+o]);
  }
  {
    int rr = tid >> 3, pp = tid & 7;        // row 0..31, part 0..7
    float rs = (rr < 8) ? scr_ : (rr < 16 ? sck_ : 0.1f);
    int base = rr*127 + pp*16;
    int cnt = (pp == 7) ? 15 : 16;
    for (int e = 0; e < cnt; ++e) re[base+e] = rel[base+e]*rs;
  }
  float kreg[8], kq[8];                     // lane tx holds k[c][j=tx]
  #pragma unroll
  for (int c = 0; c < 8; ++c){
    int o = g*32 + 8 + c;
    float kv = fmaf(bq[o], qkv[((size_t)b*256 + o)*64 + tx], bq[256+o]);
    kreg[c] = kv; kq[c] = scq*kv;
  }
  __syncthreads();

  // ---- phase A: logits, all scales folded, shift dropped (softmax-inv) ----
  #pragma unroll 4
  for (int t = 0; t < 16; ++t){
    int i = ty + 4*t;
    int dq = i - tx + 63, dk = tx - i + 63;
    float acc = 0.f;
    #pragma unroll
    for (int c = 0; c < 8; ++c){
      float qv = q[c][i];
      acc = fmaf(qv, kq[c], acc);
      acc = fmaf(qv, re[c*127 + dq], acc);
      acc = fmaf(kreg[c], re[(8+c)*127 + dk], acc);
    }
    P[i][tx] = acc;
  }
  __syncthreads();

  // ---- phase B: softmax; thread (row=tid>>2, seg=tid&3) owns 16 elems ----
  {
    const int row = tid >> 2, sl = tid & 3;
    float e0[16];
    #pragma unroll
    for (int e = 0; e < 16; ++e) e0[e] = P[row][sl*16 + e];
    float m0 = fmaxf(fmaxf(e0[0],e0[1]),  fmaxf(e0[2],e0[3]));
    float m1 = fmaxf(fmaxf(e0[4],e0[5]),  fmaxf(e0[6],e0[7]));
    float m2 = fmaxf(fmaxf(e0[8],e0[9]),  fmaxf(e0[10],e0[11]));
    float m3 = fmaxf(fmaxf(e0[12],e0[13]),fmaxf(e0[14],e0[15]));
    float m = fmaxf(fmaxf(m0,m1), fmaxf(m2,m3));
    m = fmaxf(m, __shfl_xor(m, 1, 64));
    m = fmaxf(m, __shfl_xor(m, 2, 64));
    float s = 0.f;
    #pragma unroll
    for (int e = 0; e < 16; ++e){ float ex = __expf(e0[e]-m); e0[e]=ex; s += ex; }
    s += __shfl_xor(s, 1, 64);
    s += __shfl_xor(s, 2, 64);
    #pragma unroll
    for (int e = 0; e < 16; ++e) P[row][sl*16 + e] = e0[e];   // unnormalized
    if (sl == 0) rinv[row] = 1.0f/s;
  }
  __syncthreads();

  // ---- phase C: sv (ty 0..1) / sve (ty 2..3); lanes = i ----
  float out8[8];
  #pragma unroll
  for (int c = 0; c < 8; ++c) out8[c] = 0.f;
  const int i = tx;
  if (ty < 2){
    const int c0 = ty*8;
    #pragma unroll 4
    for (int jj = 0; jj < 64; ++jj){
      float p = P[i][jj];
      const float* vp = &vT[jj][c0];
      #pragma unroll
      for (int cc = 0; cc < 8; ++cc) out8[cc] = fmaf(p, vp[cc], out8[cc]);
    }
  } else {
    const int c0 = (ty-2)*8;
    #pragma unroll 2
    for (int jj = 0; jj < 64; ++jj){
      float p = P[i][jj];
      int d = i - jj + 63;
      #pragma unroll
      for (int cc = 0; cc < 8; ++cc)
        out8[cc] = fmaf(p, re[(16+c0+cc)*127 + d], out8[cc]);
    }
  }
  const float ri = rinv[i];
  const int chbase = (ty < 2) ? (g*16 + ty*8) : (128 + g*16 + (ty-2)*8);
  float* accb = accbo + (size_t)(b & (NCOPY-1)) * 512;
  #pragma unroll
  for (int cc = 0; cc < 8; ++cc){
    float val = out8[cc]*ri;
    svout[((size_t)b*256 + chbase + cc)*64 + i] = val;
    float s  = wave_sum(val);
    float s2 = wave_sum(val*val);
    if (tx == 0){ atomicAdd(&accb[chbase+cc], s); atomicAdd(&accb[256+chbase+cc], s2); }
  }
}

// ---------------------------------------------------------------------------
// bo-BN + pair-sum + transpose (h-axial -> w-axial input)
// ---------------------------------------------------------------------------
__global__ __launch_bounds__(256) void k_pairT(const float* __restrict__ sv,
    const float* __restrict__ bo, float* __restrict__ win)
{
  __shared__ float t[64][65];
  const int c = blockIdx.x, n = blockIdx.y;
  const int tx = threadIdx.x, ty = threadIdx.y;
  const float s0 = bo[2*c], s1 = bo[2*c+1];
  const float sh = bo[256 + 2*c] + bo[256 + 2*c + 1];
  const float* base = sv + (size_t)(n*64)*256*64;
  #pragma unroll
  for (int r = 0; r < 16; ++r){
    int w_ = ty + r*4;
    float v0 = base[((size_t)w_*256 + 2*c    )*64 + tx];
    float v1 = base[((size_t)w_*256 + 2*c + 1)*64 + tx];
    t[w_][tx] = fmaf(s0, v0, fmaf(s1, v1, sh));
  }
  __syncthreads();
  float* dst = win + (size_t)(n*64)*8192 + (size_t)c*64;
  #pragma unroll
  for (int r = 0; r < 16; ++r){
    int h_ = ty + r*4;
    dst[(size_t)h_*8192 + tx] = t[tx][h_];
  }
}

// ---------------------------------------------------------------------------
// bo-BN + pair-sum, no transpose (w-axial -> natural NCHW)
// ---------------------------------------------------------------------------
__global__ __launch_bounds__(256) void k_pair_w(const float* __restrict__ sv,
    const float* __restrict__ bo, float* __restrict__ wbuf)
{
  const int m = blockIdx.x, n = blockIdx.y;
  const int tx = threadIdx.x, ty = threadIdx.y;
  const float s0 = bo[2*m], s1 = bo[2*m+1];
  const float sh = bo[256 + 2*m] + bo[256 + 2*m + 1];
  #pragma unroll
  for (int r = 0; r < 16; ++r){
    int h = ty + r*4;
    float v0 = sv[((size_t)(n*64+h)*256 + 2*m    )*64 + tx];
    float v1 = sv[((size_t)(n*64+h)*256 + 2*m + 1)*64 + tx];
    wbuf[((size_t)(n*128+m)*64 + h)*64 + tx] = fmaf(s0, v0, fmaf(s1, v1, sh));
  }
}

// ---------------------------------------------------------------------------

extern "C" void kernel_launch(void* const* d_in, const int* in_sizes, int n_in,
                              void* d_out, int out_size, void* d_ws, size_t ws_size,
                              hipStream_t stream)
{
  const float* x     = (const float*)d_in[0];
  const float* c1_w  = (const float*)d_in[1];
  const float* c1_b  = (const float*)d_in[2];
  const float* cd_w  = (const float*)d_in[3];
  const float* cd_b  = (const float*)d_in[4];
  const float* bn1_g = (const float*)d_in[5];
  const float* bn1_b = (const float*)d_in[6];
  const float* h_qkv = (const float*)d_in[7];
  const float* h_bqg = (const float*)d_in[8];
  const float* h_bqb = (const float*)d_in[9];
  const float* h_bsg = (const float*)d_in[10];
  const float* h_bsb = (const float*)d_in[11];
  const float* h_bog = (const float*)d_in[12];
  const float* h_bob = (const float*)d_in[13];
  const float* h_rel = (const float*)d_in[14];
  const float* w_qkv = (const float*)d_in[15];
  const float* w_bqg = (const float*)d_in[16];
  const float* w_bqb = (const float*)d_in[17];
  const float* w_bsg = (const float*)d_in[18];
  const float* w_bsb = (const float*)d_in[19];
  const float* w_bog = (const float*)d_in[20];
  const float* w_bob = (const float*)d_in[21];
  const float* w_rel = (const float*)d_in[22];
  const float* cu_w  = (const float*)d_in[23];
  const float* cu_b  = (const float*)d_in[24];
  const float* bn2_g = (const float*)d_in[25];
  const float* bn2_b = (const float*)d_in[26];
  float* out = (float*)d_out;
  char* ws = (char*)d_ws;

  // big buffers (aliased across dead stages), peak 160MB:
  float* OUT0 = (float*)(ws + 0);                    // 32MB (n,128,4096)
  float* HIN  = (float*)(ws + (32ull<<20));          // 32MB (1024,128,64)
  float* QKV  = (float*)(ws + (64ull<<20));          // 64MB (1024,256,64) h-phase
  float* SVO  = (float*)(ws + 0);                    // 64MB, after OUT0/HIN dead
  float* WIN  = (float*)(ws + (64ull<<20));          // 32MB, after QKV(h) dead
  float* QKVW = (float*)(ws + (96ull<<20));          // 64MB w-phase
  float* WBUF = (float*)(ws + (64ull<<20));          // 32MB, after WIN dead
  float* Y2   = (float*)(ws + (96ull<<20));          // 64MB, after QKVW dead
  float* ST   = (float*)(ws + (160ull<<20));         // stats region

  // NCOPY=64 spread accumulators (sizes in floats):
  float* ACC_BN1 = ST;             // 16384
  float* ACC_BQ  = ST + 16384;     // 32768
  float* ACC_SIM = ST + 49152;     // 3072
  float* ACC_BO  = ST + 52224;     // 32768
  float* ACC_BQW = ST + 84992;     // 32768
  float* ACC_SIMW= ST + 117760;    // 3072
  float* ACC_BOW = ST + 120832;    // 32768
  float* ACC_BN2 = ST + 153600;    // 32768  -> ACC total 186368 floats
  float* SCB     = ST + 186368;
  float* SC_BN1 = SCB;        float* SC_BQ  = SCB + 256;
  float* SC_SIM = SCB + 768;  float* SC_BO  = SCB + 816;
  float* SC_BQW = SCB + 1328; float* SC_SIMW= SCB + 1840;
  float* SC_BOW = SCB + 1888; float* SC_BN2 = SCB + 2400;  // -> 2912
  float* RWH  = ST + 189280;  // 9216 floats
  float* RWW  = ST + 198496;  // 9216 floats (end 207712)
  // bf16 weights:
  ushort* CDBF = (ushort*)(ST + 207712);   // 16384
  ushort* QHBF = CDBF + 16384;             // 32768
  ushort* QWBF = CDBF + 49152;             // 32768
  ushort* CUBF = CDBF + 81920;             // 32768
  ushort* C1BF = CDBF + 114688;            // 32768 (end 147456 ushorts)

  hipMemsetAsync(ST, 0, 186368*sizeof(float), stream);

  const dim3 blk(64,4);
  const float inv64k = 1.f/65536.f;
  const float invsim = 1.f/4194304.f;

  // weight conversions + rel prep
  k_cvt<<<64, 256, 0, stream>>>(cd_w, CDBF, 16384);
  k_cvt<<<128, 256, 0, stream>>>(h_qkv, QHBF, 32768);
  k_cvt<<<128, 256, 0, stream>>>(w_qkv, QWBF, 32768);
  k_cvt<<<128, 256, 0, stream>>>(cu_w, CUBF, 32768);
  k_cvt<<<128, 256, 0, stream>>>(c1_w, C1BF, 32768);
  k_prep_rel<<<2, blk, 0, stream>>>(h_rel, RWH);
  k_prep_rel<<<2, blk, 0, stream>>>(w_rel, RWW);

  // cd conv + bn1 stats
  k_gemm<128,0,12><<<1024, 256, 0, stream>>>(x, CDBF, cd_b, OUT0, ACC_BN1, nullptr, nullptr);
  k_finalize<<<1, 128, 0, stream>>>(ACC_BN1, bn1_g, bn1_b, SC_BN1, 128, inv64k);
  k_trans_bnrelu<<<dim3(128,16), blk, 0, stream>>>(OUT0, SC_BN1, HIN);

  // ---- h axial ----
  k_gemm<256,1,6><<<1024, 256, 0, stream>>>(HIN, QHBF, nullptr, QKV, ACC_BQ, nullptr, nullptr);
  k_finalize<<<1, 256, 0, stream>>>(ACC_BQ, h_bqg, h_bqb, SC_BQ, 256, inv64k);
  k_att_stats<<<1024, blk, 0, stream>>>(QKV, SC_BQ, RWH, ACC_SIM);
  k_finalize<<<1, 32, 0, stream>>>(ACC_SIM, h_bsg, h_bsb, SC_SIM, 24, invsim);
  k_att2<<<dim3(1024,8), blk, 0, stream>>>(QKV, SC_BQ, h_rel, SC_SIM, SVO, ACC_BO);
  k_finalize<<<1, 256, 0, stream>>>(ACC_BO, h_bog, h_bob, SC_BO, 256, inv64k);
  k_pairT<<<dim3(128,16), blk, 0, stream>>>(SVO, SC_BO, WIN);

  // ---- w axial ----
  k_gemm<256,1,6><<<1024, 256, 0, stream>>>(WIN, QWBF, nullptr, QKVW, ACC_BQW, nullptr, nullptr);
  k_finalize<<<1, 256, 0, stream>>>(ACC_BQW, w_bqg, w_bqb, SC_BQW, 256, inv64k);
  k_att_stats<<<1024, blk, 0, stream>>>(QKVW, SC_BQW, RWW, ACC_SIMW);
  k_finalize<<<1, 32, 0, stream>>>(ACC_SIMW, w_bsg, w_bsb, SC_SIMW, 24, invsim);
  k_att2<<<dim3(1024,8), blk, 0, stream>>>(QKVW, SC_BQW, w_rel, SC_SIMW, SVO, ACC_BOW);
  k_finalize<<<1, 256, 0, stream>>>(ACC_BOW, w_bog, w_bob, SC_BOW, 256, inv64k);
  k_pair_w<<<dim3(128,16), blk, 0, stream>>>(SVO, SC_BOW, WBUF);

  // cu conv + bn2 stats, then fused residual + c1 conv
  k_gemm<256,0,12><<<1024, 256, 0, stream>>>(WBUF, CUBF, cu_b, Y2, ACC_BN2, nullptr, nullptr);
  k_finalize<<<1, 256, 0, stream>>>(ACC_BN2, bn2_g, bn2_b, SC_BN2, 256, inv64k);
  k_gemm<256,2,12><<<1024, 256, 0, stream>>>(x, C1BF, c1_b, out, nullptr, Y2, SC_BN2);
}

// Round 5
// 830.206 us; speedup vs baseline: 6.2903x; 1.0847x over previous
//
#include <hip/hip_runtime.h>

// ---------------------------------------------------------------------------
// AxialBlock fused implementation. Round 5: k_att2 LDS-pipe cuts (read2-
// friendly phase A, balanced phase C), symmetric att_stats, fused cvt/prep.
// NB=16, CIN=128, COUT=256, MID=128, G=8, GP=16, K=64
// ---------------------------------------------------------------------------

#define NCOPY 64

typedef __attribute__((ext_vector_type(8))) short bf16x8;
typedef __attribute__((ext_vector_type(4))) float f32x4;

__device__ __forceinline__ float wave_sum(float v){
  #pragma unroll
  for (int o = 32; o; o >>= 1) v += __shfl_xor(v, o, 64);
  return v;
}
__device__ __forceinline__ ushort f2bf(float f){
  union { float f; unsigned u; } v; v.f = f;
  unsigned r = v.u + 0x7FFFu + ((v.u >> 16) & 1u);   // round-to-nearest-even
  return (ushort)(r >> 16);
}

// ---------------------------------------------------------------------------
// all 5 weight tensors fp32 -> bf16 (contiguous dst), one launch
// ---------------------------------------------------------------------------
__global__ void k_cvt5(const float* __restrict__ s0, const float* __restrict__ s1,
                       const float* __restrict__ s2, const float* __restrict__ s3,
                       const float* __restrict__ s4, ushort* __restrict__ dst){
  int i = blockIdx.x*256 + threadIdx.x;
  if (i >= 147456) return;
  float v;
  if      (i < 16384)  v = s0[i];
  else if (i < 49152)  v = s1[i-16384];
  else if (i < 81920)  v = s2[i-49152];
  else if (i < 114688) v = s3[i-81920];
  else                 v = s4[i-114688];
  dst[i] = f2bf(v);
}

// ---------------------------------------------------------------------------
// MFMA GEMM: out[o][col] = sum_c Wb[o][c] * X[c][col]  (+ epilogue per MODE)
// MODE 0: + bias, write, stats.  MODE 1: write, stats.  MODE 2: + bias +
// scsh residual, write, no stats.
// ---------------------------------------------------------------------------
template<int O, int MODE, int SLOG>
__global__ __launch_bounds__(256) void k_gemm(
    const float* __restrict__ X, const ushort* __restrict__ Wb,
    const float* __restrict__ bias, float* __restrict__ out,
    float* __restrict__ acc, const float* __restrict__ y2,
    const float* __restrict__ scsh)
{
  constexpr int RPW = O/4;       // rows per wave
  constexpr int NS  = RPW/16;    // 16-row subtiles per wave
  __shared__ ushort XT[64*128];  // [col][k] bf16, chunk-XOR swizzled

  const int tid = threadIdx.x;
  const int col0 = blockIdx.x << 6;
  const int seg  = col0 >> SLOG;
  const int p0   = col0 & ((1<<SLOG)-1);

  // ---- stage X tile (128c x 64col) -> bf16 transposed+swizzled ----
  {
    const int col = tid & 63;
    const int kc8 = tid >> 6;                  // 0..3
    const float* xb = X + (((size_t)seg*128) << SLOG) + p0 + col;
    #pragma unroll
    for (int q = 0; q < 4; ++q){
      int kc = kc8*4 + q;                      // k-chunk 0..15 (8 c's each)
      int c0 = kc*8;
      bf16x8 pk;
      #pragma unroll
      for (int j = 0; j < 8; ++j)
        pk[j] = (short)f2bf(xb[(size_t)(c0+j) << SLOG]);
      *(bf16x8*)&XT[col*128 + ((kc ^ (col & 15)) << 3)] = pk;
    }
  }
  __syncthreads();

  const int lane = tid & 63;
  const int wid  = tid >> 6;
  const int l15  = lane & 15, lg = lane >> 4;

  f32x4 accr[NS][4];
  #pragma unroll
  for (int s = 0; s < NS; ++s)
    #pragma unroll
    for (int ns = 0; ns < 4; ++ns)
      accr[s][ns] = (f32x4){0.f,0.f,0.f,0.f};

  #pragma unroll
  for (int kk = 0; kk < 4; ++kk){
    bf16x8 af[NS];
    #pragma unroll
    for (int s = 0; s < NS; ++s){
      int m = wid*RPW + s*16 + l15;
      af[s] = *(const bf16x8*)(Wb + (size_t)m*128 + kk*32 + lg*8);
    }
    bf16x8 bfr[4];
    #pragma unroll
    for (int ns = 0; ns < 4; ++ns){
      int ncol  = ns*16 + l15;
      int chunk = kk*4 + lg;
      bfr[ns] = *(const bf16x8*)&XT[ncol*128 + ((chunk ^ l15) << 3)];
    }
    #pragma unroll
    for (int s = 0; s < NS; ++s)
      #pragma unroll
      for (int ns = 0; ns < 4; ++ns)
        accr[s][ns] = __builtin_amdgcn_mfma_f32_16x16x32_bf16(
                        af[s], bfr[ns], accr[s][ns], 0, 0, 0);
  }

  // ---- epilogue ----
  float* accb = (MODE != 2) ? acc + (size_t)(blockIdx.x & (NCOPY-1))*2*O : nullptr;
  #pragma unroll
  for (int s = 0; s < NS; ++s){
    #pragma unroll
    for (int r = 0; r < 4; ++r){
      const int m = wid*RPW + s*16 + lg*4 + r;
      const float bs = (MODE != 1) ? bias[m] : 0.f;
      float vsum = 0.f, vsq = 0.f;
      #pragma unroll
      for (int ns = 0; ns < 4; ++ns){
        float v = accr[s][ns][r] + bs;
        size_t oidx = (((size_t)seg*O + m) << SLOG) + p0 + ns*16 + l15;
        if (MODE == 2)
          v += fmaf(scsh[m], y2[oidx], scsh[O+m]);
        out[oidx] = v;
        vsum += v; vsq = fmaf(v, v, vsq);
      }
      if (MODE != 2){
        #pragma unroll
        for (int o2 = 1; o2 < 16; o2 <<= 1){
          vsum += __shfl_xor(vsum, o2, 64);
          vsq  += __shfl_xor(vsq , o2, 64);
        }
        if (l15 == 0){
          atomicAdd(&accb[m],   vsum);
          atomicAdd(&accb[O+m], vsq);
        }
      }
    }
  }
}

// ---------------------------------------------------------------------------
// BN finalize: sum NCOPY copies; scsh[c]=g*rstd ; scsh[C+c]=b-mean*scale
// ---------------------------------------------------------------------------
__global__ void k_finalize(const float* __restrict__ acc, const float* __restrict__ g,
    const float* __restrict__ b, float* __restrict__ scsh, int C, float invcnt)
{
  int c = blockIdx.x*blockDim.x + threadIdx.x;
  if (c >= C) return;
  float s = 0.f, s2 = 0.f;
  #pragma unroll 4
  for (int k2 = 0; k2 < NCOPY; ++k2){
    s  += acc[(size_t)k2*2*C + c];
    s2 += acc[(size_t)k2*2*C + C + c];
  }
  float mean = s*invcnt;
  float var  = s2*invcnt - mean*mean;
  float sc = g[c]*rsqrtf(var + 1e-5f);
  scsh[c]   = sc;
  scsh[C+c] = fmaf(-mean, sc, b[c]);
}

// ---------------------------------------------------------------------------
// bn1+relu + transpose: hin[(n*64+w)*8192 + c*64 + h] = relu(bn(out0[n][c][h][w]))
// ---------------------------------------------------------------------------
__global__ __launch_bounds__(256) void k_trans_bnrelu(const float* __restrict__ out0,
    const float* __restrict__ scsh, float* __restrict__ hin)
{
  __shared__ float t[64][65];
  const int c = blockIdx.x, n = blockIdx.y;
  const int tx = threadIdx.x, ty = threadIdx.y;
  const float sc = scsh[c], sh = scsh[128+c];
  const float* src = out0 + ((size_t)n*128 + c)*4096;
  #pragma unroll
  for (int r = 0; r < 16; ++r){
    int h = ty + r*4;
    t[h][tx] = src[h*64 + tx];
  }
  __syncthreads();
  float* dst = hin + (size_t)(n*64)*8192 + (size_t)c*64;
  #pragma unroll
  for (int r = 0; r < 16; ++r){
    int w_ = ty + r*4;
    float vv = fmaf(sc, t[tx][w_], sh);
    dst[(size_t)w_*8192 + tx] = fmaxf(vv, 0.f);
  }
}

// ---------------------------------------------------------------------------
// rel windowed sums/correlations for sim-BN stats (both h and w in one grid)
// ---------------------------------------------------------------------------
__global__ __launch_bounds__(256) void k_prep_rel2(const float* __restrict__ relh,
    const float* __restrict__ relw, float* __restrict__ rwh, float* __restrict__ rww)
{
  const float* rel = (blockIdx.x & 2) ? relw : relh;
  float* rw        = (blockIdx.x & 2) ? rww  : rwh;
  const int side = blockIdx.x & 1;
  const float* base = rel + side*8*127;
  float* Wout = rw + side*4096;
  float* Sout = rw + 8192 + side*512;
  const int tid = threadIdx.y*64 + threadIdx.x;
  for (int idx = tid; idx < 4096; idx += 256){
    int pr = idx >> 6, i = idx & 63;
    int c = pr >> 3, c2 = pr & 7;
    const float* r1 = base + c*127 + i;
    const float* r2 = base + c2*127 + i;
    float s = 0.f;
    #pragma unroll 8
    for (int u = 0; u < 64; ++u) s = fmaf(r1[u], r2[u], s);
    Wout[idx] = s;
  }
  for (int idx = tid; idx < 512; idx += 256){
    int c = idx >> 6, i = idx & 63;
    const float* r1 = base + c*127 + i;
    float s = 0.f;
    #pragma unroll 8
    for (int u = 0; u < 64; ++u) s += r1[u];
    Sout[idx] = s;
  }
}

// ---------------------------------------------------------------------------
// sim-BN stats per (b,g) via Gram factorization (symmetric pairs only).
// grid (1024), block (64,4)
// ---------------------------------------------------------------------------
__global__ __launch_bounds__(256) void k_att_stats(const float* __restrict__ qkv,
    const float* __restrict__ bq, const float* __restrict__ rw, float* __restrict__ accsim)
{
  __shared__ float WqS[4096], WkS[4096], SqS[512], SkS[512];
  const int b = blockIdx.x;
  const int tx = threadIdx.x, ty = threadIdx.y;
  const int tid = ty*64 + tx;
  for (int idx = tid; idx < 4096; idx += 256){ WqS[idx] = rw[idx]; WkS[idx] = rw[4096+idx]; }
  for (int idx = tid; idx < 512;  idx += 256){ SqS[idx] = rw[8192+idx]; SkS[idx] = rw[8704+idx]; }
  __syncthreads();
  float* accb = accsim + (size_t)(b & (NCOPY-1)) * 48;
  const int i = tx;
  for (int gi = 0; gi < 2; ++gi){
    int g = ty*2 + gi;
    float q[8], k[8];
    #pragma unroll
    for (int c = 0; c < 8; ++c){
      int oq = g*32 + c, ok = oq + 8;
      q[c] = fmaf(bq[oq], qkv[((size_t)b*256 + oq)*64 + i], bq[256+oq]);
      k[c] = fmaf(bq[ok], qkv[((size_t)b*256 + ok)*64 + i], bq[256+ok]);
    }
    float qs[8], ks[8];
    #pragma unroll
    for (int c = 0; c < 8; ++c){ qs[c] = wave_sum(q[c]); ks[c] = wave_sum(k[c]); }
    float sum_qk = 0.f;
    #pragma unroll
    for (int c = 0; c < 8; ++c) sum_qk = fmaf(qs[c], ks[c], sum_qk);
    // symmetric Gram: off-diagonal pairs counted twice
    float ss_qk = 0.f;
    #pragma unroll
    for (int c = 0; c < 8; ++c){
      #pragma unroll
      for (int c2 = c; c2 < 8; ++c2){
        float gq = wave_sum(q[c]*q[c2]);
        float gk = wave_sum(k[c]*k[c2]);
        float w2 = (c2 == c) ? 1.f : 2.f;
        ss_qk = fmaf(w2, gq*gk, ss_qk);
      }
    }
    float tq = 0.f, tk = 0.f, tq2 = 0.f, tk2 = 0.f;
    #pragma unroll
    for (int c = 0; c < 8; ++c){
      tq = fmaf(q[c], SqS[c*64 + i], tq);
      tk = fmaf(k[c], SkS[c*64 + i], tk);
    }
    #pragma unroll
    for (int c = 0; c < 8; ++c){
      #pragma unroll
      for (int c2 = c; c2 < 8; ++c2){
        float w2 = (c2 == c) ? 1.f : 2.f;
        tq2 = fmaf(w2*q[c]*q[c2], WqS[(c*8+c2)*64 + i], tq2);
        tk2 = fmaf(w2*k[c]*k[c2], WkS[(c*8+c2)*64 + i], tk2);
      }
    }
    float sum_qr = 0.1f  * wave_sum(tq);
    float ss_qr  = 0.01f * wave_sum(tq2);
    float sum_kr = 0.1f  * wave_sum(tk);
    float ss_kr  = 0.01f * wave_sum(tk2);
    if (tx == 0){
      atomicAdd(&accb[g],      sum_qk); atomicAdd(&accb[24+g],    ss_qk);
      atomicAdd(&accb[8+g],    sum_qr); atomicAdd(&accb[24+8+g],  ss_qr);
      atomicAdd(&accb[16+g],   sum_kr); atomicAdd(&accb[24+16+g], ss_kr);
    }
  }
}

// ---------------------------------------------------------------------------
// attention pass 2 (R5): read2-friendly logits, balanced sv/sve phase C.
// grid (1024 b, 8 g), block (64,4)
// ---------------------------------------------------------------------------
__global__ __launch_bounds__(256) void k_att2(const float* __restrict__ qkv,
    const float* __restrict__ bq, const float* __restrict__ rel,
    const float* __restrict__ simsc, float* __restrict__ svout, float* __restrict__ accbo)
{
  __shared__ float q[8][64];
  __shared__ float vT[64][20];   // transposed V: vT[j][c], padded for float4
  __shared__ float re[4064];     // 32 rel rows x 127, BN/0.1-scaled
  __shared__ float P[64][65];
  __shared__ float rinv[64];
  const int b = blockIdx.x, g = blockIdx.y;
  const int tx = threadIdx.x, ty = threadIdx.y;
  const int tid = ty*64 + tx;

  const float scq  = simsc[g];
  const float scr_ = 0.1f*simsc[8+g];
  const float sck_ = 0.1f*simsc[16+g];

  // ---- stage q, vT (transposed), re (scale-folded), k in regs ----
  #pragma unroll
  for (int r = 0; r < 2; ++r){
    int u = ty + r*4;                       // 0..7: q rows
    int o = g*32 + u;
    q[u][tx] = fmaf(bq[o], qkv[((size_t)b*256 + o)*64 + tx], bq[256+o]);
  }
  #pragma unroll
  for (int r = 0; r < 4; ++r){
    int u = ty + r*4;                       // 0..15: v channels
    int o = g*32 + 16 + u;
    vT[tx][u] = fmaf(bq[o], qkv[((size_t)b*256 + o)*64 + tx], bq[256+o]);
  }
  {
    int rr = tid >> 3, pp = tid & 7;        // row 0..31, part 0..7
    float rs = (rr < 8) ? scr_ : (rr < 16 ? sck_ : 0.1f);
    int base = rr*127 + pp*16;
    int cnt = (pp == 7) ? 15 : 16;
    for (int e = 0; e < cnt; ++e) re[base+e] = rel[base+e]*rs;
  }
  float kreg[8], kq[8];                     // lane tx holds k[c][j=tx]
  #pragma unroll
  for (int c = 0; c < 8; ++c){
    int o = g*32 + 8 + c;
    float kv = fmaf(bq[o], qkv[((size_t)b*256 + o)*64 + tx], bq[256+o]);
    kreg[c] = kv; kq[c] = scq*kv;
  }
  __syncthreads();

  // ---- phase A: wave ty owns rows i0=ty*16..+15; lane = j = tx.
  // All LDS streams consecutive-offset -> ds_read2 merge, conflict-free. ----
  {
    const int i0 = ty*16;
    float acc[16];
    #pragma unroll
    for (int t = 0; t < 16; ++t) acc[t] = 0.f;
    #pragma unroll
    for (int c = 0; c < 8; ++c){
      const float kqc = kq[c], krc = kreg[c];
      const float* qrow = &q[c][i0];                    // uniform, offsets +t
      const float* rq = &re[c*127     + i0 - tx + 63];  // per-lane, offsets +t
      const float* rk = &re[(8+c)*127 + tx - i0 + 48];  // per-lane, offsets 15-t
      #pragma unroll
      for (int t = 0; t < 16; ++t){
        float qv = qrow[t];
        acc[t] = fmaf(qv, kqc, acc[t]);
        acc[t] = fmaf(qv, rq[t], acc[t]);
        acc[t] = fmaf(krc, rk[15-t], acc[t]);
      }
    }
    #pragma unroll
    for (int t = 0; t < 16; ++t) P[i0 + t][tx] = acc[t];
  }
  __syncthreads();

  // ---- phase B: softmax; thread (row=tid>>2, seg=tid&3) owns 16 elems ----
  {
    const int row = tid >> 2, sl = tid & 3;
    float e0[16];
    #pragma unroll
    for (int e = 0; e < 16; ++e) e0[e] = P[row][sl*16 + e];
    float m0 = fmaxf(fmaxf(e0[0],e0[1]),  fmaxf(e0[2],e0[3]));
    float m1 = fmaxf(fmaxf(e0[4],e0[5]),  fmaxf(e0[6],e0[7]));
    float m2 = fmaxf(fmaxf(e0[8],e0[9]),  fmaxf(e0[10],e0[11]));
    float m3 = fmaxf(fmaxf(e0[12],e0[13]),fmaxf(e0[14],e0[15]));
    float m = fmaxf(fmaxf(m0,m1), fmaxf(m2,m3));
    m = fmaxf(m, __shfl_xor(m, 1, 64));
    m = fmaxf(m, __shfl_xor(m, 2, 64));
    float s = 0.f;
    #pragma unroll
    for (int e = 0; e < 16; ++e){ float ex = __expf(e0[e]-m); e0[e]=ex; s += ex; }
    s += __shfl_xor(s, 1, 64);
    s += __shfl_xor(s, 2, 64);
    #pragma unroll
    for (int e = 0; e < 16; ++e) P[row][sl*16 + e] = e0[e];   // unnormalized
    if (sl == 0) rinv[row] = 1.0f/s;
  }
  __syncthreads();

  // ---- phase C (balanced): every wave does 4 sv + 4 sve channels ----
  const int c0 = ty*4;
  float osv[4] = {0.f,0.f,0.f,0.f};
  float ose[4] = {0.f,0.f,0.f,0.f};
  const int i = tx;
  {
    const float* pr  = &P[i][0];                       // per-lane, offsets +jj
    const float* re0 = &re[(16+c0+0)*127 + i + 63];    // per-lane, offsets -jj
    const float* re1 = re0 + 127;
    const float* re2 = re1 + 127;
    const float* re3 = re2 + 127;
    #pragma unroll 8
    for (int jj = 0; jj < 64; ++jj){
      float p = pr[jj];
      const f32x4 vv = *(const f32x4*)&vT[jj][c0];     // uniform, aligned
      osv[0] = fmaf(p, vv[0], osv[0]);
      osv[1] = fmaf(p, vv[1], osv[1]);
      osv[2] = fmaf(p, vv[2], osv[2]);
      osv[3] = fmaf(p, vv[3], osv[3]);
      ose[0] = fmaf(p, re0[-jj], ose[0]);
      ose[1] = fmaf(p, re1[-jj], ose[1]);
      ose[2] = fmaf(p, re2[-jj], ose[2]);
      ose[3] = fmaf(p, re3[-jj], ose[3]);
    }
  }
  const float ri = rinv[i];
  float* accb = accbo + (size_t)(b & (NCOPY-1)) * 512;
  #pragma unroll
  for (int cc = 0; cc < 4; ++cc){
    float val = osv[cc]*ri;
    int ch = g*16 + c0 + cc;
    svout[((size_t)b*256 + ch)*64 + i] = val;
    float s  = wave_sum(val);
    float s2 = wave_sum(val*val);
    if (tx == 0){ atomicAdd(&accb[ch], s); atomicAdd(&accb[256+ch], s2); }
  }
  #pragma unroll
  for (int cc = 0; cc < 4; ++cc){
    float val = ose[cc]*ri;
    int ch = 128 + g*16 + c0 + cc;
    svout[((size_t)b*256 + ch)*64 + i] = val;
    float s  = wave_sum(val);
    float s2 = wave_sum(val*val);
    if (tx == 0){ atomicAdd(&accb[ch], s); atomicAdd(&accb[256+ch], s2); }
  }
}

// ---------------------------------------------------------------------------
// bo-BN + pair-sum + transpose (h-axial -> w-axial input)
// ---------------------------------------------------------------------------
__global__ __launch_bounds__(256) void k_pairT(const float* __restrict__ sv,
    const float* __restrict__ bo, float* __restrict__ win)
{
  __shared__ float t[64][65];
  const int c = blockIdx.x, n = blockIdx.y;
  const int tx = threadIdx.x, ty = threadIdx.y;
  const float s0 = bo[2*c], s1 = bo[2*c+1];
  const float sh = bo[256 + 2*c] + bo[256 + 2*c + 1];
  const float* base = sv + (size_t)(n*64)*256*64;
  #pragma unroll
  for (int r = 0; r < 16; ++r){
    int w_ = ty + r*4;
    float v0 = base[((size_t)w_*256 + 2*c    )*64 + tx];
    float v1 = base[((size_t)w_*256 + 2*c + 1)*64 + tx];
    t[w_][tx] = fmaf(s0, v0, fmaf(s1, v1, sh));
  }
  __syncthreads();
  float* dst = win + (size_t)(n*64)*8192 + (size_t)c*64;
  #pragma unroll
  for (int r = 0; r < 16; ++r){
    int h_ = ty + r*4;
    dst[(size_t)h_*8192 + tx] = t[tx][h_];
  }
}

// ---------------------------------------------------------------------------
// bo-BN + pair-sum, no transpose (w-axial -> natural NCHW)
// ---------------------------------------------------------------------------
__global__ __launch_bounds__(256) void k_pair_w(const float* __restrict__ sv,
    const float* __restrict__ bo, float* __restrict__ wbuf)
{
  const int m = blockIdx.x, n = blockIdx.y;
  const int tx = threadIdx.x, ty = threadIdx.y;
  const float s0 = bo[2*m], s1 = bo[2*m+1];
  const float sh = bo[256 + 2*m] + bo[256 + 2*m + 1];
  #pragma unroll
  for (int r = 0; r < 16; ++r){
    int h = ty + r*4;
    float v0 = sv[((size_t)(n*64+h)*256 + 2*m    )*64 + tx];
    float v1 = sv[((size_t)(n*64+h)*256 + 2*m + 1)*64 + tx];
    wbuf[((size_t)(n*128+m)*64 + h)*64 + tx] = fmaf(s0, v0, fmaf(s1, v1, sh));
  }
}

// ---------------------------------------------------------------------------

extern "C" void kernel_launch(void* const* d_in, const int* in_sizes, int n_in,
                              void* d_out, int out_size, void* d_ws, size_t ws_size,
                              hipStream_t stream)
{
  const float* x     = (const float*)d_in[0];
  const float* c1_w  = (const float*)d_in[1];
  const float* c1_b  = (const float*)d_in[2];
  const float* cd_w  = (const float*)d_in[3];
  const float* cd_b  = (const float*)d_in[4];
  const float* bn1_g = (const float*)d_in[5];
  const float* bn1_b = (const float*)d_in[6];
  const float* h_qkv = (const float*)d_in[7];
  const float* h_bqg = (const float*)d_in[8];
  const float* h_bqb = (const float*)d_in[9];
  const float* h_bsg = (const float*)d_in[10];
  const float* h_bsb = (const float*)d_in[11];
  const float* h_bog = (const float*)d_in[12];
  const float* h_bob = (const float*)d_in[13];
  const float* h_rel = (const float*)d_in[14];
  const float* w_qkv = (const float*)d_in[15];
  const float* w_bqg = (const float*)d_in[16];
  const float* w_bqb = (const float*)d_in[17];
  const float* w_bsg = (const float*)d_in[18];
  const float* w_bsb = (const float*)d_in[19];
  const float* w_bog = (const float*)d_in[20];
  const float* w_bob = (const float*)d_in[21];
  const float* w_rel = (const float*)d_in[22];
  const float* cu_w  = (const float*)d_in[23];
  const float* cu_b  = (const float*)d_in[24];
  const float* bn2_g = (const float*)d_in[25];
  const float* bn2_b = (const float*)d_in[26];
  float* out = (float*)d_out;
  char* ws = (char*)d_ws;

  // big buffers (aliased across dead stages), peak 160MB:
  float* OUT0 = (float*)(ws + 0);                    // 32MB (n,128,4096)
  float* HIN  = (float*)(ws + (32ull<<20));          // 32MB (1024,128,64)
  float* QKV  = (float*)(ws + (64ull<<20));          // 64MB (1024,256,64) h-phase
  float* SVO  = (float*)(ws + 0);                    // 64MB, after OUT0/HIN dead
  float* WIN  = (float*)(ws + (64ull<<20));          // 32MB, after QKV(h) dead
  float* QKVW = (float*)(ws + (96ull<<20));          // 64MB w-phase
  float* WBUF = (float*)(ws + (64ull<<20));          // 32MB, after WIN dead
  float* Y2   = (float*)(ws + (96ull<<20));          // 64MB, after QKVW dead
  float* ST   = (float*)(ws + (160ull<<20));         // stats region

  // NCOPY=64 spread accumulators (sizes in floats):
  float* ACC_BN1 = ST;             // 16384
  float* ACC_BQ  = ST + 16384;     // 32768
  float* ACC_SIM = ST + 49152;     // 3072
  float* ACC_BO  = ST + 52224;     // 32768
  float* ACC_BQW = ST + 84992;     // 32768
  float* ACC_SIMW= ST + 117760;    // 3072
  float* ACC_BOW = ST + 120832;    // 32768
  float* ACC_BN2 = ST + 153600;    // 32768  -> ACC total 186368 floats
  float* SCB     = ST + 186368;
  float* SC_BN1 = SCB;        float* SC_BQ  = SCB + 256;
  float* SC_SIM = SCB + 768;  float* SC_BO  = SCB + 816;
  float* SC_BQW = SCB + 1328; float* SC_SIMW= SCB + 1840;
  float* SC_BOW = SCB + 1888; float* SC_BN2 = SCB + 2400;  // -> 2912
  float* RWH  = ST + 189280;  // 9216 floats
  float* RWW  = ST + 198496;  // 9216 floats (end 207712)
  // bf16 weights (contiguous for k_cvt5):
  ushort* CDBF = (ushort*)(ST + 207712);   // 16384
  ushort* QHBF = CDBF + 16384;             // 32768
  ushort* QWBF = CDBF + 49152;             // 32768
  ushort* CUBF = CDBF + 81920;             // 32768
  ushort* C1BF = CDBF + 114688;            // 32768 (end 147456 ushorts)

  hipMemsetAsync(ST, 0, 186368*sizeof(float), stream);

  const dim3 blk(64,4);
  const float inv64k = 1.f/65536.f;
  const float invsim = 1.f/4194304.f;

  // weight conversions + rel prep (fused launches)
  k_cvt5<<<576, 256, 0, stream>>>(cd_w, h_qkv, w_qkv, cu_w, c1_w, CDBF);
  k_prep_rel2<<<4, blk, 0, stream>>>(h_rel, w_rel, RWH, RWW);

  // cd conv + bn1 stats
  k_gemm<128,0,12><<<1024, 256, 0, stream>>>(x, CDBF, cd_b, OUT0, ACC_BN1, nullptr, nullptr);
  k_finalize<<<1, 128, 0, stream>>>(ACC_BN1, bn1_g, bn1_b, SC_BN1, 128, inv64k);
  k_trans_bnrelu<<<dim3(128,16), blk, 0, stream>>>(OUT0, SC_BN1, HIN);

  // ---- h axial ----
  k_gemm<256,1,6><<<1024, 256, 0, stream>>>(HIN, QHBF, nullptr, QKV, ACC_BQ, nullptr, nullptr);
  k_finalize<<<1, 256, 0, stream>>>(ACC_BQ, h_bqg, h_bqb, SC_BQ, 256, inv64k);
  k_att_stats<<<1024, blk, 0, stream>>>(QKV, SC_BQ, RWH, ACC_SIM);
  k_finalize<<<1, 32, 0, stream>>>(ACC_SIM, h_bsg, h_bsb, SC_SIM, 24, invsim);
  k_att2<<<dim3(1024,8), blk, 0, stream>>>(QKV, SC_BQ, h_rel, SC_SIM, SVO, ACC_BO);
  k_finalize<<<1, 256, 0, stream>>>(ACC_BO, h_bog, h_bob, SC_BO, 256, inv64k);
  k_pairT<<<dim3(128,16), blk, 0, stream>>>(SVO, SC_BO, WIN);

  // ---- w axial ----
  k_gemm<256,1,6><<<1024, 256, 0, stream>>>(WIN, QWBF, nullptr, QKVW, ACC_BQW, nullptr, nullptr);
  k_finalize<<<1, 256, 0, stream>>>(ACC_BQW, w_bqg, w_bqb, SC_BQW, 256, inv64k);
  k_att_stats<<<1024, blk, 0, stream>>>(QKVW, SC_BQW, RWW, ACC_SIMW);
  k_finalize<<<1, 32, 0, stream>>>(ACC_SIMW, w_bsg, w_bsb, SC_SIMW, 24, invsim);
  k_att2<<<dim3(1024,8), blk, 0, stream>>>(QKVW, SC_BQW, w_rel, SC_SIMW, SVO, ACC_BOW);
  k_finalize<<<1, 256, 0, stream>>>(ACC_BOW, w_bog, w_bob, SC_BOW, 256, inv64k);
  k_pair_w<<<dim3(128,16), blk, 0, stream>>>(SVO, SC_BOW, WBUF);

  // cu conv + bn2 stats, then fused residual + c1 conv
  k_gemm<256,0,12><<<1024, 256, 0, stream>>>(WBUF, CUBF, cu_b, Y2, ACC_BN2, nullptr, nullptr);
  k_finalize<<<1, 256, 0, stream>>>(ACC_BN2, bn2_g, bn2_b, SC_BN2, 256, inv64k);
  k_gemm<256,2,12><<<1024, 256, 0, stream>>>(x, C1BF, c1_b, out, nullptr, Y2, SC_BN2);
}

// Round 6
// 685.563 us; speedup vs baseline: 7.6175x; 1.2110x over previous
//
#include <hip/hip_runtime.h>

// ---------------------------------------------------------------------------
// AxialBlock fused implementation. Round 6: k_att2 phase C via MFMA
// (sv = P·V^T; sve = P'·Re^T with Toeplitz skew P'[i][d]=P[i][i-d+63]),
// bf16 P/P'/V/Re operands, LDS lifetime aliasing -> 4 blocks/CU.
// NB=16, CIN=128, COUT=256, MID=128, G=8, GP=16, K=64
// ---------------------------------------------------------------------------

#define NCOPY 64

typedef __attribute__((ext_vector_type(8))) short bf16x8;
typedef __attribute__((ext_vector_type(4))) short bf16x4;
typedef __attribute__((ext_vector_type(4))) float f32x4;

__device__ __forceinline__ float wave_sum(float v){
  #pragma unroll
  for (int o = 32; o; o >>= 1) v += __shfl_xor(v, o, 64);
  return v;
}
__device__ __forceinline__ ushort f2bf(float f){
  union { float f; unsigned u; } v; v.f = f;
  unsigned r = v.u + 0x7FFFu + ((v.u >> 16) & 1u);   // round-to-nearest-even
  return (ushort)(r >> 16);
}

// ---------------------------------------------------------------------------
// all 5 weight tensors fp32 -> bf16 (contiguous dst), one launch
// ---------------------------------------------------------------------------
__global__ void k_cvt5(const float* __restrict__ s0, const float* __restrict__ s1,
                       const float* __restrict__ s2, const float* __restrict__ s3,
                       const float* __restrict__ s4, ushort* __restrict__ dst){
  int i = blockIdx.x*256 + threadIdx.x;
  if (i >= 147456) return;
  float v;
  if      (i < 16384)  v = s0[i];
  else if (i < 49152)  v = s1[i-16384];
  else if (i < 81920)  v = s2[i-49152];
  else if (i < 114688) v = s3[i-81920];
  else                 v = s4[i-114688];
  dst[i] = f2bf(v);
}

// ---------------------------------------------------------------------------
// MFMA GEMM: out[o][col] = sum_c Wb[o][c] * X[c][col]  (+ epilogue per MODE)
// MODE 0: + bias, write, stats.  MODE 1: write, stats.  MODE 2: + bias +
// scsh residual, write, no stats.
// ---------------------------------------------------------------------------
template<int O, int MODE, int SLOG>
__global__ __launch_bounds__(256) void k_gemm(
    const float* __restrict__ X, const ushort* __restrict__ Wb,
    const float* __restrict__ bias, float* __restrict__ out,
    float* __restrict__ acc, const float* __restrict__ y2,
    const float* __restrict__ scsh)
{
  constexpr int RPW = O/4;       // rows per wave
  constexpr int NS  = RPW/16;    // 16-row subtiles per wave
  __shared__ ushort XT[64*128];  // [col][k] bf16, chunk-XOR swizzled

  const int tid = threadIdx.x;
  const int col0 = blockIdx.x << 6;
  const int seg  = col0 >> SLOG;
  const int p0   = col0 & ((1<<SLOG)-1);

  // ---- stage X tile (128c x 64col) -> bf16 transposed+swizzled ----
  {
    const int col = tid & 63;
    const int kc8 = tid >> 6;                  // 0..3
    const float* xb = X + (((size_t)seg*128) << SLOG) + p0 + col;
    #pragma unroll
    for (int q = 0; q < 4; ++q){
      int kc = kc8*4 + q;                      // k-chunk 0..15 (8 c's each)
      int c0 = kc*8;
      bf16x8 pk;
      #pragma unroll
      for (int j = 0; j < 8; ++j)
        pk[j] = (short)f2bf(xb[(size_t)(c0+j) << SLOG]);
      *(bf16x8*)&XT[col*128 + ((kc ^ (col & 15)) << 3)] = pk;
    }
  }
  __syncthreads();

  const int lane = tid & 63;
  const int wid  = tid >> 6;
  const int l15  = lane & 15, lg = lane >> 4;

  f32x4 accr[NS][4];
  #pragma unroll
  for (int s = 0; s < NS; ++s)
    #pragma unroll
    for (int ns = 0; ns < 4; ++ns)
      accr[s][ns] = (f32x4){0.f,0.f,0.f,0.f};

  #pragma unroll
  for (int kk = 0; kk < 4; ++kk){
    bf16x8 af[NS];
    #pragma unroll
    for (int s = 0; s < NS; ++s){
      int m = wid*RPW + s*16 + l15;
      af[s] = *(const bf16x8*)(Wb + (size_t)m*128 + kk*32 + lg*8);
    }
    bf16x8 bfr[4];
    #pragma unroll
    for (int ns = 0; ns < 4; ++ns){
      int ncol  = ns*16 + l15;
      int chunk = kk*4 + lg;
      bfr[ns] = *(const bf16x8*)&XT[ncol*128 + ((chunk ^ l15) << 3)];
    }
    #pragma unroll
    for (int s = 0; s < NS; ++s)
      #pragma unroll
      for (int ns = 0; ns < 4; ++ns)
        accr[s][ns] = __builtin_amdgcn_mfma_f32_16x16x32_bf16(
                        af[s], bfr[ns], accr[s][ns], 0, 0, 0);
  }

  // ---- epilogue ----
  float* accb = (MODE != 2) ? acc + (size_t)(blockIdx.x & (NCOPY-1))*2*O : nullptr;
  #pragma unroll
  for (int s = 0; s < NS; ++s){
    #pragma unroll
    for (int r = 0; r < 4; ++r){
      const int m = wid*RPW + s*16 + lg*4 + r;
      const float bs = (MODE != 1) ? bias[m] : 0.f;
      float vsum = 0.f, vsq = 0.f;
      #pragma unroll
      for (int ns = 0; ns < 4; ++ns){
        float v = accr[s][ns][r] + bs;
        size_t oidx = (((size_t)seg*O + m) << SLOG) + p0 + ns*16 + l15;
        if (MODE == 2)
          v += fmaf(scsh[m], y2[oidx], scsh[O+m]);
        out[oidx] = v;
        vsum += v; vsq = fmaf(v, v, vsq);
      }
      if (MODE != 2){
        #pragma unroll
        for (int o2 = 1; o2 < 16; o2 <<= 1){
          vsum += __shfl_xor(vsum, o2, 64);
          vsq  += __shfl_xor(vsq , o2, 64);
        }
        if (l15 == 0){
          atomicAdd(&accb[m],   vsum);
          atomicAdd(&accb[O+m], vsq);
        }
      }
    }
  }
}

// ---------------------------------------------------------------------------
// BN finalize: sum NCOPY copies; scsh[c]=g*rstd ; scsh[C+c]=b-mean*scale
// ---------------------------------------------------------------------------
__global__ void k_finalize(const float* __restrict__ acc, const float* __restrict__ g,
    const float* __restrict__ b, float* __restrict__ scsh, int C, float invcnt)
{
  int c = blockIdx.x*blockDim.x + threadIdx.x;
  if (c >= C) return;
  float s = 0.f, s2 = 0.f;
  #pragma unroll 4
  for (int k2 = 0; k2 < NCOPY; ++k2){
    s  += acc[(size_t)k2*2*C + c];
    s2 += acc[(size_t)k2*2*C + C + c];
  }
  float mean = s*invcnt;
  float var  = s2*invcnt - mean*mean;
  float sc = g[c]*rsqrtf(var + 1e-5f);
  scsh[c]   = sc;
  scsh[C+c] = fmaf(-mean, sc, b[c]);
}

// ---------------------------------------------------------------------------
// bn1+relu + transpose: hin[(n*64+w)*8192 + c*64 + h] = relu(bn(out0[n][c][h][w]))
// ---------------------------------------------------------------------------
__global__ __launch_bounds__(256) void k_trans_bnrelu(const float* __restrict__ out0,
    const float* __restrict__ scsh, float* __restrict__ hin)
{
  __shared__ float t[64][65];
  const int c = blockIdx.x, n = blockIdx.y;
  const int tx = threadIdx.x, ty = threadIdx.y;
  const float sc = scsh[c], sh = scsh[128+c];
  const float* src = out0 + ((size_t)n*128 + c)*4096;
  #pragma unroll
  for (int r = 0; r < 16; ++r){
    int h = ty + r*4;
    t[h][tx] = src[h*64 + tx];
  }
  __syncthreads();
  float* dst = hin + (size_t)(n*64)*8192 + (size_t)c*64;
  #pragma unroll
  for (int r = 0; r < 16; ++r){
    int w_ = ty + r*4;
    float vv = fmaf(sc, t[tx][w_], sh);
    dst[(size_t)w_*8192 + tx] = fmaxf(vv, 0.f);
  }
}

// ---------------------------------------------------------------------------
// rel windowed sums/correlations for sim-BN stats (both h and w in one grid)
// ---------------------------------------------------------------------------
__global__ __launch_bounds__(256) void k_prep_rel2(const float* __restrict__ relh,
    const float* __restrict__ relw, float* __restrict__ rwh, float* __restrict__ rww)
{
  const float* rel = (blockIdx.x & 2) ? relw : relh;
  float* rw        = (blockIdx.x & 2) ? rww  : rwh;
  const int side = blockIdx.x & 1;
  const float* base = rel + side*8*127;
  float* Wout = rw + side*4096;
  float* Sout = rw + 8192 + side*512;
  const int tid = threadIdx.y*64 + threadIdx.x;
  for (int idx = tid; idx < 4096; idx += 256){
    int pr = idx >> 6, i = idx & 63;
    int c = pr >> 3, c2 = pr & 7;
    const float* r1 = base + c*127 + i;
    const float* r2 = base + c2*127 + i;
    float s = 0.f;
    #pragma unroll 8
    for (int u = 0; u < 64; ++u) s = fmaf(r1[u], r2[u], s);
    Wout[idx] = s;
  }
  for (int idx = tid; idx < 512; idx += 256){
    int c = idx >> 6, i = idx & 63;
    const float* r1 = base + c*127 + i;
    float s = 0.f;
    #pragma unroll 8
    for (int u = 0; u < 64; ++u) s += r1[u];
    Sout[idx] = s;
  }
}

// ---------------------------------------------------------------------------
// sim-BN stats per (b,g) via Gram factorization (symmetric pairs only).
// grid (1024), block (64,4)
// ---------------------------------------------------------------------------
__global__ __launch_bounds__(256) void k_att_stats(const float* __restrict__ qkv,
    const float* __restrict__ bq, const float* __restrict__ rw, float* __restrict__ accsim)
{
  __shared__ float WqS[4096], WkS[4096], SqS[512], SkS[512];
  const int b = blockIdx.x;
  const int tx = threadIdx.x, ty = threadIdx.y;
  const int tid = ty*64 + tx;
  for (int idx = tid; idx < 4096; idx += 256){ WqS[idx] = rw[idx]; WkS[idx] = rw[4096+idx]; }
  for (int idx = tid; idx < 512;  idx += 256){ SqS[idx] = rw[8192+idx]; SkS[idx] = rw[8704+idx]; }
  __syncthreads();
  float* accb = accsim + (size_t)(b & (NCOPY-1)) * 48;
  const int i = tx;
  for (int gi = 0; gi < 2; ++gi){
    int g = ty*2 + gi;
    float q[8], k[8];
    #pragma unroll
    for (int c = 0; c < 8; ++c){
      int oq = g*32 + c, ok = oq + 8;
      q[c] = fmaf(bq[oq], qkv[((size_t)b*256 + oq)*64 + i], bq[256+oq]);
      k[c] = fmaf(bq[ok], qkv[((size_t)b*256 + ok)*64 + i], bq[256+ok]);
    }
    float qs[8], ks[8];
    #pragma unroll
    for (int c = 0; c < 8; ++c){ qs[c] = wave_sum(q[c]); ks[c] = wave_sum(k[c]); }
    float sum_qk = 0.f;
    #pragma unroll
    for (int c = 0; c < 8; ++c) sum_qk = fmaf(qs[c], ks[c], sum_qk);
    float ss_qk = 0.f;
    #pragma unroll
    for (int c = 0; c < 8; ++c){
      #pragma unroll
      for (int c2 = c; c2 < 8; ++c2){
        float gq = wave_sum(q[c]*q[c2]);
        float gk = wave_sum(k[c]*k[c2]);
        float w2 = (c2 == c) ? 1.f : 2.f;
        ss_qk = fmaf(w2, gq*gk, ss_qk);
      }
    }
    float tq = 0.f, tk = 0.f, tq2 = 0.f, tk2 = 0.f;
    #pragma unroll
    for (int c = 0; c < 8; ++c){
      tq = fmaf(q[c], SqS[c*64 + i], tq);
      tk = fmaf(k[c], SkS[c*64 + i], tk);
    }
    #pragma unroll
    for (int c = 0; c < 8; ++c){
      #pragma unroll
      for (int c2 = c; c2 < 8; ++c2){
        float w2 = (c2 == c) ? 1.f : 2.f;
        tq2 = fmaf(w2*q[c]*q[c2], WqS[(c*8+c2)*64 + i], tq2);
        tk2 = fmaf(w2*k[c]*k[c2], WkS[(c*8+c2)*64 + i], tk2);
      }
    }
    float sum_qr = 0.1f  * wave_sum(tq);
    float ss_qr  = 0.01f * wave_sum(tq2);
    float sum_kr = 0.1f  * wave_sum(tk);
    float ss_kr  = 0.01f * wave_sum(tk2);
    if (tx == 0){
      atomicAdd(&accb[g],      sum_qk); atomicAdd(&accb[24+g],    ss_qk);
      atomicAdd(&accb[8+g],    sum_qr); atomicAdd(&accb[24+8+g],  ss_qr);
      atomicAdd(&accb[16+g],   sum_kr); atomicAdd(&accb[24+16+g], ss_kr);
    }
  }
}

// ---------------------------------------------------------------------------
// attention pass 2 (R6): fp32 VALU logits -> group softmax -> bf16 P/P'
// -> MFMA sv/sve.  grid (1024 b, 8 g), block (64,4)
//
// LDS lifetime plan (bytes):
//   A-phase:  [0]     RE32  8128  (16 rows x 127 f32, scale-folded q_e/k_e)
//             [8128]  Q     2048  (8x64 f32)
//             [10176] P32   17408 (64x68 f32 logits)            end 27584
//   B->C:     [0]     PB    8192  (64x64 bf16, chunk-swizzled)
//             [8192]  PP    16384 (64x128 bf16 skewed, swizzled)
//             [24576] RINV  256
//   persist:  [27584] VB    2304  (16x72 bf16: V^T[c][j], swizzled)
//             [29888] REB   4352  (16x136 bf16: 0.1*rel_v[c][d], swizzled)
//   total 34240
// ---------------------------------------------------------------------------
__global__ __launch_bounds__(256) void k_att2(const float* __restrict__ qkv,
    const float* __restrict__ bq, const float* __restrict__ rel,
    const float* __restrict__ simsc, float* __restrict__ svout, float* __restrict__ accbo)
{
  __shared__ __align__(16) char smem[34240];
  float*  RE32 = (float*)(smem);
  float*  Q    = (float*)(smem + 8128);
  float*  P32  = (float*)(smem + 10176);     // [64][68]
  float*  RINV = (float*)(smem + 24576);

  const int b = blockIdx.x, g = blockIdx.y;
  const int tx = threadIdx.x, ty = threadIdx.y;
  const int tid = ty*64 + tx;

  const float scq  = simsc[g];
  const float scr_ = 0.1f*simsc[8+g];
  const float sck_ = 0.1f*simsc[16+g];

  // ---- stage Q (f32), RE32 rows 0..15 (scale-folded), VB/REB (bf16), k regs ----
  #pragma unroll
  for (int r = 0; r < 2; ++r){
    int u = ty + r*4;                       // 0..7: q rows
    int o = g*32 + u;
    Q[u*64 + tx] = fmaf(bq[o], qkv[((size_t)b*256 + o)*64 + tx], bq[256+o]);
  }
  {
    int rr = tid >> 4, pp = tid & 15;       // row 0..15, part 0..15 (8 elems)
    float rs = (rr < 8) ? scr_ : sck_;
    int base = rr*127 + pp*8;
    int cnt = (pp == 15) ? 7 : 8;
    for (int e = 0; e < cnt; ++e) RE32[base+e] = rel[base+e]*rs;
  }
  {
    // VB[c][j] = bn(v[c][j]) bf16, c-major stride 144B, chunk-XOR swizzle
    int c = tid >> 4, j4 = (tid & 15)*4;
    int o = g*32 + 16 + c;
    float gsc = bq[o], gsh = bq[256+o];
    const float* src = &qkv[((size_t)b*256 + o)*64 + j4];
    bf16x4 pv;
    #pragma unroll
    for (int e = 0; e < 4; ++e) pv[e] = (short)f2bf(fmaf(gsc, src[e], gsh));
    *(bf16x4*)(smem + 27584 + c*144 + (((j4>>3) ^ (c&7))<<4) + (j4&7)*2) = pv;
  }
  {
    // REB[c][d] = 0.1*rel[16+c][d] bf16 (d=127 -> 0), stride 272B, swizzled
    int c = tid >> 4, d8 = (tid & 15)*8;
    const float* rsrc = &rel[(16+c)*127 + d8];
    bf16x8 pk;
    #pragma unroll
    for (int e = 0; e < 8; ++e){
      int d = d8 + e;
      pk[e] = (d < 127) ? (short)f2bf(0.1f*rsrc[e]) : (short)0;
    }
    *(bf16x8*)(smem + 29888 + c*272 + (((d8>>3) ^ (c&15))<<4)) = pk;
  }
  float kreg[8], kq[8];                     // lane tx holds k[c][j=tx]
  #pragma unroll
  for (int c = 0; c < 8; ++c){
    int o = g*32 + 8 + c;
    float kv = fmaf(bq[o], qkv[((size_t)b*256 + o)*64 + tx], bq[256+o]);
    kreg[c] = kv; kq[c] = scq*kv;
  }
  __syncthreads();

  // ---- phase A: fp32 logits; wave ty owns rows i0..i0+15, lane = j = tx ----
  {
    const int i0 = ty*16;
    float acc[16];
    #pragma unroll
    for (int t = 0; t < 16; ++t) acc[t] = 0.f;
    #pragma unroll
    for (int c = 0; c < 8; ++c){
      const float kqc = kq[c], krc = kreg[c];
      const float* qrow = &Q[c*64 + i0];                  // uniform, +t
      const float* rq = &RE32[c*127     + i0 - tx + 63];  // per-lane, +t
      const float* rk = &RE32[(8+c)*127 + tx - i0 + 48];  // per-lane, 15-t
      #pragma unroll
      for (int t = 0; t < 16; ++t){
        float qv = qrow[t];
        acc[t] = fmaf(qv, kqc, acc[t]);
        acc[t] = fmaf(qv, rq[t], acc[t]);
        acc[t] = fmaf(krc, rk[15-t], acc[t]);
      }
    }
    #pragma unroll
    for (int t = 0; t < 16; ++t) P32[(i0 + t)*68 + tx] = acc[t];
  }
  __syncthreads();

  // ---- phase B: softmax; thread (row=tid>>2, sl=tid&3) owns 16 elems ----
  float e0[16];
  const int row = tid >> 2, sl = tid & 3;
  {
    const float* prow = &P32[row*68 + sl*16];
    #pragma unroll
    for (int e = 0; e < 16; ++e) e0[e] = prow[e];
    float m0 = fmaxf(fmaxf(e0[0],e0[1]),  fmaxf(e0[2],e0[3]));
    float m1 = fmaxf(fmaxf(e0[4],e0[5]),  fmaxf(e0[6],e0[7]));
    float m2 = fmaxf(fmaxf(e0[8],e0[9]),  fmaxf(e0[10],e0[11]));
    float m3 = fmaxf(fmaxf(e0[12],e0[13]),fmaxf(e0[14],e0[15]));
    float m = fmaxf(fmaxf(m0,m1), fmaxf(m2,m3));
    m = fmaxf(m, __shfl_xor(m, 1, 64));
    m = fmaxf(m, __shfl_xor(m, 2, 64));
    float s = 0.f;
    #pragma unroll
    for (int e = 0; e < 16; ++e){ float ex = __expf(e0[e]-m); e0[e]=ex; s += ex; }
    s += __shfl_xor(s, 1, 64);
    s += __shfl_xor(s, 2, 64);
    __syncthreads();                        // bar1: P32 now dead
    // zero PP (16384B / 256 thr = 64B each)
    {
      f32x4 z = (f32x4){0.f,0.f,0.f,0.f};
      float* zp = (float*)(smem + 8192 + tid*64);
      *(f32x4*)(zp+0) = z; *(f32x4*)(zp+4) = z;
      *(f32x4*)(zp+8) = z; *(f32x4*)(zp+12) = z;
    }
    if (sl == 0) RINV[row] = 1.0f/s;
    __syncthreads();                        // bar2
    // PB: row-major bf16 chunks, swizzle chunk^(row&7)
    bf16x8 pk0, pk1;
    #pragma unroll
    for (int e = 0; e < 8; ++e){ pk0[e] = (short)f2bf(e0[e]); pk1[e] = (short)f2bf(e0[8+e]); }
    char* pbbase = smem + 0 + row*128;
    *(bf16x8*)(pbbase + (((2*sl    ) ^ (row&7))<<4)) = pk0;
    *(bf16x8*)(pbbase + (((2*sl + 1) ^ (row&7))<<4)) = pk1;
    // PP band: P'[row][d] = P[row][j], d = row - j + 63
    char* ppbase = smem + 8192 + row*256;
    #pragma unroll
    for (int e = 0; e < 16; ++e){
      int j = sl*16 + e, d = row - j + 63;
      *(ushort*)(ppbase + (((d>>3) ^ (row&15))<<4) + (d&7)*2) = f2bf(e0[e]);
    }
  }
  __syncthreads();                          // bar3

  // ---- phase C: MFMA. wave ty: output rows i0..i0+15, cols = 16 channels ----
  {
    const int l15 = tx & 15, lg = tx >> 4;
    const int i0 = ty*16;
    const int rowA = i0 + l15;
    char* pbA = smem + 0    + rowA*128;
    char* ppA = smem + 8192 + rowA*256;
    char* vbB = smem + 27584 + l15*144;
    char* reB = smem + 29888 + l15*272;
    f32x4 accv = (f32x4){0.f,0.f,0.f,0.f};
    f32x4 acce = (f32x4){0.f,0.f,0.f,0.f};
    #pragma unroll
    for (int kk = 0; kk < 2; ++kk){
      bf16x8 a  = *(bf16x8*)(pbA + (((kk*4+lg) ^ (rowA&7))<<4));
      bf16x8 bb = *(bf16x8*)(vbB + (((kk*4+lg) ^ (l15&7))<<4));
      accv = __builtin_amdgcn_mfma_f32_16x16x32_bf16(a, bb, accv, 0, 0, 0);
    }
    #pragma unroll
    for (int kk = 0; kk < 4; ++kk){
      bf16x8 a  = *(bf16x8*)(ppA + (((kk*4+lg) ^ (rowA&15))<<4));
      bf16x8 bb = *(bf16x8*)(reB + (((kk*4+lg) ^ (l15&15))<<4));
      acce = __builtin_amdgcn_mfma_f32_16x16x32_bf16(a, bb, acce, 0, 0, 0);
    }
    f32x4 ri4 = *(f32x4*)(smem + 24576 + (i0 + lg*4)*4);
    float* accb = accbo + (size_t)(b & (NCOPY-1)) * 512;
    // sv
    {
      f32x4 vals;
      float vsum = 0.f, vsq = 0.f;
      #pragma unroll
      for (int r = 0; r < 4; ++r){
        float v = accv[r]*ri4[r];
        vals[r] = v; vsum += v; vsq = fmaf(v, v, vsq);
      }
      int ch = g*16 + l15;
      *(f32x4*)&svout[((size_t)b*256 + ch)*64 + i0 + lg*4] = vals;
      vsum += __shfl_xor(vsum, 16, 64); vsum += __shfl_xor(vsum, 32, 64);
      vsq  += __shfl_xor(vsq , 16, 64); vsq  += __shfl_xor(vsq , 32, 64);
      if (lg == 0){ atomicAdd(&accb[ch], vsum); atomicAdd(&accb[256+ch], vsq); }
    }
    // sve
    {
      f32x4 vals;
      float vsum = 0.f, vsq = 0.f;
      #pragma unroll
      for (int r = 0; r < 4; ++r){
        float v = acce[r]*ri4[r];
        vals[r] = v; vsum += v; vsq = fmaf(v, v, vsq);
      }
      int ch = 128 + g*16 + l15;
      *(f32x4*)&svout[((size_t)b*256 + ch)*64 + i0 + lg*4] = vals;
      vsum += __shfl_xor(vsum, 16, 64); vsum += __shfl_xor(vsum, 32, 64);
      vsq  += __shfl_xor(vsq , 16, 64); vsq  += __shfl_xor(vsq , 32, 64);
      if (lg == 0){ atomicAdd(&accb[ch], vsum); atomicAdd(&accb[256+ch], vsq); }
    }
  }
}

// ---------------------------------------------------------------------------
// bo-BN + pair-sum + transpose (h-axial -> w-axial input)
// ---------------------------------------------------------------------------
__global__ __launch_bounds__(256) void k_pairT(const float* __restrict__ sv,
    const float* __restrict__ bo, float* __restrict__ win)
{
  __shared__ float t[64][65];
  const int c = blockIdx.x, n = blockIdx.y;
  const int tx = threadIdx.x, ty = threadIdx.y;
  const float s0 = bo[2*c], s1 = bo[2*c+1];
  const float sh = bo[256 + 2*c] + bo[256 + 2*c + 1];
  const float* base = sv + (size_t)(n*64)*256*64;
  #pragma unroll
  for (int r = 0; r < 16; ++r){
    int w_ = ty + r*4;
    float v0 = base[((size_t)w_*256 + 2*c    )*64 + tx];
    float v1 = base[((size_t)w_*256 + 2*c + 1)*64 + tx];
    t[w_][tx] = fmaf(s0, v0, fmaf(s1, v1, sh));
  }
  __syncthreads();
  float* dst = win + (size_t)(n*64)*8192 + (size_t)c*64;
  #pragma unroll
  for (int r = 0; r < 16; ++r){
    int h_ = ty + r*4;
    dst[(size_t)h_*8192 + tx] = t[tx][h_];
  }
}

// ---------------------------------------------------------------------------
// bo-BN + pair-sum, no transpose (w-axial -> natural NCHW)
// ---------------------------------------------------------------------------
__global__ __launch_bounds__(256) void k_pair_w(const float* __restrict__ sv,
    const float* __restrict__ bo, float* __restrict__ wbuf)
{
  const int m = blockIdx.x, n = blockIdx.y;
  const int tx = threadIdx.x, ty = threadIdx.y;
  const float s0 = bo[2*m], s1 = bo[2*m+1];
  const float sh = bo[256 + 2*m] + bo[256 + 2*m + 1];
  #pragma unroll
  for (int r = 0; r < 16; ++r){
    int h = ty + r*4;
    float v0 = sv[((size_t)(n*64+h)*256 + 2*m    )*64 + tx];
    float v1 = sv[((size_t)(n*64+h)*256 + 2*m + 1)*64 + tx];
    wbuf[((size_t)(n*128+m)*64 + h)*64 + tx] = fmaf(s0, v0, fmaf(s1, v1, sh));
  }
}

// ---------------------------------------------------------------------------

extern "C" void kernel_launch(void* const* d_in, const int* in_sizes, int n_in,
                              void* d_out, int out_size, void* d_ws, size_t ws_size,
                              hipStream_t stream)
{
  const float* x     = (const float*)d_in[0];
  const float* c1_w  = (const float*)d_in[1];
  const float* c1_b  = (const float*)d_in[2];
  const float* cd_w  = (const float*)d_in[3];
  const float* cd_b  = (const float*)d_in[4];
  const float* bn1_g = (const float*)d_in[5];
  const float* bn1_b = (const float*)d_in[6];
  const float* h_qkv = (const float*)d_in[7];
  const float* h_bqg = (const float*)d_in[8];
  const float* h_bqb = (const float*)d_in[9];
  const float* h_bsg = (const float*)d_in[10];
  const float* h_bsb = (const float*)d_in[11];
  const float* h_bog = (const float*)d_in[12];
  const float* h_bob = (const float*)d_in[13];
  const float* h_rel = (const float*)d_in[14];
  const float* w_qkv = (const float*)d_in[15];
  const float* w_bqg = (const float*)d_in[16];
  const float* w_bqb = (const float*)d_in[17];
  const float* w_bsg = (const float*)d_in[18];
  const float* w_bsb = (const float*)d_in[19];
  const float* w_bog = (const float*)d_in[20];
  const float* w_bob = (const float*)d_in[21];
  const float* w_rel = (const float*)d_in[22];
  const float* cu_w  = (const float*)d_in[23];
  const float* cu_b  = (const float*)d_in[24];
  const float* bn2_g = (const float*)d_in[25];
  const float* bn2_b = (const float*)d_in[26];
  float* out = (float*)d_out;
  char* ws = (char*)d_ws;

  // big buffers (aliased across dead stages), peak 160MB:
  float* OUT0 = (float*)(ws + 0);                    // 32MB (n,128,4096)
  float* HIN  = (float*)(ws + (32ull<<20));          // 32MB (1024,128,64)
  float* QKV  = (float*)(ws + (64ull<<20));          // 64MB (1024,256,64) h-phase
  float* SVO  = (float*)(ws + 0);                    // 64MB, after OUT0/HIN dead
  float* WIN  = (float*)(ws + (64ull<<20));          // 32MB, after QKV(h) dead
  float* QKVW = (float*)(ws + (96ull<<20));          // 64MB w-phase
  float* WBUF = (float*)(ws + (64ull<<20));          // 32MB, after WIN dead
  float* Y2   = (float*)(ws + (96ull<<20));          // 64MB, after QKVW dead
  float* ST   = (float*)(ws + (160ull<<20));         // stats region

  // NCOPY=64 spread accumulators (sizes in floats):
  float* ACC_BN1 = ST;             // 16384
  float* ACC_BQ  = ST + 16384;     // 32768
  float* ACC_SIM = ST + 49152;     // 3072
  float* ACC_BO  = ST + 52224;     // 32768
  float* ACC_BQW = ST + 84992;     // 32768
  float* ACC_SIMW= ST + 117760;    // 3072
  float* ACC_BOW = ST + 120832;    // 32768
  float* ACC_BN2 = ST + 153600;    // 32768  -> ACC total 186368 floats
  float* SCB     = ST + 186368;
  float* SC_BN1 = SCB;        float* SC_BQ  = SCB + 256;
  float* SC_SIM = SCB + 768;  float* SC_BO  = SCB + 816;
  float* SC_BQW = SCB + 1328; float* SC_SIMW= SCB + 1840;
  float* SC_BOW = SCB + 1888; float* SC_BN2 = SCB + 2400;  // -> 2912
  float* RWH  = ST + 189280;  // 9216 floats
  float* RWW  = ST + 198496;  // 9216 floats (end 207712)
  // bf16 weights (contiguous for k_cvt5):
  ushort* CDBF = (ushort*)(ST + 207712);   // 16384
  ushort* QHBF = CDBF + 16384;             // 32768
  ushort* QWBF = CDBF + 49152;             // 32768
  ushort* CUBF = CDBF + 81920;             // 32768
  ushort* C1BF = CDBF + 114688;            // 32768 (end 147456 ushorts)

  hipMemsetAsync(ST, 0, 186368*sizeof(float), stream);

  const dim3 blk(64,4);
  const float inv64k = 1.f/65536.f;
  const float invsim = 1.f/4194304.f;

  // weight conversions + rel prep (fused launches)
  k_cvt5<<<576, 256, 0, stream>>>(cd_w, h_qkv, w_qkv, cu_w, c1_w, CDBF);
  k_prep_rel2<<<4, blk, 0, stream>>>(h_rel, w_rel, RWH, RWW);

  // cd conv + bn1 stats
  k_gemm<128,0,12><<<1024, 256, 0, stream>>>(x, CDBF, cd_b, OUT0, ACC_BN1, nullptr, nullptr);
  k_finalize<<<1, 128, 0, stream>>>(ACC_BN1, bn1_g, bn1_b, SC_BN1, 128, inv64k);
  k_trans_bnrelu<<<dim3(128,16), blk, 0, stream>>>(OUT0, SC_BN1, HIN);

  // ---- h axial ----
  k_gemm<256,1,6><<<1024, 256, 0, stream>>>(HIN, QHBF, nullptr, QKV, ACC_BQ, nullptr, nullptr);
  k_finalize<<<1, 256, 0, stream>>>(ACC_BQ, h_bqg, h_bqb, SC_BQ, 256, inv64k);
  k_att_stats<<<1024, blk, 0, stream>>>(QKV, SC_BQ, RWH, ACC_SIM);
  k_finalize<<<1, 32, 0, stream>>>(ACC_SIM, h_bsg, h_bsb, SC_SIM, 24, invsim);
  k_att2<<<dim3(1024,8), blk, 0, stream>>>(QKV, SC_BQ, h_rel, SC_SIM, SVO, ACC_BO);
  k_finalize<<<1, 256, 0, stream>>>(ACC_BO, h_bog, h_bob, SC_BO, 256, inv64k);
  k_pairT<<<dim3(128,16), blk, 0, stream>>>(SVO, SC_BO, WIN);

  // ---- w axial ----
  k_gemm<256,1,6><<<1024, 256, 0, stream>>>(WIN, QWBF, nullptr, QKVW, ACC_BQW, nullptr, nullptr);
  k_finalize<<<1, 256, 0, stream>>>(ACC_BQW, w_bqg, w_bqb, SC_BQW, 256, inv64k);
  k_att_stats<<<1024, blk, 0, stream>>>(QKVW, SC_BQW, RWW, ACC_SIMW);
  k_finalize<<<1, 32, 0, stream>>>(ACC_SIMW, w_bsg, w_bsb, SC_SIMW, 24, invsim);
  k_att2<<<dim3(1024,8), blk, 0, stream>>>(QKVW, SC_BQW, w_rel, SC_SIMW, SVO, ACC_BOW);
  k_finalize<<<1, 256, 0, stream>>>(ACC_BOW, w_bog, w_bob, SC_BOW, 256, inv64k);
  k_pair_w<<<dim3(128,16), blk, 0, stream>>>(SVO, SC_BOW, WBUF);

  // cu conv + bn2 stats, then fused residual + c1 conv
  k_gemm<256,0,12><<<1024, 256, 0, stream>>>(WBUF, CUBF, cu_b, Y2, ACC_BN2, nullptr, nullptr);
  k_finalize<<<1, 256, 0, stream>>>(ACC_BN2, bn2_g, bn2_b, SC_BN2, 256, inv64k);
  k_gemm<256,2,12><<<1024, 256, 0, stream>>>(x, C1BF, c1_b, out, nullptr, Y2, SC_BN2);
}

// Round 7
// 445.817 us; speedup vs baseline: 11.7140x; 1.5378x over previous
//
#include <hip/hip_runtime.h>

// ---------------------------------------------------------------------------
// AxialBlock fused implementation. Round 7: k_att_stats via MFMA Gram
// (G = A·A^T, rowsums = A·1) replacing ~180 wave_sums/thread with 4 MFMAs.
// NB=16, CIN=128, COUT=256, MID=128, G=8, GP=16, K=64
// ---------------------------------------------------------------------------

#define NCOPY 64

typedef __attribute__((ext_vector_type(8))) short bf16x8;
typedef __attribute__((ext_vector_type(4))) short bf16x4;
typedef __attribute__((ext_vector_type(4))) float f32x4;

__device__ __forceinline__ float wave_sum(float v){
  #pragma unroll
  for (int o = 32; o; o >>= 1) v += __shfl_xor(v, o, 64);
  return v;
}
__device__ __forceinline__ ushort f2bf(float f){
  union { float f; unsigned u; } v; v.f = f;
  unsigned r = v.u + 0x7FFFu + ((v.u >> 16) & 1u);   // round-to-nearest-even
  return (ushort)(r >> 16);
}

// ---------------------------------------------------------------------------
// all 5 weight tensors fp32 -> bf16 (contiguous dst), one launch
// ---------------------------------------------------------------------------
__global__ void k_cvt5(const float* __restrict__ s0, const float* __restrict__ s1,
                       const float* __restrict__ s2, const float* __restrict__ s3,
                       const float* __restrict__ s4, ushort* __restrict__ dst){
  int i = blockIdx.x*256 + threadIdx.x;
  if (i >= 147456) return;
  float v;
  if      (i < 16384)  v = s0[i];
  else if (i < 49152)  v = s1[i-16384];
  else if (i < 81920)  v = s2[i-49152];
  else if (i < 114688) v = s3[i-81920];
  else                 v = s4[i-114688];
  dst[i] = f2bf(v);
}

// ---------------------------------------------------------------------------
// MFMA GEMM: out[o][col] = sum_c Wb[o][c] * X[c][col]  (+ epilogue per MODE)
// MODE 0: + bias, write, stats.  MODE 1: write, stats.  MODE 2: + bias +
// scsh residual, write, no stats.
// ---------------------------------------------------------------------------
template<int O, int MODE, int SLOG>
__global__ __launch_bounds__(256) void k_gemm(
    const float* __restrict__ X, const ushort* __restrict__ Wb,
    const float* __restrict__ bias, float* __restrict__ out,
    float* __restrict__ acc, const float* __restrict__ y2,
    const float* __restrict__ scsh)
{
  constexpr int RPW = O/4;       // rows per wave
  constexpr int NS  = RPW/16;    // 16-row subtiles per wave
  __shared__ ushort XT[64*128];  // [col][k] bf16, chunk-XOR swizzled

  const int tid = threadIdx.x;
  const int col0 = blockIdx.x << 6;
  const int seg  = col0 >> SLOG;
  const int p0   = col0 & ((1<<SLOG)-1);

  // ---- stage X tile (128c x 64col) -> bf16 transposed+swizzled ----
  {
    const int col = tid & 63;
    const int kc8 = tid >> 6;                  // 0..3
    const float* xb = X + (((size_t)seg*128) << SLOG) + p0 + col;
    #pragma unroll
    for (int q = 0; q < 4; ++q){
      int kc = kc8*4 + q;                      // k-chunk 0..15 (8 c's each)
      int c0 = kc*8;
      bf16x8 pk;
      #pragma unroll
      for (int j = 0; j < 8; ++j)
        pk[j] = (short)f2bf(xb[(size_t)(c0+j) << SLOG]);
      *(bf16x8*)&XT[col*128 + ((kc ^ (col & 15)) << 3)] = pk;
    }
  }
  __syncthreads();

  const int lane = tid & 63;
  const int wid  = tid >> 6;
  const int l15  = lane & 15, lg = lane >> 4;

  f32x4 accr[NS][4];
  #pragma unroll
  for (int s = 0; s < NS; ++s)
    #pragma unroll
    for (int ns = 0; ns < 4; ++ns)
      accr[s][ns] = (f32x4){0.f,0.f,0.f,0.f};

  #pragma unroll
  for (int kk = 0; kk < 4; ++kk){
    bf16x8 af[NS];
    #pragma unroll
    for (int s = 0; s < NS; ++s){
      int m = wid*RPW + s*16 + l15;
      af[s] = *(const bf16x8*)(Wb + (size_t)m*128 + kk*32 + lg*8);
    }
    bf16x8 bfr[4];
    #pragma unroll
    for (int ns = 0; ns < 4; ++ns){
      int ncol  = ns*16 + l15;
      int chunk = kk*4 + lg;
      bfr[ns] = *(const bf16x8*)&XT[ncol*128 + ((chunk ^ l15) << 3)];
    }
    #pragma unroll
    for (int s = 0; s < NS; ++s)
      #pragma unroll
      for (int ns = 0; ns < 4; ++ns)
        accr[s][ns] = __builtin_amdgcn_mfma_f32_16x16x32_bf16(
                        af[s], bfr[ns], accr[s][ns], 0, 0, 0);
  }

  // ---- epilogue ----
  float* accb = (MODE != 2) ? acc + (size_t)(blockIdx.x & (NCOPY-1))*2*O : nullptr;
  #pragma unroll
  for (int s = 0; s < NS; ++s){
    #pragma unroll
    for (int r = 0; r < 4; ++r){
      const int m = wid*RPW + s*16 + lg*4 + r;
      const float bs = (MODE != 1) ? bias[m] : 0.f;
      float vsum = 0.f, vsq = 0.f;
      #pragma unroll
      for (int ns = 0; ns < 4; ++ns){
        float v = accr[s][ns][r] + bs;
        size_t oidx = (((size_t)seg*O + m) << SLOG) + p0 + ns*16 + l15;
        if (MODE == 2)
          v += fmaf(scsh[m], y2[oidx], scsh[O+m]);
        out[oidx] = v;
        vsum += v; vsq = fmaf(v, v, vsq);
      }
      if (MODE != 2){
        #pragma unroll
        for (int o2 = 1; o2 < 16; o2 <<= 1){
          vsum += __shfl_xor(vsum, o2, 64);
          vsq  += __shfl_xor(vsq , o2, 64);
        }
        if (l15 == 0){
          atomicAdd(&accb[m],   vsum);
          atomicAdd(&accb[O+m], vsq);
        }
      }
    }
  }
}

// ---------------------------------------------------------------------------
// BN finalize: sum NCOPY copies; scsh[c]=g*rstd ; scsh[C+c]=b-mean*scale
// ---------------------------------------------------------------------------
__global__ void k_finalize(const float* __restrict__ acc, const float* __restrict__ g,
    const float* __restrict__ b, float* __restrict__ scsh, int C, float invcnt)
{
  int c = blockIdx.x*blockDim.x + threadIdx.x;
  if (c >= C) return;
  float s = 0.f, s2 = 0.f;
  #pragma unroll 4
  for (int k2 = 0; k2 < NCOPY; ++k2){
    s  += acc[(size_t)k2*2*C + c];
    s2 += acc[(size_t)k2*2*C + C + c];
  }
  float mean = s*invcnt;
  float var  = s2*invcnt - mean*mean;
  float sc = g[c]*rsqrtf(var + 1e-5f);
  scsh[c]   = sc;
  scsh[C+c] = fmaf(-mean, sc, b[c]);
}

// ---------------------------------------------------------------------------
// bn1+relu + transpose: hin[(n*64+w)*8192 + c*64 + h] = relu(bn(out0[n][c][h][w]))
// ---------------------------------------------------------------------------
__global__ __launch_bounds__(256) void k_trans_bnrelu(const float* __restrict__ out0,
    const float* __restrict__ scsh, float* __restrict__ hin)
{
  __shared__ float t[64][65];
  const int c = blockIdx.x, n = blockIdx.y;
  const int tx = threadIdx.x, ty = threadIdx.y;
  const float sc = scsh[c], sh = scsh[128+c];
  const float* src = out0 + ((size_t)n*128 + c)*4096;
  #pragma unroll
  for (int r = 0; r < 16; ++r){
    int h = ty + r*4;
    t[h][tx] = src[h*64 + tx];
  }
  __syncthreads();
  float* dst = hin + (size_t)(n*64)*8192 + (size_t)c*64;
  #pragma unroll
  for (int r = 0; r < 16; ++r){
    int w_ = ty + r*4;
    float vv = fmaf(sc, t[tx][w_], sh);
    dst[(size_t)w_*8192 + tx] = fmaxf(vv, 0.f);
  }
}

// ---------------------------------------------------------------------------
// rel windowed sums/correlations for sim-BN stats (both h and w in one grid)
// ---------------------------------------------------------------------------
__global__ __launch_bounds__(256) void k_prep_rel2(const float* __restrict__ relh,
    const float* __restrict__ relw, float* __restrict__ rwh, float* __restrict__ rww)
{
  const float* rel = (blockIdx.x & 2) ? relw : relh;
  float* rw        = (blockIdx.x & 2) ? rww  : rwh;
  const int side = blockIdx.x & 1;
  const float* base = rel + side*8*127;
  float* Wout = rw + side*4096;
  float* Sout = rw + 8192 + side*512;
  const int tid = threadIdx.y*64 + threadIdx.x;
  for (int idx = tid; idx < 4096; idx += 256){
    int pr = idx >> 6, i = idx & 63;
    int c = pr >> 3, c2 = pr & 7;
    const float* r1 = base + c*127 + i;
    const float* r2 = base + c2*127 + i;
    float s = 0.f;
    #pragma unroll 8
    for (int u = 0; u < 64; ++u) s = fmaf(r1[u], r2[u], s);
    Wout[idx] = s;
  }
  for (int idx = tid; idx < 512; idx += 256){
    int c = idx >> 6, i = idx & 63;
    const float* r1 = base + c*127 + i;
    float s = 0.f;
    #pragma unroll 8
    for (int u = 0; u < 64; ++u) s += r1[u];
    Sout[idx] = s;
  }
}

// ---------------------------------------------------------------------------
// sim-BN stats per (b,g), R7: Gram + rowsums via MFMA (A=[q;k] 16x64 bf16,
// G=A·A^T, R=A·1), windowed-table part on VALU. grid (1024), block (64,4)
// ---------------------------------------------------------------------------
__global__ __launch_bounds__(256, 4) void k_att_stats(const float* __restrict__ qkv,
    const float* __restrict__ bq, const float* __restrict__ rw, float* __restrict__ accsim)
{
  __shared__ float WqS[4096], WkS[4096], SqS[512], SkS[512];
  const int b = blockIdx.x;
  const int tx = threadIdx.x, ty = threadIdx.y;
  const int tid = ty*64 + tx;
  for (int idx = tid; idx < 4096; idx += 256){ WqS[idx] = rw[idx]; WkS[idx] = rw[4096+idx]; }
  for (int idx = tid; idx < 512;  idx += 256){ SqS[idx] = rw[8192+idx]; SkS[idx] = rw[8704+idx]; }
  __syncthreads();
  float* accb = accsim + (size_t)(b & (NCOPY-1)) * 48;
  const int i = tx;
  const int l15 = tx & 15, lg = tx >> 4;
  const short one_bf = (short)0x3F80;
  const bf16x8 ones = {one_bf,one_bf,one_bf,one_bf,one_bf,one_bf,one_bf,one_bf};

  #pragma unroll
  for (int gi = 0; gi < 2; ++gi){
    const int g = ty*2 + gi;
    // ---- i-layout q,k (lane = i) for the windowed-table stats ----
    float q[8], k[8];
    #pragma unroll
    for (int c = 0; c < 8; ++c){
      int oq = g*32 + c, ok = oq + 8;
      q[c] = fmaf(bq[oq], qkv[((size_t)b*256 + oq)*64 + i], bq[256+oq]);
      k[c] = fmaf(bq[ok], qkv[((size_t)b*256 + ok)*64 + i], bq[256+ok]);
    }
    // ---- frag-layout A = [q0..q7; k0..k7] (16x64), lane (l15=row, lg) ----
    const int och = g*32 + l15;               // rows 0..7 = q, 8..15 = k
    const float gsc = bq[och], gsh = bq[256+och];
    const float* src = &qkv[((size_t)b*256 + och)*64 + lg*8];
    bf16x8 a0, a1;
    #pragma unroll
    for (int j = 0; j < 8; ++j) a0[j] = (short)f2bf(fmaf(gsc, src[j],      gsh));
    #pragma unroll
    for (int j = 0; j < 8; ++j) a1[j] = (short)f2bf(fmaf(gsc, src[32 + j], gsh));
    // ---- G = A·A^T ; R = A·1  (b-frag of A^T == a-frag) ----
    f32x4 G = (f32x4){0.f,0.f,0.f,0.f};
    f32x4 R = (f32x4){0.f,0.f,0.f,0.f};
    G = __builtin_amdgcn_mfma_f32_16x16x32_bf16(a0, a0, G, 0, 0, 0);
    G = __builtin_amdgcn_mfma_f32_16x16x32_bf16(a1, a1, G, 0, 0, 0);
    R = __builtin_amdgcn_mfma_f32_16x16x32_bf16(a0, ones, R, 0, 0, 0);
    R = __builtin_amdgcn_mfma_f32_16x16x32_bf16(a1, ones, R, 0, 0, 0);
    // ---- epilogue: ss_qk = sum G_q ⊙ G_k ; sum_qk = qs·ks ----
    // C layout: col = l15, row = lg*4 + r. Gk[c][c2] = G[row+8][col+8] -> lane^40.
    // ks_c = R[row+8][*] -> lane^32.
    float ss = 0.f, sqk = 0.f;
    const bool gq_lane = (l15 < 8) && (lg < 2);
    const bool r_lane  = (l15 == 0) && (lg < 2);
    #pragma unroll
    for (int r = 0; r < 4; ++r){
      float gsw = __shfl_xor(G[r], 40, 64);
      float rsw = __shfl_xor(R[r], 32, 64);
      if (gq_lane) ss  = fmaf(G[r], gsw, ss);
      if (r_lane)  sqk = fmaf(R[r], rsw, sqk);
    }
    // ---- windowed-table stats (per-lane i partials) ----
    float aq = 0.f, ak = 0.f, aq2 = 0.f, ak2 = 0.f;
    #pragma unroll
    for (int c = 0; c < 8; ++c){
      aq = fmaf(q[c], SqS[c*64 + i], aq);
      ak = fmaf(k[c], SkS[c*64 + i], ak);
    }
    #pragma unroll
    for (int c = 0; c < 8; ++c){
      #pragma unroll
      for (int c2 = c; c2 < 8; ++c2){
        float w2 = (c2 == c) ? 1.f : 2.f;
        aq2 = fmaf(w2*q[c]*q[c2], WqS[(c*8+c2)*64 + i], aq2);
        ak2 = fmaf(w2*k[c]*k[c2], WkS[(c*8+c2)*64 + i], ak2);
      }
    }
    // ---- 6 wave reductions + atomics ----
    sqk = wave_sum(sqk);  ss  = wave_sum(ss);
    aq  = wave_sum(aq);   ak  = wave_sum(ak);
    aq2 = wave_sum(aq2);  ak2 = wave_sum(ak2);
    if (tx == 0){
      atomicAdd(&accb[g],      sqk);       atomicAdd(&accb[24+g],    ss);
      atomicAdd(&accb[8+g],    0.1f*aq);   atomicAdd(&accb[24+8+g],  0.01f*aq2);
      atomicAdd(&accb[16+g],   0.1f*ak);   atomicAdd(&accb[24+16+g], 0.01f*ak2);
    }
  }
}

// ---------------------------------------------------------------------------
// attention pass 2 (R6): fp32 VALU logits -> group softmax -> bf16 P/P'
// -> MFMA sv/sve.  grid (1024 b, 8 g), block (64,4)
// ---------------------------------------------------------------------------
__global__ __launch_bounds__(256) void k_att2(const float* __restrict__ qkv,
    const float* __restrict__ bq, const float* __restrict__ rel,
    const float* __restrict__ simsc, float* __restrict__ svout, float* __restrict__ accbo)
{
  __shared__ __align__(16) char smem[34240];
  float*  RE32 = (float*)(smem);
  float*  Q    = (float*)(smem + 8128);
  float*  P32  = (float*)(smem + 10176);     // [64][68]
  float*  RINV = (float*)(smem + 24576);

  const int b = blockIdx.x, g = blockIdx.y;
  const int tx = threadIdx.x, ty = threadIdx.y;
  const int tid = ty*64 + tx;

  const float scq  = simsc[g];
  const float scr_ = 0.1f*simsc[8+g];
  const float sck_ = 0.1f*simsc[16+g];

  // ---- stage Q (f32), RE32 rows 0..15 (scale-folded), VB/REB (bf16), k regs ----
  #pragma unroll
  for (int r = 0; r < 2; ++r){
    int u = ty + r*4;                       // 0..7: q rows
    int o = g*32 + u;
    Q[u*64 + tx] = fmaf(bq[o], qkv[((size_t)b*256 + o)*64 + tx], bq[256+o]);
  }
  {
    int rr = tid >> 4, pp = tid & 15;       // row 0..15, part 0..15 (8 elems)
    float rs = (rr < 8) ? scr_ : sck_;
    int base = rr*127 + pp*8;
    int cnt = (pp == 15) ? 7 : 8;
    for (int e = 0; e < cnt; ++e) RE32[base+e] = rel[base+e]*rs;
  }
  {
    // VB[c][j] = bn(v[c][j]) bf16, c-major stride 144B, chunk-XOR swizzle
    int c = tid >> 4, j4 = (tid & 15)*4;
    int o = g*32 + 16 + c;
    float gsc = bq[o], gsh = bq[256+o];
    const float* src = &qkv[((size_t)b*256 + o)*64 + j4];
    bf16x4 pv;
    #pragma unroll
    for (int e = 0; e < 4; ++e) pv[e] = (short)f2bf(fmaf(gsc, src[e], gsh));
    *(bf16x4*)(smem + 27584 + c*144 + (((j4>>3) ^ (c&7))<<4) + (j4&7)*2) = pv;
  }
  {
    // REB[c][d] = 0.1*rel[16+c][d] bf16 (d=127 -> 0), stride 272B, swizzled
    int c = tid >> 4, d8 = (tid & 15)*8;
    const float* rsrc = &rel[(16+c)*127 + d8];
    bf16x8 pk;
    #pragma unroll
    for (int e = 0; e < 8; ++e){
      int d = d8 + e;
      pk[e] = (d < 127) ? (short)f2bf(0.1f*rsrc[e]) : (short)0;
    }
    *(bf16x8*)(smem + 29888 + c*272 + (((d8>>3) ^ (c&15))<<4)) = pk;
  }
  float kreg[8], kq[8];                     // lane tx holds k[c][j=tx]
  #pragma unroll
  for (int c = 0; c < 8; ++c){
    int o = g*32 + 8 + c;
    float kv = fmaf(bq[o], qkv[((size_t)b*256 + o)*64 + tx], bq[256+o]);
    kreg[c] = kv; kq[c] = scq*kv;
  }
  __syncthreads();

  // ---- phase A: fp32 logits; wave ty owns rows i0..i0+15, lane = j = tx ----
  {
    const int i0 = ty*16;
    float acc[16];
    #pragma unroll
    for (int t = 0; t < 16; ++t) acc[t] = 0.f;
    #pragma unroll
    for (int c = 0; c < 8; ++c){
      const float kqc = kq[c], krc = kreg[c];
      const float* qrow = &Q[c*64 + i0];                  // uniform, +t
      const float* rq = &RE32[c*127     + i0 - tx + 63];  // per-lane, +t
      const float* rk = &RE32[(8+c)*127 + tx - i0 + 48];  // per-lane, 15-t
      #pragma unroll
      for (int t = 0; t < 16; ++t){
        float qv = qrow[t];
        acc[t] = fmaf(qv, kqc, acc[t]);
        acc[t] = fmaf(qv, rq[t], acc[t]);
        acc[t] = fmaf(krc, rk[15-t], acc[t]);
      }
    }
    #pragma unroll
    for (int t = 0; t < 16; ++t) P32[(i0 + t)*68 + tx] = acc[t];
  }
  __syncthreads();

  // ---- phase B: softmax; thread (row=tid>>2, sl=tid&3) owns 16 elems ----
  float e0[16];
  const int row = tid >> 2, sl = tid & 3;
  {
    const float* prow = &P32[row*68 + sl*16];
    #pragma unroll
    for (int e = 0; e < 16; ++e) e0[e] = prow[e];
    float m0 = fmaxf(fmaxf(e0[0],e0[1]),  fmaxf(e0[2],e0[3]));
    float m1 = fmaxf(fmaxf(e0[4],e0[5]),  fmaxf(e0[6],e0[7]));
    float m2 = fmaxf(fmaxf(e0[8],e0[9]),  fmaxf(e0[10],e0[11]));
    float m3 = fmaxf(fmaxf(e0[12],e0[13]),fmaxf(e0[14],e0[15]));
    float m = fmaxf(fmaxf(m0,m1), fmaxf(m2,m3));
    m = fmaxf(m, __shfl_xor(m, 1, 64));
    m = fmaxf(m, __shfl_xor(m, 2, 64));
    float s = 0.f;
    #pragma unroll
    for (int e = 0; e < 16; ++e){ float ex = __expf(e0[e]-m); e0[e]=ex; s += ex; }
    s += __shfl_xor(s, 1, 64);
    s += __shfl_xor(s, 2, 64);
    __syncthreads();                        // bar1: P32 now dead
    {
      f32x4 z = (f32x4){0.f,0.f,0.f,0.f};
      float* zp = (float*)(smem + 8192 + tid*64);
      *(f32x4*)(zp+0) = z; *(f32x4*)(zp+4) = z;
      *(f32x4*)(zp+8) = z; *(f32x4*)(zp+12) = z;
    }
    if (sl == 0) RINV[row] = 1.0f/s;
    __syncthreads();                        // bar2
    bf16x8 pk0, pk1;
    #pragma unroll
    for (int e = 0; e < 8; ++e){ pk0[e] = (short)f2bf(e0[e]); pk1[e] = (short)f2bf(e0[8+e]); }
    char* pbbase = smem + 0 + row*128;
    *(bf16x8*)(pbbase + (((2*sl    ) ^ (row&7))<<4)) = pk0;
    *(bf16x8*)(pbbase + (((2*sl + 1) ^ (row&7))<<4)) = pk1;
    char* ppbase = smem + 8192 + row*256;
    #pragma unroll
    for (int e = 0; e < 16; ++e){
      int j = sl*16 + e, d = row - j + 63;
      *(ushort*)(ppbase + (((d>>3) ^ (row&15))<<4) + (d&7)*2) = f2bf(e0[e]);
    }
  }
  __syncthreads();                          // bar3

  // ---- phase C: MFMA. wave ty: output rows i0..i0+15, cols = 16 channels ----
  {
    const int l15 = tx & 15, lg = tx >> 4;
    const int i0 = ty*16;
    const int rowA = i0 + l15;
    char* pbA = smem + 0    + rowA*128;
    char* ppA = smem + 8192 + rowA*256;
    char* vbB = smem + 27584 + l15*144;
    char* reB = smem + 29888 + l15*272;
    f32x4 accv = (f32x4){0.f,0.f,0.f,0.f};
    f32x4 acce = (f32x4){0.f,0.f,0.f,0.f};
    #pragma unroll
    for (int kk = 0; kk < 2; ++kk){
      bf16x8 a  = *(bf16x8*)(pbA + (((kk*4+lg) ^ (rowA&7))<<4));
      bf16x8 bb = *(bf16x8*)(vbB + (((kk*4+lg) ^ (l15&7))<<4));
      accv = __builtin_amdgcn_mfma_f32_16x16x32_bf16(a, bb, accv, 0, 0, 0);
    }
    #pragma unroll
    for (int kk = 0; kk < 4; ++kk){
      bf16x8 a  = *(bf16x8*)(ppA + (((kk*4+lg) ^ (rowA&15))<<4));
      bf16x8 bb = *(bf16x8*)(reB + (((kk*4+lg) ^ (l15&15))<<4));
      acce = __builtin_amdgcn_mfma_f32_16x16x32_bf16(a, bb, acce, 0, 0, 0);
    }
    f32x4 ri4 = *(f32x4*)(smem + 24576 + (i0 + lg*4)*4);
    float* accb = accbo + (size_t)(b & (NCOPY-1)) * 512;
    {
      f32x4 vals;
      float vsum = 0.f, vsq = 0.f;
      #pragma unroll
      for (int r = 0; r < 4; ++r){
        float v = accv[r]*ri4[r];
        vals[r] = v; vsum += v; vsq = fmaf(v, v, vsq);
      }
      int ch = g*16 + l15;
      *(f32x4*)&svout[((size_t)b*256 + ch)*64 + i0 + lg*4] = vals;
      vsum += __shfl_xor(vsum, 16, 64); vsum += __shfl_xor(vsum, 32, 64);
      vsq  += __shfl_xor(vsq , 16, 64); vsq  += __shfl_xor(vsq , 32, 64);
      if (lg == 0){ atomicAdd(&accb[ch], vsum); atomicAdd(&accb[256+ch], vsq); }
    }
    {
      f32x4 vals;
      float vsum = 0.f, vsq = 0.f;
      #pragma unroll
      for (int r = 0; r < 4; ++r){
        float v = acce[r]*ri4[r];
        vals[r] = v; vsum += v; vsq = fmaf(v, v, vsq);
      }
      int ch = 128 + g*16 + l15;
      *(f32x4*)&svout[((size_t)b*256 + ch)*64 + i0 + lg*4] = vals;
      vsum += __shfl_xor(vsum, 16, 64); vsum += __shfl_xor(vsum, 32, 64);
      vsq  += __shfl_xor(vsq , 16, 64); vsq  += __shfl_xor(vsq , 32, 64);
      if (lg == 0){ atomicAdd(&accb[ch], vsum); atomicAdd(&accb[256+ch], vsq); }
    }
  }
}

// ---------------------------------------------------------------------------
// bo-BN + pair-sum + transpose (h-axial -> w-axial input)
// ---------------------------------------------------------------------------
__global__ __launch_bounds__(256) void k_pairT(const float* __restrict__ sv,
    const float* __restrict__ bo, float* __restrict__ win)
{
  __shared__ float t[64][65];
  const int c = blockIdx.x, n = blockIdx.y;
  const int tx = threadIdx.x, ty = threadIdx.y;
  const float s0 = bo[2*c], s1 = bo[2*c+1];
  const float sh = bo[256 + 2*c] + bo[256 + 2*c + 1];
  const float* base = sv + (size_t)(n*64)*256*64;
  #pragma unroll
  for (int r = 0; r < 16; ++r){
    int w_ = ty + r*4;
    float v0 = base[((size_t)w_*256 + 2*c    )*64 + tx];
    float v1 = base[((size_t)w_*256 + 2*c + 1)*64 + tx];
    t[w_][tx] = fmaf(s0, v0, fmaf(s1, v1, sh));
  }
  __syncthreads();
  float* dst = win + (size_t)(n*64)*8192 + (size_t)c*64;
  #pragma unroll
  for (int r = 0; r < 16; ++r){
    int h_ = ty + r*4;
    dst[(size_t)h_*8192 + tx] = t[tx][h_];
  }
}

// ---------------------------------------------------------------------------
// bo-BN + pair-sum, no transpose (w-axial -> natural NCHW)
// ---------------------------------------------------------------------------
__global__ __launch_bounds__(256) void k_pair_w(const float* __restrict__ sv,
    const float* __restrict__ bo, float* __restrict__ wbuf)
{
  const int m = blockIdx.x, n = blockIdx.y;
  const int tx = threadIdx.x, ty = threadIdx.y;
  const float s0 = bo[2*m], s1 = bo[2*m+1];
  const float sh = bo[256 + 2*m] + bo[256 + 2*m + 1];
  #pragma unroll
  for (int r = 0; r < 16; ++r){
    int h = ty + r*4;
    float v0 = sv[((size_t)(n*64+h)*256 + 2*m    )*64 + tx];
    float v1 = sv[((size_t)(n*64+h)*256 + 2*m + 1)*64 + tx];
    wbuf[((size_t)(n*128+m)*64 + h)*64 + tx] = fmaf(s0, v0, fmaf(s1, v1, sh));
  }
}

// ---------------------------------------------------------------------------

extern "C" void kernel_launch(void* const* d_in, const int* in_sizes, int n_in,
                              void* d_out, int out_size, void* d_ws, size_t ws_size,
                              hipStream_t stream)
{
  const float* x     = (const float*)d_in[0];
  const float* c1_w  = (const float*)d_in[1];
  const float* c1_b  = (const float*)d_in[2];
  const float* cd_w  = (const float*)d_in[3];
  const float* cd_b  = (const float*)d_in[4];
  const float* bn1_g = (const float*)d_in[5];
  const float* bn1_b = (const float*)d_in[6];
  const float* h_qkv = (const float*)d_in[7];
  const float* h_bqg = (const float*)d_in[8];
  const float* h_bqb = (const float*)d_in[9];
  const float* h_bsg = (const float*)d_in[10];
  const float* h_bsb = (const float*)d_in[11];
  const float* h_bog = (const float*)d_in[12];
  const float* h_bob = (const float*)d_in[13];
  const float* h_rel = (const float*)d_in[14];
  const float* w_qkv = (const float*)d_in[15];
  const float* w_bqg = (const float*)d_in[16];
  const float* w_bqb = (const float*)d_in[17];
  const float* w_bsg = (const float*)d_in[18];
  const float* w_bsb = (const float*)d_in[19];
  const float* w_bog = (const float*)d_in[20];
  const float* w_bob = (const float*)d_in[21];
  const float* w_rel = (const float*)d_in[22];
  const float* cu_w  = (const float*)d_in[23];
  const float* cu_b  = (const float*)d_in[24];
  const float* bn2_g = (const float*)d_in[25];
  const float* bn2_b = (const float*)d_in[26];
  float* out = (float*)d_out;
  char* ws = (char*)d_ws;

  // big buffers (aliased across dead stages), peak 160MB:
  float* OUT0 = (float*)(ws + 0);                    // 32MB (n,128,4096)
  float* HIN  = (float*)(ws + (32ull<<20));          // 32MB (1024,128,64)
  float* QKV  = (float*)(ws + (64ull<<20));          // 64MB (1024,256,64) h-phase
  float* SVO  = (float*)(ws + 0);                    // 64MB, after OUT0/HIN dead
  float* WIN  = (float*)(ws + (64ull<<20));          // 32MB, after QKV(h) dead
  float* QKVW = (float*)(ws + (96ull<<20));          // 64MB w-phase
  float* WBUF = (float*)(ws + (64ull<<20));          // 32MB, after WIN dead
  float* Y2   = (float*)(ws + (96ull<<20));          // 64MB, after QKVW dead
  float* ST   = (float*)(ws + (160ull<<20));         // stats region

  // NCOPY=64 spread accumulators (sizes in floats):
  float* ACC_BN1 = ST;             // 16384
  float* ACC_BQ  = ST + 16384;     // 32768
  float* ACC_SIM = ST + 49152;     // 3072
  float* ACC_BO  = ST + 52224;     // 32768
  float* ACC_BQW = ST + 84992;     // 32768
  float* ACC_SIMW= ST + 117760;    // 3072
  float* ACC_BOW = ST + 120832;    // 32768
  float* ACC_BN2 = ST + 153600;    // 32768  -> ACC total 186368 floats
  float* SCB     = ST + 186368;
  float* SC_BN1 = SCB;        float* SC_BQ  = SCB + 256;
  float* SC_SIM = SCB + 768;  float* SC_BO  = SCB + 816;
  float* SC_BQW = SCB + 1328; float* SC_SIMW= SCB + 1840;
  float* SC_BOW = SCB + 1888; float* SC_BN2 = SCB + 2400;  // -> 2912
  float* RWH  = ST + 189280;  // 9216 floats
  float* RWW  = ST + 198496;  // 9216 floats (end 207712)
  // bf16 weights (contiguous for k_cvt5):
  ushort* CDBF = (ushort*)(ST + 207712);   // 16384
  ushort* QHBF = CDBF + 16384;             // 32768
  ushort* QWBF = CDBF + 49152;             // 32768
  ushort* CUBF = CDBF + 81920;             // 32768
  ushort* C1BF = CDBF + 114688;            // 32768 (end 147456 ushorts)

  hipMemsetAsync(ST, 0, 186368*sizeof(float), stream);

  const dim3 blk(64,4);
  const float inv64k = 1.f/65536.f;
  const float invsim = 1.f/4194304.f;

  // weight conversions + rel prep (fused launches)
  k_cvt5<<<576, 256, 0, stream>>>(cd_w, h_qkv, w_qkv, cu_w, c1_w, CDBF);
  k_prep_rel2<<<4, blk, 0, stream>>>(h_rel, w_rel, RWH, RWW);

  // cd conv + bn1 stats
  k_gemm<128,0,12><<<1024, 256, 0, stream>>>(x, CDBF, cd_b, OUT0, ACC_BN1, nullptr, nullptr);
  k_finalize<<<1, 128, 0, stream>>>(ACC_BN1, bn1_g, bn1_b, SC_BN1, 128, inv64k);
  k_trans_bnrelu<<<dim3(128,16), blk, 0, stream>>>(OUT0, SC_BN1, HIN);

  // ---- h axial ----
  k_gemm<256,1,6><<<1024, 256, 0, stream>>>(HIN, QHBF, nullptr, QKV, ACC_BQ, nullptr, nullptr);
  k_finalize<<<1, 256, 0, stream>>>(ACC_BQ, h_bqg, h_bqb, SC_BQ, 256, inv64k);
  k_att_stats<<<1024, blk, 0, stream>>>(QKV, SC_BQ, RWH, ACC_SIM);
  k_finalize<<<1, 32, 0, stream>>>(ACC_SIM, h_bsg, h_bsb, SC_SIM, 24, invsim);
  k_att2<<<dim3(1024,8), blk, 0, stream>>>(QKV, SC_BQ, h_rel, SC_SIM, SVO, ACC_BO);
  k_finalize<<<1, 256, 0, stream>>>(ACC_BO, h_bog, h_bob, SC_BO, 256, inv64k);
  k_pairT<<<dim3(128,16), blk, 0, stream>>>(SVO, SC_BO, WIN);

  // ---- w axial ----
  k_gemm<256,1,6><<<1024, 256, 0, stream>>>(WIN, QWBF, nullptr, QKVW, ACC_BQW, nullptr, nullptr);
  k_finalize<<<1, 256, 0, stream>>>(ACC_BQW, w_bqg, w_bqb, SC_BQW, 256, inv64k);
  k_att_stats<<<1024, blk, 0, stream>>>(QKVW, SC_BQW, RWW, ACC_SIMW);
  k_finalize<<<1, 32, 0, stream>>>(ACC_SIMW, w_bsg, w_bsb, SC_SIMW, 24, invsim);
  k_att2<<<dim3(1024,8), blk, 0, stream>>>(QKVW, SC_BQW, w_rel, SC_SIMW, SVO, ACC_BOW);
  k_finalize<<<1, 256, 0, stream>>>(ACC_BOW, w_bog, w_bob, SC_BOW, 256, inv64k);
  k_pair_w<<<dim3(128,16), blk, 0, stream>>>(SVO, SC_BOW, WBUF);

  // cu conv + bn2 stats, then fused residual + c1 conv
  k_gemm<256,0,12><<<1024, 256, 0, stream>>>(WBUF, CUBF, cu_b, Y2, ACC_BN2, nullptr, nullptr);
  k_finalize<<<1, 256, 0, stream>>>(ACC_BN2, bn2_g, bn2_b, SC_BN2, 256, inv64k);
  k_gemm<256,2,12><<<1024, 256, 0, stream>>>(x, C1BF, c1_b, out, nullptr, Y2, SC_BN2);
}

// Round 8
// 400.712 us; speedup vs baseline: 13.0325x; 1.1126x over previous
//
#include <hip/hip_runtime.h>

// ---------------------------------------------------------------------------
// AxialBlock fused implementation. Round 8: bf16 intermediates (OUT0/HIN/
// WIN/WBUF/SVO/Y2) + k_att2 phase-A reorientation (lane=i, contiguous re
// reads, packed-fma). NB=16, CIN=128, COUT=256, MID=128, G=8, GP=16, K=64
// ---------------------------------------------------------------------------

#define NCOPY 64

typedef __attribute__((ext_vector_type(8))) short bf16x8;
typedef __attribute__((ext_vector_type(4))) short bf16x4;
typedef __attribute__((ext_vector_type(4))) float f32x4;
typedef __attribute__((ext_vector_type(2))) float f32x2;

__device__ __forceinline__ float wave_sum(float v){
  #pragma unroll
  for (int o = 32; o; o >>= 1) v += __shfl_xor(v, o, 64);
  return v;
}
__device__ __forceinline__ ushort f2bf(float f){
  union { float f; unsigned u; } v; v.f = f;
  unsigned r = v.u + 0x7FFFu + ((v.u >> 16) & 1u);   // round-to-nearest-even
  return (ushort)(r >> 16);
}
__device__ __forceinline__ float bf2f(ushort u){
  union { unsigned u; float f; } v; v.u = ((unsigned)u) << 16;
  return v.f;
}

// ---------------------------------------------------------------------------
// all 5 weight tensors fp32 -> bf16 (contiguous dst), one launch
// ---------------------------------------------------------------------------
__global__ void k_cvt5(const float* __restrict__ s0, const float* __restrict__ s1,
                       const float* __restrict__ s2, const float* __restrict__ s3,
                       const float* __restrict__ s4, ushort* __restrict__ dst){
  int i = blockIdx.x*256 + threadIdx.x;
  if (i >= 147456) return;
  float v;
  if      (i < 16384)  v = s0[i];
  else if (i < 49152)  v = s1[i-16384];
  else if (i < 81920)  v = s2[i-49152];
  else if (i < 114688) v = s3[i-81920];
  else                 v = s4[i-114688];
  dst[i] = f2bf(v);
}

// ---------------------------------------------------------------------------
// MFMA GEMM: out[o][col] = sum_c Wb[o][c] * X[c][col]  (+ epilogue per MODE)
// MODE 0: + bias, write, stats.  MODE 1: write, stats.  MODE 2: + bias +
// scsh*y2(bf16) residual, write, no stats.  INBF/OUTBF: X/out are bf16.
// ---------------------------------------------------------------------------
template<int O, int MODE, int SLOG, int INBF, int OUTBF>
__global__ __launch_bounds__(256) void k_gemm(
    const void* __restrict__ X_, const ushort* __restrict__ Wb,
    const float* __restrict__ bias, void* __restrict__ out_,
    float* __restrict__ acc, const ushort* __restrict__ y2,
    const float* __restrict__ scsh)
{
  constexpr int RPW = O/4;       // rows per wave
  constexpr int NS  = RPW/16;    // 16-row subtiles per wave
  __shared__ ushort XT[64*128];  // [col][k] bf16, chunk-XOR swizzled

  const int tid = threadIdx.x;
  const int col0 = blockIdx.x << 6;
  const int seg  = col0 >> SLOG;
  const int p0   = col0 & ((1<<SLOG)-1);

  // ---- stage X tile (128c x 64col) -> bf16 transposed+swizzled ----
  {
    const int col = tid & 63;
    const int kc8 = tid >> 6;                  // 0..3
    #pragma unroll
    for (int q = 0; q < 4; ++q){
      int kc = kc8*4 + q;                      // k-chunk 0..15 (8 c's each)
      int c0 = kc*8;
      bf16x8 pk;
      if constexpr (INBF){
        const ushort* xb = (const ushort*)X_ + (((size_t)seg*128) << SLOG) + p0 + col;
        #pragma unroll
        for (int j = 0; j < 8; ++j)
          pk[j] = (short)xb[(size_t)(c0+j) << SLOG];
      } else {
        const float* xb = (const float*)X_ + (((size_t)seg*128) << SLOG) + p0 + col;
        #pragma unroll
        for (int j = 0; j < 8; ++j)
          pk[j] = (short)f2bf(xb[(size_t)(c0+j) << SLOG]);
      }
      *(bf16x8*)&XT[col*128 + ((kc ^ (col & 15)) << 3)] = pk;
    }
  }
  __syncthreads();

  const int lane = tid & 63;
  const int wid  = tid >> 6;
  const int l15  = lane & 15, lg = lane >> 4;

  f32x4 accr[NS][4];
  #pragma unroll
  for (int s = 0; s < NS; ++s)
    #pragma unroll
    for (int ns = 0; ns < 4; ++ns)
      accr[s][ns] = (f32x4){0.f,0.f,0.f,0.f};

  #pragma unroll
  for (int kk = 0; kk < 4; ++kk){
    bf16x8 af[NS];
    #pragma unroll
    for (int s = 0; s < NS; ++s){
      int m = wid*RPW + s*16 + l15;
      af[s] = *(const bf16x8*)(Wb + (size_t)m*128 + kk*32 + lg*8);
    }
    bf16x8 bfr[4];
    #pragma unroll
    for (int ns = 0; ns < 4; ++ns){
      int ncol  = ns*16 + l15;
      int chunk = kk*4 + lg;
      bfr[ns] = *(const bf16x8*)&XT[ncol*128 + ((chunk ^ l15) << 3)];
    }
    #pragma unroll
    for (int s = 0; s < NS; ++s)
      #pragma unroll
      for (int ns = 0; ns < 4; ++ns)
        accr[s][ns] = __builtin_amdgcn_mfma_f32_16x16x32_bf16(
                        af[s], bfr[ns], accr[s][ns], 0, 0, 0);
  }

  // ---- epilogue ----
  float* accb = (MODE != 2) ? acc + (size_t)(blockIdx.x & (NCOPY-1))*2*O : nullptr;
  #pragma unroll
  for (int s = 0; s < NS; ++s){
    #pragma unroll
    for (int r = 0; r < 4; ++r){
      const int m = wid*RPW + s*16 + lg*4 + r;
      const float bs = (MODE != 1) ? bias[m] : 0.f;
      float vsum = 0.f, vsq = 0.f;
      #pragma unroll
      for (int ns = 0; ns < 4; ++ns){
        float v = accr[s][ns][r] + bs;
        size_t oidx = (((size_t)seg*O + m) << SLOG) + p0 + ns*16 + l15;
        if (MODE == 2)
          v += fmaf(scsh[m], bf2f(y2[oidx]), scsh[O+m]);
        if constexpr (OUTBF) ((ushort*)out_)[oidx] = f2bf(v);
        else                 ((float*) out_)[oidx] = v;
        vsum += v; vsq = fmaf(v, v, vsq);
      }
      if (MODE != 2){
        #pragma unroll
        for (int o2 = 1; o2 < 16; o2 <<= 1){
          vsum += __shfl_xor(vsum, o2, 64);
          vsq  += __shfl_xor(vsq , o2, 64);
        }
        if (l15 == 0){
          atomicAdd(&accb[m],   vsum);
          atomicAdd(&accb[O+m], vsq);
        }
      }
    }
  }
}

// ---------------------------------------------------------------------------
// BN finalize: sum NCOPY copies; scsh[c]=g*rstd ; scsh[C+c]=b-mean*scale
// ---------------------------------------------------------------------------
__global__ void k_finalize(const float* __restrict__ acc, const float* __restrict__ g,
    const float* __restrict__ b, float* __restrict__ scsh, int C, float invcnt)
{
  int c = blockIdx.x*blockDim.x + threadIdx.x;
  if (c >= C) return;
  float s = 0.f, s2 = 0.f;
  #pragma unroll 4
  for (int k2 = 0; k2 < NCOPY; ++k2){
    s  += acc[(size_t)k2*2*C + c];
    s2 += acc[(size_t)k2*2*C + C + c];
  }
  float mean = s*invcnt;
  float var  = s2*invcnt - mean*mean;
  float sc = g[c]*rsqrtf(var + 1e-5f);
  scsh[c]   = sc;
  scsh[C+c] = fmaf(-mean, sc, b[c]);
}

// ---------------------------------------------------------------------------
// bn1+relu + transpose: hin[(n*64+w)*8192 + c*64 + h] = relu(bn(out0)) (bf16)
// ---------------------------------------------------------------------------
__global__ __launch_bounds__(256) void k_trans_bnrelu(const ushort* __restrict__ out0,
    const float* __restrict__ scsh, ushort* __restrict__ hin)
{
  __shared__ float t[64][65];
  const int c = blockIdx.x, n = blockIdx.y;
  const int tx = threadIdx.x, ty = threadIdx.y;
  const float sc = scsh[c], sh = scsh[128+c];
  const ushort* src = out0 + ((size_t)n*128 + c)*4096;
  #pragma unroll
  for (int r = 0; r < 16; ++r){
    int h = ty + r*4;
    t[h][tx] = bf2f(src[h*64 + tx]);
  }
  __syncthreads();
  ushort* dst = hin + (size_t)(n*64)*8192 + (size_t)c*64;
  #pragma unroll
  for (int r = 0; r < 16; ++r){
    int w_ = ty + r*4;
    float vv = fmaf(sc, t[tx][w_], sh);
    dst[(size_t)w_*8192 + tx] = f2bf(fmaxf(vv, 0.f));
  }
}

// ---------------------------------------------------------------------------
// rel windowed sums/correlations for sim-BN stats (both h and w in one grid)
// ---------------------------------------------------------------------------
__global__ __launch_bounds__(256) void k_prep_rel2(const float* __restrict__ relh,
    const float* __restrict__ relw, float* __restrict__ rwh, float* __restrict__ rww)
{
  const float* rel = (blockIdx.x & 2) ? relw : relh;
  float* rw        = (blockIdx.x & 2) ? rww  : rwh;
  const int side = blockIdx.x & 1;
  const float* base = rel + side*8*127;
  float* Wout = rw + side*4096;
  float* Sout = rw + 8192 + side*512;
  const int tid = threadIdx.y*64 + threadIdx.x;
  for (int idx = tid; idx < 4096; idx += 256){
    int pr = idx >> 6, i = idx & 63;
    int c = pr >> 3, c2 = pr & 7;
    const float* r1 = base + c*127 + i;
    const float* r2 = base + c2*127 + i;
    float s = 0.f;
    #pragma unroll 8
    for (int u = 0; u < 64; ++u) s = fmaf(r1[u], r2[u], s);
    Wout[idx] = s;
  }
  for (int idx = tid; idx < 512; idx += 256){
    int c = idx >> 6, i = idx & 63;
    const float* r1 = base + c*127 + i;
    float s = 0.f;
    #pragma unroll 8
    for (int u = 0; u < 64; ++u) s += r1[u];
    Sout[idx] = s;
  }
}

// ---------------------------------------------------------------------------
// sim-BN stats per (b,g): Gram + rowsums via MFMA, table part on VALU.
// grid (1024), block (64,4)
// ---------------------------------------------------------------------------
__global__ __launch_bounds__(256, 4) void k_att_stats(const float* __restrict__ qkv,
    const float* __restrict__ bq, const float* __restrict__ rw, float* __restrict__ accsim)
{
  __shared__ float WqS[4096], WkS[4096], SqS[512], SkS[512];
  const int b = blockIdx.x;
  const int tx = threadIdx.x, ty = threadIdx.y;
  const int tid = ty*64 + tx;
  for (int idx = tid; idx < 4096; idx += 256){ WqS[idx] = rw[idx]; WkS[idx] = rw[4096+idx]; }
  for (int idx = tid; idx < 512;  idx += 256){ SqS[idx] = rw[8192+idx]; SkS[idx] = rw[8704+idx]; }
  __syncthreads();
  float* accb = accsim + (size_t)(b & (NCOPY-1)) * 48;
  const int i = tx;
  const int l15 = tx & 15, lg = tx >> 4;
  const short one_bf = (short)0x3F80;
  const bf16x8 ones = {one_bf,one_bf,one_bf,one_bf,one_bf,one_bf,one_bf,one_bf};

  #pragma unroll
  for (int gi = 0; gi < 2; ++gi){
    const int g = ty*2 + gi;
    float q[8], k[8];
    #pragma unroll
    for (int c = 0; c < 8; ++c){
      int oq = g*32 + c, ok = oq + 8;
      q[c] = fmaf(bq[oq], qkv[((size_t)b*256 + oq)*64 + i], bq[256+oq]);
      k[c] = fmaf(bq[ok], qkv[((size_t)b*256 + ok)*64 + i], bq[256+ok]);
    }
    const int och = g*32 + l15;               // rows 0..7 = q, 8..15 = k
    const float gsc = bq[och], gsh = bq[256+och];
    const float* src = &qkv[((size_t)b*256 + och)*64 + lg*8];
    bf16x8 a0, a1;
    #pragma unroll
    for (int j = 0; j < 8; ++j) a0[j] = (short)f2bf(fmaf(gsc, src[j],      gsh));
    #pragma unroll
    for (int j = 0; j < 8; ++j) a1[j] = (short)f2bf(fmaf(gsc, src[32 + j], gsh));
    f32x4 G = (f32x4){0.f,0.f,0.f,0.f};
    f32x4 R = (f32x4){0.f,0.f,0.f,0.f};
    G = __builtin_amdgcn_mfma_f32_16x16x32_bf16(a0, a0, G, 0, 0, 0);
    G = __builtin_amdgcn_mfma_f32_16x16x32_bf16(a1, a1, G, 0, 0, 0);
    R = __builtin_amdgcn_mfma_f32_16x16x32_bf16(a0, ones, R, 0, 0, 0);
    R = __builtin_amdgcn_mfma_f32_16x16x32_bf16(a1, ones, R, 0, 0, 0);
    float ss = 0.f, sqk = 0.f;
    const bool gq_lane = (l15 < 8) && (lg < 2);
    const bool r_lane  = (l15 == 0) && (lg < 2);
    #pragma unroll
    for (int r = 0; r < 4; ++r){
      float gsw = __shfl_xor(G[r], 40, 64);
      float rsw = __shfl_xor(R[r], 32, 64);
      if (gq_lane) ss  = fmaf(G[r], gsw, ss);
      if (r_lane)  sqk = fmaf(R[r], rsw, sqk);
    }
    float aq = 0.f, ak = 0.f, aq2 = 0.f, ak2 = 0.f;
    #pragma unroll
    for (int c = 0; c < 8; ++c){
      aq = fmaf(q[c], SqS[c*64 + i], aq);
      ak = fmaf(k[c], SkS[c*64 + i], ak);
    }
    #pragma unroll
    for (int c = 0; c < 8; ++c){
      #pragma unroll
      for (int c2 = c; c2 < 8; ++c2){
        float w2 = (c2 == c) ? 1.f : 2.f;
        aq2 = fmaf(w2*q[c]*q[c2], WqS[(c*8+c2)*64 + i], aq2);
        ak2 = fmaf(w2*k[c]*k[c2], WkS[(c*8+c2)*64 + i], ak2);
      }
    }
    sqk = wave_sum(sqk);  ss  = wave_sum(ss);
    aq  = wave_sum(aq);   ak  = wave_sum(ak);
    aq2 = wave_sum(aq2);  ak2 = wave_sum(ak2);
    if (tx == 0){
      atomicAdd(&accb[g],      sqk);       atomicAdd(&accb[24+g],    ss);
      atomicAdd(&accb[8+g],    0.1f*aq);   atomicAdd(&accb[24+8+g],  0.01f*aq2);
      atomicAdd(&accb[16+g],   0.1f*ak);   atomicAdd(&accb[24+16+g], 0.01f*ak2);
    }
  }
}

// ---------------------------------------------------------------------------
// attention pass 2 (R8): lane=i fp32 logits (contiguous re reads, pk-fma)
// -> group softmax -> bf16 P/P' -> MFMA sv/sve -> bf16 svout.
// grid (1024 b, 8 g), block (64,4)
//
// LDS (bytes):  [0]      P32   16896 (64x66 f32)
//               [16896]  REQT   6144 (128 rows x 48B: 8 f32 + pad)
//               [23040]  REKT   6144
//               [29184]  KT     2048 (64 x 8 f32)
//               [31232]  VB     2304 (16x72 bf16, swizzled)
//               [33536]  REB    4352 (16x136 bf16, swizzled)
//               [37888]  RINV    256
//  aliased after bar1:  PB 8192 @0, PP 16384 @8192 (within dead P32/REQT)
// ---------------------------------------------------------------------------
__global__ __launch_bounds__(256) void k_att2(const float* __restrict__ qkv,
    const float* __restrict__ bq, const float* __restrict__ rel,
    const float* __restrict__ simsc, ushort* __restrict__ svout, float* __restrict__ accbo)
{
  __shared__ __align__(16) char smem[38144];
  float* P32  = (float*)(smem);            // [64][66]
  float* REQT = (float*)(smem + 16896);    // [128][12] (8 used)
  float* REKT = (float*)(smem + 23040);
  float* KT   = (float*)(smem + 29184);    // [64][8]
  float* RINV = (float*)(smem + 37888);

  const int b = blockIdx.x, g = blockIdx.y;
  const int tx = threadIdx.x, ty = threadIdx.y;
  const int tid = ty*64 + tx;
  const float scq  = simsc[g];
  const float scr_ = 0.1f*simsc[8+g];
  const float sck_ = 0.1f*simsc[16+g];

  // ---- staging ----
  if (tid < 128){                          // KT[j][c] = bn(k[c][j])
    int j = tid & 63, h = tid >> 6;
    f32x4 kv;
    #pragma unroll
    for (int e = 0; e < 4; ++e){
      int o = g*32 + 8 + h*4 + e;
      kv[e] = fmaf(bq[o], qkv[((size_t)b*256 + o)*64 + j], bq[256+o]);
    }
    *(f32x4*)(KT + j*8 + h*4) = kv;
  }
  if (tid < 254){                          // REQT/REKT rows (scale folded)
    int side = tid >= 127;
    int d = tid - side*127;
    float rs = side ? sck_ : scr_;
    float* dst = (side ? REKT : REQT) + d*12;
    f32x4 r0, r1;
    #pragma unroll
    for (int e = 0; e < 4; ++e) r0[e] = rel[(side*8 + e)*127 + d]*rs;
    #pragma unroll
    for (int e = 0; e < 4; ++e) r1[e] = rel[(side*8 + 4 + e)*127 + d]*rs;
    *(f32x4*)dst = r0; *(f32x4*)(dst+4) = r1;
  }
  {
    // VB[c][j] bf16, chunk-XOR swizzle
    int c = tid >> 4, j4 = (tid & 15)*4;
    int o = g*32 + 16 + c;
    float gsc = bq[o], gsh = bq[256+o];
    const float* src = &qkv[((size_t)b*256 + o)*64 + j4];
    bf16x4 pv;
    #pragma unroll
    for (int e = 0; e < 4; ++e) pv[e] = (short)f2bf(fmaf(gsc, src[e], gsh));
    *(bf16x4*)(smem + 31232 + c*144 + (((j4>>3) ^ (c&7))<<4) + (j4&7)*2) = pv;
  }
  {
    // REB[c][d] = 0.1*rel[16+c][d] bf16, swizzled
    int c = tid >> 4, d8 = (tid & 15)*8;
    const float* rsrc = &rel[(16+c)*127 + d8];
    bf16x8 pk;
    #pragma unroll
    for (int e = 0; e < 8; ++e){
      int d = d8 + e;
      pk[e] = (d < 127) ? (short)f2bf(0.1f*rsrc[e]) : (short)0;
    }
    *(bf16x8*)(smem + 33536 + c*272 + (((d8>>3) ^ (c&15))<<4)) = pk;
  }
  float q8[8], qs8[8];                     // per-lane q (i = tx), scq-folded copy
  #pragma unroll
  for (int c = 0; c < 8; ++c){
    int o = g*32 + c;
    float qv = fmaf(bq[o], qkv[((size_t)b*256 + o)*64 + tx], bq[256+o]);
    q8[c] = qv; qs8[c] = scq*qv;
  }
  __syncthreads();

  // ---- phase A: lane = i = tx; wave ty covers j = ty*16..+15 ----
  {
    const int j0 = ty*16;
    const f32x2* q2  = (const f32x2*)q8;
    const f32x2* qs2 = (const f32x2*)qs8;
    #pragma unroll
    for (int t = 0; t < 16; ++t){
      const int j = j0 + t;
      const f32x2* kt = (const f32x2*)(KT + j*8);
      const f32x2* rq = (const f32x2*)(REQT + (tx - j + 63)*12);
      const f32x2* rk = (const f32x2*)(REKT + (j - tx + 63)*12);
      f32x2 a2 = (f32x2){0.f, 0.f};
      #pragma unroll
      for (int c2 = 0; c2 < 4; ++c2){
        f32x2 ktv = kt[c2];
        a2 = __builtin_elementwise_fma(qs2[c2], ktv,    a2);
        a2 = __builtin_elementwise_fma(q2[c2],  rq[c2], a2);
        a2 = __builtin_elementwise_fma(ktv,     rk[c2], a2);
      }
      P32[tx*66 + j] = a2.x + a2.y;
    }
  }
  __syncthreads();

  // ---- phase B: softmax; thread (row=tid>>2, sl=tid&3) owns 16 elems ----
  float e0[16];
  const int row = tid >> 2, sl = tid & 3;
  {
    const float* prow = &P32[row*66 + sl*16];
    #pragma unroll
    for (int e = 0; e < 16; ++e) e0[e] = prow[e];
    float m0 = fmaxf(fmaxf(e0[0],e0[1]),  fmaxf(e0[2],e0[3]));
    float m1 = fmaxf(fmaxf(e0[4],e0[5]),  fmaxf(e0[6],e0[7]));
    float m2 = fmaxf(fmaxf(e0[8],e0[9]),  fmaxf(e0[10],e0[11]));
    float m3 = fmaxf(fmaxf(e0[12],e0[13]),fmaxf(e0[14],e0[15]));
    float m = fmaxf(fmaxf(m0,m1), fmaxf(m2,m3));
    m = fmaxf(m, __shfl_xor(m, 1, 64));
    m = fmaxf(m, __shfl_xor(m, 2, 64));
    float s = 0.f;
    #pragma unroll
    for (int e = 0; e < 16; ++e){ float ex = __expf(e0[e]-m); e0[e]=ex; s += ex; }
    s += __shfl_xor(s, 1, 64);
    s += __shfl_xor(s, 2, 64);
    __syncthreads();                        // bar1: P32/REQT/REKT/KT now dead
    {
      f32x4 z = (f32x4){0.f,0.f,0.f,0.f};
      float* zp = (float*)(smem + 8192 + tid*64);
      *(f32x4*)(zp+0) = z; *(f32x4*)(zp+4) = z;
      *(f32x4*)(zp+8) = z; *(f32x4*)(zp+12) = z;
    }
    if (sl == 0) RINV[row] = 1.0f/s;
    __syncthreads();                        // bar2
    bf16x8 pk0, pk1;
    #pragma unroll
    for (int e = 0; e < 8; ++e){ pk0[e] = (short)f2bf(e0[e]); pk1[e] = (short)f2bf(e0[8+e]); }
    char* pbbase = smem + 0 + row*128;
    *(bf16x8*)(pbbase + (((2*sl    ) ^ (row&7))<<4)) = pk0;
    *(bf16x8*)(pbbase + (((2*sl + 1) ^ (row&7))<<4)) = pk1;
    char* ppbase = smem + 8192 + row*256;
    #pragma unroll
    for (int e = 0; e < 16; ++e){
      int j = sl*16 + e, d = row - j + 63;
      *(ushort*)(ppbase + (((d>>3) ^ (row&15))<<4) + (d&7)*2) = f2bf(e0[e]);
    }
  }
  __syncthreads();                          // bar3

  // ---- phase C: MFMA. wave ty: output rows i0..i0+15, cols = 16 channels ----
  {
    const int l15 = tx & 15, lg = tx >> 4;
    const int i0 = ty*16;
    const int rowA = i0 + l15;
    char* pbA = smem + 0    + rowA*128;
    char* ppA = smem + 8192 + rowA*256;
    char* vbB = smem + 31232 + l15*144;
    char* reB = smem + 33536 + l15*272;
    f32x4 accv = (f32x4){0.f,0.f,0.f,0.f};
    f32x4 acce = (f32x4){0.f,0.f,0.f,0.f};
    #pragma unroll
    for (int kk = 0; kk < 2; ++kk){
      bf16x8 a  = *(bf16x8*)(pbA + (((kk*4+lg) ^ (rowA&7))<<4));
      bf16x8 bb = *(bf16x8*)(vbB + (((kk*4+lg) ^ (l15&7))<<4));
      accv = __builtin_amdgcn_mfma_f32_16x16x32_bf16(a, bb, accv, 0, 0, 0);
    }
    #pragma unroll
    for (int kk = 0; kk < 4; ++kk){
      bf16x8 a  = *(bf16x8*)(ppA + (((kk*4+lg) ^ (rowA&15))<<4));
      bf16x8 bb = *(bf16x8*)(reB + (((kk*4+lg) ^ (l15&15))<<4));
      acce = __builtin_amdgcn_mfma_f32_16x16x32_bf16(a, bb, acce, 0, 0, 0);
    }
    f32x4 ri4 = *(f32x4*)(smem + 37888 + (i0 + lg*4)*4);
    float* accb = accbo + (size_t)(b & (NCOPY-1)) * 512;
    {
      bf16x4 vb4;
      float vsum = 0.f, vsq = 0.f;
      #pragma unroll
      for (int r = 0; r < 4; ++r){
        float v = accv[r]*ri4[r];
        vb4[r] = (short)f2bf(v); vsum += v; vsq = fmaf(v, v, vsq);
      }
      int ch = g*16 + l15;
      *(bf16x4*)&svout[((size_t)b*256 + ch)*64 + i0 + lg*4] = vb4;
      vsum += __shfl_xor(vsum, 16, 64); vsum += __shfl_xor(vsum, 32, 64);
      vsq  += __shfl_xor(vsq , 16, 64); vsq  += __shfl_xor(vsq , 32, 64);
      if (lg == 0){ atomicAdd(&accb[ch], vsum); atomicAdd(&accb[256+ch], vsq); }
    }
    {
      bf16x4 vb4;
      float vsum = 0.f, vsq = 0.f;
      #pragma unroll
      for (int r = 0; r < 4; ++r){
        float v = acce[r]*ri4[r];
        vb4[r] = (short)f2bf(v); vsum += v; vsq = fmaf(v, v, vsq);
      }
      int ch = 128 + g*16 + l15;
      *(bf16x4*)&svout[((size_t)b*256 + ch)*64 + i0 + lg*4] = vb4;
      vsum += __shfl_xor(vsum, 16, 64); vsum += __shfl_xor(vsum, 32, 64);
      vsq  += __shfl_xor(vsq , 16, 64); vsq  += __shfl_xor(vsq , 32, 64);
      if (lg == 0){ atomicAdd(&accb[ch], vsum); atomicAdd(&accb[256+ch], vsq); }
    }
  }
}

// ---------------------------------------------------------------------------
// bo-BN + pair-sum + transpose (h-axial -> w-axial input), bf16 in/out
// ---------------------------------------------------------------------------
__global__ __launch_bounds__(256) void k_pairT(const ushort* __restrict__ sv,
    const float* __restrict__ bo, ushort* __restrict__ win)
{
  __shared__ float t[64][65];
  const int c = blockIdx.x, n = blockIdx.y;
  const int tx = threadIdx.x, ty = threadIdx.y;
  const float s0 = bo[2*c], s1 = bo[2*c+1];
  const float sh = bo[256 + 2*c] + bo[256 + 2*c + 1];
  const ushort* base = sv + (size_t)(n*64)*256*64;
  #pragma unroll
  for (int r = 0; r < 16; ++r){
    int w_ = ty + r*4;
    float v0 = bf2f(base[((size_t)w_*256 + 2*c    )*64 + tx]);
    float v1 = bf2f(base[((size_t)w_*256 + 2*c + 1)*64 + tx]);
    t[w_][tx] = fmaf(s0, v0, fmaf(s1, v1, sh));
  }
  __syncthreads();
  ushort* dst = win + (size_t)(n*64)*8192 + (size_t)c*64;
  #pragma unroll
  for (int r = 0; r < 16; ++r){
    int h_ = ty + r*4;
    dst[(size_t)h_*8192 + tx] = f2bf(t[tx][h_]);
  }
}

// ---------------------------------------------------------------------------
// bo-BN + pair-sum, no transpose (w-axial -> natural NCHW), bf16 in/out
// ---------------------------------------------------------------------------
__global__ __launch_bounds__(256) void k_pair_w(const ushort* __restrict__ sv,
    const float* __restrict__ bo, ushort* __restrict__ wbuf)
{
  const int m = blockIdx.x, n = blockIdx.y;
  const int tx = threadIdx.x, ty = threadIdx.y;
  const float s0 = bo[2*m], s1 = bo[2*m+1];
  const float sh = bo[256 + 2*m] + bo[256 + 2*m + 1];
  #pragma unroll
  for (int r = 0; r < 16; ++r){
    int h = ty + r*4;
    float v0 = bf2f(sv[((size_t)(n*64+h)*256 + 2*m    )*64 + tx]);
    float v1 = bf2f(sv[((size_t)(n*64+h)*256 + 2*m + 1)*64 + tx]);
    wbuf[((size_t)(n*128+m)*64 + h)*64 + tx] = f2bf(fmaf(s0, v0, fmaf(s1, v1, sh)));
  }
}

// ---------------------------------------------------------------------------

extern "C" void kernel_launch(void* const* d_in, const int* in_sizes, int n_in,
                              void* d_out, int out_size, void* d_ws, size_t ws_size,
                              hipStream_t stream)
{
  const float* x     = (const float*)d_in[0];
  const float* c1_w  = (const float*)d_in[1];
  const float* c1_b  = (const float*)d_in[2];
  const float* cd_w  = (const float*)d_in[3];
  const float* cd_b  = (const float*)d_in[4];
  const float* bn1_g = (const float*)d_in[5];
  const float* bn1_b = (const float*)d_in[6];
  const float* h_qkv = (const float*)d_in[7];
  const float* h_bqg = (const float*)d_in[8];
  const float* h_bqb = (const float*)d_in[9];
  const float* h_bsg = (const float*)d_in[10];
  const float* h_bsb = (const float*)d_in[11];
  const float* h_bog = (const float*)d_in[12];
  const float* h_bob = (const float*)d_in[13];
  const float* h_rel = (const float*)d_in[14];
  const float* w_qkv = (const float*)d_in[15];
  const float* w_bqg = (const float*)d_in[16];
  const float* w_bqb = (const float*)d_in[17];
  const float* w_bsg = (const float*)d_in[18];
  const float* w_bsb = (const float*)d_in[19];
  const float* w_bog = (const float*)d_in[20];
  const float* w_bob = (const float*)d_in[21];
  const float* w_rel = (const float*)d_in[22];
  const float* cu_w  = (const float*)d_in[23];
  const float* cu_b  = (const float*)d_in[24];
  const float* bn2_g = (const float*)d_in[25];
  const float* bn2_b = (const float*)d_in[26];
  float* out = (float*)d_out;
  char* ws = (char*)d_ws;

  // big buffers (aliased across dead stages; offsets unchanged, some now bf16):
  ushort* OUT0 = (ushort*)(ws + 0);                  // 16MB bf16 (n,128,4096)
  ushort* HIN  = (ushort*)(ws + (32ull<<20));        // 16MB bf16 (1024,128,64)
  float*  QKV  = (float*)(ws + (64ull<<20));         // 64MB f32 (1024,256,64) h
  ushort* SVO  = (ushort*)(ws + 0);                  // 32MB bf16, after OUT0/HIN dead
  ushort* WIN  = (ushort*)(ws + (64ull<<20));        // 16MB bf16, after QKV(h) dead
  float*  QKVW = (float*)(ws + (96ull<<20));         // 64MB f32 w-phase
  ushort* WBUF = (ushort*)(ws + (64ull<<20));        // 16MB bf16, after WIN dead
  ushort* Y2   = (ushort*)(ws + (96ull<<20));        // 32MB bf16, after QKVW dead
  float*  ST   = (float*)(ws + (160ull<<20));        // stats region

  // NCOPY=64 spread accumulators (sizes in floats):
  float* ACC_BN1 = ST;             // 16384
  float* ACC_BQ  = ST + 16384;     // 32768
  float* ACC_SIM = ST + 49152;     // 3072
  float* ACC_BO  = ST + 52224;     // 32768
  float* ACC_BQW = ST + 84992;     // 32768
  float* ACC_SIMW= ST + 117760;    // 3072
  float* ACC_BOW = ST + 120832;    // 32768
  float* ACC_BN2 = ST + 153600;    // 32768  -> ACC total 186368 floats
  float* SCB     = ST + 186368;
  float* SC_BN1 = SCB;        float* SC_BQ  = SCB + 256;
  float* SC_SIM = SCB + 768;  float* SC_BO  = SCB + 816;
  float* SC_BQW = SCB + 1328; float* SC_SIMW= SCB + 1840;
  float* SC_BOW = SCB + 1888; float* SC_BN2 = SCB + 2400;  // -> 2912
  float* RWH  = ST + 189280;  // 9216 floats
  float* RWW  = ST + 198496;  // 9216 floats (end 207712)
  // bf16 weights (contiguous for k_cvt5):
  ushort* CDBF = (ushort*)(ST + 207712);   // 16384
  ushort* QHBF = CDBF + 16384;             // 32768
  ushort* QWBF = CDBF + 49152;             // 32768
  ushort* CUBF = CDBF + 81920;             // 32768
  ushort* C1BF = CDBF + 114688;            // 32768 (end 147456 ushorts)

  hipMemsetAsync(ST, 0, 186368*sizeof(float), stream);

  const dim3 blk(64,4);
  const float inv64k = 1.f/65536.f;
  const float invsim = 1.f/4194304.f;

  // weight conversions + rel prep (fused launches)
  k_cvt5<<<576, 256, 0, stream>>>(cd_w, h_qkv, w_qkv, cu_w, c1_w, CDBF);
  k_prep_rel2<<<4, blk, 0, stream>>>(h_rel, w_rel, RWH, RWW);

  // cd conv + bn1 stats
  k_gemm<128,0,12,0,1><<<1024, 256, 0, stream>>>(x, CDBF, cd_b, OUT0, ACC_BN1, nullptr, nullptr);
  k_finalize<<<1, 128, 0, stream>>>(ACC_BN1, bn1_g, bn1_b, SC_BN1, 128, inv64k);
  k_trans_bnrelu<<<dim3(128,16), blk, 0, stream>>>(OUT0, SC_BN1, HIN);

  // ---- h axial ----
  k_gemm<256,1,6,1,0><<<1024, 256, 0, stream>>>(HIN, QHBF, nullptr, QKV, ACC_BQ, nullptr, nullptr);
  k_finalize<<<1, 256, 0, stream>>>(ACC_BQ, h_bqg, h_bqb, SC_BQ, 256, inv64k);
  k_att_stats<<<1024, blk, 0, stream>>>(QKV, SC_BQ, RWH, ACC_SIM);
  k_finalize<<<1, 32, 0, stream>>>(ACC_SIM, h_bsg, h_bsb, SC_SIM, 24, invsim);
  k_att2<<<dim3(1024,8), blk, 0, stream>>>(QKV, SC_BQ, h_rel, SC_SIM, SVO, ACC_BO);
  k_finalize<<<1, 256, 0, stream>>>(ACC_BO, h_bog, h_bob, SC_BO, 256, inv64k);
  k_pairT<<<dim3(128,16), blk, 0, stream>>>(SVO, SC_BO, WIN);

  // ---- w axial ----
  k_gemm<256,1,6,1,0><<<1024, 256, 0, stream>>>(WIN, QWBF, nullptr, QKVW, ACC_BQW, nullptr, nullptr);
  k_finalize<<<1, 256, 0, stream>>>(ACC_BQW, w_bqg, w_bqb, SC_BQW, 256, inv64k);
  k_att_stats<<<1024, blk, 0, stream>>>(QKVW, SC_BQW, RWW, ACC_SIMW);
  k_finalize<<<1, 32, 0, stream>>>(ACC_SIMW, w_bsg, w_bsb, SC_SIMW, 24, invsim);
  k_att2<<<dim3(1024,8), blk, 0, stream>>>(QKVW, SC_BQW, w_rel, SC_SIMW, SVO, ACC_BOW);
  k_finalize<<<1, 256, 0, stream>>>(ACC_BOW, w_bog, w_bob, SC_BOW, 256, inv64k);
  k_pair_w<<<dim3(128,16), blk, 0, stream>>>(SVO, SC_BOW, WBUF);

  // cu conv + bn2 stats, then fused residual + c1 conv
  k_gemm<256,0,12,1,1><<<1024, 256, 0, stream>>>(WBUF, CUBF, cu_b, Y2, ACC_BN2, nullptr, nullptr);
  k_finalize<<<1, 256, 0, stream>>>(ACC_BN2, bn2_g, bn2_b, SC_BN2, 256, inv64k);
  k_gemm<256,2,12,0,0><<<1024, 256, 0, stream>>>(x, C1BF, c1_b, out, nullptr, Y2, SC_BN2);
}